// Round 1
// baseline (3668.472 us; speedup 1.0000x reference)
//
#include <hip/hip_runtime.h>

#define DEV __device__ __forceinline__

typedef __bf16 bf16x8 __attribute__((ext_vector_type(8)));
typedef float f32x4 __attribute__((ext_vector_type(4)));

DEV unsigned short f2bf(float f) {
  union { float f; unsigned u; } v; v.f = f;
  unsigned r = v.u + 0x7FFFu + ((v.u >> 16) & 1u);
  return (unsigned short)(r >> 16);
}
DEV float bf2f(unsigned short h) {
  union { float f; unsigned u; } v; v.u = ((unsigned)h) << 16;
  return v.f;
}

// async global->LDS, 16B per lane. LDS dest is wave-uniform base + lane*16;
// passing (base + tid*16) works because readfirstlane(lane0 ptr) + lane*16 == tid*16.
DEV void gload16(const void* g, void* l) {
  __builtin_amdgcn_global_load_lds(
      (__attribute__((address_space(1))) void*)(g),
      (__attribute__((address_space(3))) void*)(l), 16, 0, 0);
}

// ---------------------------------------------------------------------------
// GEMM: out[M][N] = lrelu(A[M][K] @ Bt[N][K]^T + bias[N]), all bf16 in, bf16 out,
// fp32 accum via v_mfma_f32_16x16x32_bf16. Tiles: BM=BN=128, BK=64, 256 thr.
// LDS tiles stored with XOR swizzle: LDS[r*128 + kb] = row r bytes [kb ^ ((r&7)<<4)].
// Staged via global_load_lds with pre-swizzled per-lane GLOBAL source (rule #21).
// ---------------------------------------------------------------------------
__global__ __launch_bounds__(256) void gemm_bl(
    const unsigned short* __restrict__ A,
    const unsigned short* __restrict__ Bt,
    const float* __restrict__ bias,
    unsigned short* __restrict__ Out,
    int M, int N, int K,
    long sA, long sB, long sBias, long sOut)
{
  A    += (size_t)blockIdx.z * sA;
  Bt   += (size_t)blockIdx.z * sB;
  bias += (size_t)blockIdx.z * sBias;
  Out  += (size_t)blockIdx.z * sOut;

  const int tid  = threadIdx.x;
  const int lane = tid & 63;
  const int wid  = tid >> 6;
  const int wm   = wid >> 1, wn = wid & 1;
  const int m0   = blockIdx.y * 128, n0 = blockIdx.x * 128;

  __shared__ alignas(16) char smA[16384];
  __shared__ alignas(16) char smB[16384];

  f32x4 acc[4][4];
  const f32x4 fz = {0.f, 0.f, 0.f, 0.f};
#pragma unroll
  for (int i = 0; i < 4; ++i)
#pragma unroll
    for (int j = 0; j < 4; ++j) acc[i][j] = fz;

  const size_t ldab = (size_t)K * 2;     // bytes per row of A and Bt
  const int rr    = tid >> 3;            // 0..31 (row within 32-row issue group)
  const int chunk = (tid & 7) ^ (rr & 7);// swizzled 16B-chunk within the 128B row slice
  const char* gA = (const char*)A  + (size_t)(m0 + rr) * ldab + chunk * 16;
  const char* gB = (const char*)Bt + (size_t)(n0 + rr) * ldab + chunk * 16;
  char* lA = smA + tid * 16;
  char* lB = smB + tid * 16;
  const size_t rowStep = 32 * ldab;

  // fragment LDS byte offsets (swizzle is lane-only since rows step by 16)
  const int swz = (lane & 7) << 4;
  int aoff[4][2], boff[4][2];
#pragma unroll
  for (int f = 0; f < 4; ++f) {
    const int ra = wm * 64 + f * 16 + (lane & 15);
    const int rb = wn * 64 + f * 16 + (lane & 15);
#pragma unroll
    for (int ks = 0; ks < 2; ++ks) {
      const int kb = ks * 64 + ((lane >> 4) << 4);
      aoff[f][ks] = ra * 128 + (kb ^ swz);
      boff[f][ks] = rb * 128 + (kb ^ swz);
    }
  }

  const int nkt = K >> 6;
  for (int kt = 0; kt < nkt; ++kt) {
    const char* sa = gA + (size_t)kt * 128;
    const char* sb = gB + (size_t)kt * 128;
    gload16(sa,               lA);
    gload16(sa +     rowStep, lA + 4096);
    gload16(sa + 2 * rowStep, lA + 8192);
    gload16(sa + 3 * rowStep, lA + 12288);
    gload16(sb,               lB);
    gload16(sb +     rowStep, lB + 4096);
    gload16(sb + 2 * rowStep, lB + 8192);
    gload16(sb + 3 * rowStep, lB + 12288);
    __syncthreads();
#pragma unroll
    for (int ks = 0; ks < 2; ++ks) {
      bf16x8 af[4], bf[4];
#pragma unroll
      for (int f = 0; f < 4; ++f) af[f] = *(const bf16x8*)(smA + aoff[f][ks]);
#pragma unroll
      for (int f = 0; f < 4; ++f) bf[f] = *(const bf16x8*)(smB + boff[f][ks]);
#pragma unroll
      for (int mi = 0; mi < 4; ++mi)
#pragma unroll
        for (int ni = 0; ni < 4; ++ni)
          acc[mi][ni] = __builtin_amdgcn_mfma_f32_16x16x32_bf16(
              af[mi], bf[ni], acc[mi][ni], 0, 0, 0);
    }
    __syncthreads();
  }

  // epilogue: bias + lrelu + bf16 store. C/D layout: col=lane&15, row=(lane>>4)*4+reg
#pragma unroll
  for (int ni = 0; ni < 4; ++ni) {
    const int c = n0 + wn * 64 + ni * 16 + (lane & 15);
    const float bv = bias[c];
#pragma unroll
    for (int mi = 0; mi < 4; ++mi) {
#pragma unroll
      for (int j = 0; j < 4; ++j) {
        const int r = m0 + wm * 64 + mi * 16 + ((lane >> 4) << 2) + j;
        float v = acc[mi][ni][j] + bv;
        v = v >= 0.f ? v : 0.1f * v;
        Out[(size_t)r * N + c] = f2bf(v);
      }
    }
  }
}

// ---------------------------------------------------------------------------
// fp32 [K][N] -> bf16 [N][K] (per-z slab), LDS-tiled transpose
// ---------------------------------------------------------------------------
__global__ __launch_bounds__(256) void conv_t(
    const float* __restrict__ src, unsigned short* __restrict__ dst, int K, int N)
{
  const size_t zo = (size_t)blockIdx.z * K * N;
  src += zo; dst += zo;
  const int k0 = blockIdx.x * 64, n0 = blockIdx.y * 64;
  __shared__ unsigned short lds[64][68];
  const int t = threadIdx.x;
  const int cr = t >> 4;         // 0..15
  const int cc = (t & 15) * 4;
#pragma unroll
  for (int i = 0; i < 4; ++i) {
    const int row = i * 16 + cr;
    const float4 v = *(const float4*)(src + (size_t)(k0 + row) * N + n0 + cc);
    lds[row][cc + 0] = f2bf(v.x); lds[row][cc + 1] = f2bf(v.y);
    lds[row][cc + 2] = f2bf(v.z); lds[row][cc + 3] = f2bf(v.w);
  }
  __syncthreads();
#pragma unroll
  for (int i = 0; i < 4; ++i) {
    const int nrow = i * 16 + cr;
    ushort4 u = make_ushort4(lds[cc + 0][nrow], lds[cc + 1][nrow],
                             lds[cc + 2][nrow], lds[cc + 3][nrow]);
    *(ushort4*)(dst + (size_t)(n0 + nrow) * K + k0 + cc) = u;
  }
}

// fp32 -> bf16, 8 elements/thread
__global__ __launch_bounds__(256) void conv_x(
    const float* __restrict__ src, unsigned short* __restrict__ dst, int n8)
{
  const int i = blockIdx.x * 256 + threadIdx.x;
  if (i >= n8) return;
  const float4* p = (const float4*)(src + (size_t)i * 8);
  const float4 a = p[0], b = p[1];
  ushort4 u0 = make_ushort4(f2bf(a.x), f2bf(a.y), f2bf(a.z), f2bf(a.w));
  ushort4 u1 = make_ushort4(f2bf(b.x), f2bf(b.y), f2bf(b.z), f2bf(b.w));
  *(ushort4*)(dst + (size_t)i * 8)     = u0;
  *(ushort4*)(dst + (size_t)i * 8 + 4) = u1;
}

// ---------------------------------------------------------------------------
// gates: one wave per row; 56 logits via shuffle-reduce dots, softmax per group.
// gates ws layout per row: [0:20]=sh, [20:32]=sa, [32:44]=ra, [44:56]=ea
// ---------------------------------------------------------------------------
__global__ __launch_bounds__(64) void gates_k(
    const float* __restrict__ x,
    const float* __restrict__ Wsh, const float* __restrict__ bsh,
    const float* __restrict__ Wsa, const float* __restrict__ bsa,
    const float* __restrict__ Wra, const float* __restrict__ bra,
    const float* __restrict__ Wea, const float* __restrict__ bea,
    float* __restrict__ gates)
{
  const int b = blockIdx.x;
  const int lane = threadIdx.x;
  const float* xr = x + (size_t)b * 1024;
  float xv[16];
#pragma unroll
  for (int i = 0; i < 16; ++i) xv[i] = xr[i * 64 + lane];

  __shared__ float logit[56];
  const float* Wp[4] = {Wsh, Wsa, Wra, Wea};
  const float* bp[4] = {bsh, bsa, bra, bea};
  const int wd[4]  = {20, 12, 12, 12};
  const int off[4] = {0, 20, 32, 44};

  for (int g = 0; g < 4; ++g) {
    const float* W = Wp[g];
    const int Gw = wd[g];
    for (int c = 0; c < Gw; ++c) {
      float p = 0.f;
#pragma unroll
      for (int i = 0; i < 16; ++i) p += xv[i] * W[(size_t)(i * 64 + lane) * Gw + c];
#pragma unroll
      for (int o = 32; o; o >>= 1) p += __shfl_xor(p, o);
      if (lane == 0) logit[off[g] + c] = p + bp[g][c];
    }
  }
  __syncthreads();
  float* go = gates + (size_t)b * 56;
  for (int g = 0; g < 4; ++g) {
    const int n = wd[g], o0 = off[g];
    const float v = (lane < n) ? logit[o0 + lane] : -1e30f;
    float m = v;
#pragma unroll
    for (int o = 32; o; o >>= 1) m = fmaxf(m, __shfl_xor(m, o));
    float e = (lane < n) ? __expf(v - m) : 0.f;
    float s = e;
#pragma unroll
    for (int o = 32; o; o >>= 1) s += __shfl_xor(s, o);
    if (lane < n) go[o0 + lane] = e / s;
  }
}

// ---------------------------------------------------------------------------
// combine: per row b, stage eo[0:20][b][0:512] in LDS, emit tower_in[b][2048]
// sections: 0=shared-gate(20), 1=SA, 2=RA, 3=EA (4 task + 8 shared each)
// ---------------------------------------------------------------------------
__global__ __launch_bounds__(256) void combine_k(
    const unsigned short* __restrict__ eo,   // [20][8192][512]
    const float* __restrict__ gates,         // [8192][56]
    unsigned short* __restrict__ tin)        // [8192][2048]
{
  const int b = blockIdx.x;
  const int t = threadIdx.x;
  __shared__ alignas(16) unsigned short lds[20][512];
#pragma unroll
  for (int i = 0; i < 5; ++i) {
    const int chunk = t + i * 256;           // 0..1279
    const int e = chunk >> 6;
    const int h0 = (chunk & 63) * 8;
    *(uint4*)&lds[e][h0] = *(const uint4*)(eo + ((size_t)e * 8192 + b) * 512 + h0);
  }
  __syncthreads();

  const float* gb = gates + (size_t)b * 56;
  const int sec = t >> 6;                    // wave-uniform
  const int h0 = (t & 63) * 8;
  float acc[8] = {0.f, 0.f, 0.f, 0.f, 0.f, 0.f, 0.f, 0.f};
  if (sec == 0) {
    for (int e = 0; e < 20; ++e) {
      const float w = gb[e];
#pragma unroll
      for (int j = 0; j < 8; ++j) acc[j] += w * bf2f(lds[e][h0 + j]);
    }
  } else {
    const int goff = 20 + (sec - 1) * 12;
    const int ebase = 8 + (sec - 1) * 4;
    for (int tt = 0; tt < 4; ++tt) {
      const float w = gb[goff + tt];
#pragma unroll
      for (int j = 0; j < 8; ++j) acc[j] += w * bf2f(lds[ebase + tt][h0 + j]);
    }
    for (int ss = 0; ss < 8; ++ss) {
      const float w = gb[goff + 4 + ss];
#pragma unroll
      for (int j = 0; j < 8; ++j) acc[j] += w * bf2f(lds[ss][h0 + j]);
    }
  }
  unsigned short* ob = tin + (size_t)b * 2048 + sec * 512 + h0;
  ushort4 u0 = make_ushort4(f2bf(acc[0]), f2bf(acc[1]), f2bf(acc[2]), f2bf(acc[3]));
  ushort4 u1 = make_ushort4(f2bf(acc[4]), f2bf(acc[5]), f2bf(acc[6]), f2bf(acc[7]));
  *(ushort4*)ob = u0;
  *(ushort4*)(ob + 4) = u1;
}

// ---------------------------------------------------------------------------
// final dense: wave per (b, task); out0=[8192][6] then out1=[8192][4] flat fp32
// ---------------------------------------------------------------------------
__global__ __launch_bounds__(256) void outd_k(
    const unsigned short* __restrict__ t2,   // [2][8192][512]
    const float* __restrict__ Wd0, const float* __restrict__ bd0,
    const float* __restrict__ Wd1, const float* __restrict__ bd1,
    float* __restrict__ out)
{
  const int gid = blockIdx.x * 4 + (threadIdx.x >> 6);
  const int lane = threadIdx.x & 63;
  const int b = gid >> 1, task = gid & 1;
  const uint4 raw = *(const uint4*)(t2 + ((size_t)task * 8192 + b) * 512 + lane * 8);
  const unsigned short* rs = (const unsigned short*)&raw;
  float v[8];
#pragma unroll
  for (int j = 0; j < 8; ++j) v[j] = bf2f(rs[j]);
  const float* Wd = task ? Wd1 : Wd0;
  const float* bd = task ? bd1 : bd0;
  const int ncol = task ? 4 : 6;
  float* ob = task ? (out + (size_t)8192 * 6 + (size_t)b * 4) : (out + (size_t)b * 6);
  for (int c = 0; c < ncol; ++c) {
    float p = 0.f;
#pragma unroll
    for (int j = 0; j < 8; ++j) p += v[j] * Wd[(size_t)(lane * 8 + j) * ncol + c];
#pragma unroll
    for (int o = 32; o; o >>= 1) p += __shfl_xor(p, o);
    if (lane == 0) ob[c] = p + bd[c];
  }
}

// ---------------------------------------------------------------------------
extern "C" void kernel_launch(void* const* d_in, const int* in_sizes, int n_in,
                              void* d_out, int out_size, void* d_ws, size_t ws_size,
                              hipStream_t stream) {
  const float* x     = (const float*)d_in[0];
  const float* W1    = (const float*)d_in[1];
  const float* b1    = (const float*)d_in[2];
  const float* W2    = (const float*)d_in[3];
  const float* b2    = (const float*)d_in[4];
  const float* W3    = (const float*)d_in[5];
  const float* b3    = (const float*)d_in[6];
  const float* Wg_sh = (const float*)d_in[7];
  const float* bg_sh = (const float*)d_in[8];
  const float* Wg_sa = (const float*)d_in[9];
  const float* bg_sa = (const float*)d_in[10];
  const float* Wg_ra = (const float*)d_in[11];
  const float* bg_ra = (const float*)d_in[12];
  const float* Wg_ea = (const float*)d_in[13];
  const float* bg_ea = (const float*)d_in[14];
  const float* Wt1   = (const float*)d_in[15];
  const float* bt1   = (const float*)d_in[16];
  const float* Wt2   = (const float*)d_in[17];
  const float* bt2   = (const float*)d_in[18];
  const float* Wd0   = (const float*)d_in[19];
  const float* bd0   = (const float*)d_in[20];
  const float* Wd1   = (const float*)d_in[21];
  const float* bd1   = (const float*)d_in[22];
  float* out = (float*)d_out;

  const int B = 8192, D = 1024, H1 = 2048, H2 = 1024, H3 = 512;
  const int E = 20, TU1 = 1024, TU2 = 512, TIN = 2048;

  char* w = (char*)d_ws;
  auto alloc = [&](size_t n) { char* p = w; w += (n + 255) & ~(size_t)255; return p; };
  unsigned short* xb   = (unsigned short*)alloc((size_t)B * D * 2);
  unsigned short* W1t  = (unsigned short*)alloc((size_t)E * H1 * D * 2);
  unsigned short* W2t  = (unsigned short*)alloc((size_t)E * H2 * H1 * 2);
  unsigned short* W3t  = (unsigned short*)alloc((size_t)E * H3 * H2 * 2);
  unsigned short* Wt1t = (unsigned short*)alloc((size_t)2 * TU1 * TIN * 2);
  unsigned short* Wt2t = (unsigned short*)alloc((size_t)2 * TU2 * TU1 * 2);
  unsigned short* h1   = (unsigned short*)alloc((size_t)B * H1 * 2);
  unsigned short* h2   = (unsigned short*)alloc((size_t)B * H2 * 2);
  unsigned short* eo   = (unsigned short*)alloc((size_t)E * B * H3 * 2);
  float*          gts  = (float*)alloc((size_t)B * 56 * 4);
  unsigned short* tin  = (unsigned short*)alloc((size_t)B * TIN * 2);
  unsigned short* t1   = (unsigned short*)alloc((size_t)2 * B * TU1 * 2);
  unsigned short* t2   = (unsigned short*)alloc((size_t)2 * B * TU2 * 2);
  (void)ws_size; (void)in_sizes; (void)n_in; (void)out_size;

  // conversions
  conv_x<<<dim3((B * D / 8) / 256), 256, 0, stream>>>(x, xb, B * D / 8);
  conv_t<<<dim3(D / 64,  H1 / 64, E), 256, 0, stream>>>(W1, W1t, D, H1);
  conv_t<<<dim3(H1 / 64, H2 / 64, E), 256, 0, stream>>>(W2, W2t, H1, H2);
  conv_t<<<dim3(H2 / 64, H3 / 64, E), 256, 0, stream>>>(W3, W3t, H2, H3);
  conv_t<<<dim3(TIN / 64, TU1 / 64, 2), 256, 0, stream>>>(Wt1, Wt1t, TIN, TU1);
  conv_t<<<dim3(TU1 / 64, TU2 / 64, 2), 256, 0, stream>>>(Wt2, Wt2t, TU1, TU2);

  gates_k<<<dim3(B), 64, 0, stream>>>(x, Wg_sh, bg_sh, Wg_sa, bg_sa,
                                      Wg_ra, bg_ra, Wg_ea, bg_ea, gts);

  // experts
  for (int e = 0; e < E; ++e) {
    gemm_bl<<<dim3(H1 / 128, B / 128, 1), 256, 0, stream>>>(
        xb, W1t + (size_t)e * H1 * D, b1 + (size_t)e * H1, h1,
        B, H1, D, 0, 0, 0, 0);
    gemm_bl<<<dim3(H2 / 128, B / 128, 1), 256, 0, stream>>>(
        h1, W2t + (size_t)e * H2 * H1, b2 + (size_t)e * H2, h2,
        B, H2, H1, 0, 0, 0, 0);
    gemm_bl<<<dim3(H3 / 128, B / 128, 1), 256, 0, stream>>>(
        h2, W3t + (size_t)e * H3 * H2, b3 + (size_t)e * H3, eo + (size_t)e * B * H3,
        B, H3, H2, 0, 0, 0, 0);
  }

  combine_k<<<dim3(B), 256, 0, stream>>>(eo, gts, tin);

  // towers (batched over z = task)
  gemm_bl<<<dim3(TU1 / 128, B / 128, 2), 256, 0, stream>>>(
      tin, Wt1t, bt1, t1, B, TU1, TIN,
      0, (long)TU1 * TIN, (long)TU1, (long)B * TU1);
  gemm_bl<<<dim3(TU2 / 128, B / 128, 2), 256, 0, stream>>>(
      t1, Wt2t, bt2, t2, B, TU2, TU1,
      (long)B * TU1, (long)TU2 * TU1, (long)TU2, (long)B * TU2);

  outd_k<<<dim3(B * 2 / 4), 256, 0, stream>>>(t2, Wd0, bd0, Wd1, bd1, out);
}

// Round 3
// 2940.750 us; speedup vs baseline: 1.2475x; 1.2475x over previous
//
#include <hip/hip_runtime.h>

#define DEV __device__ __forceinline__

typedef __bf16 bf16x8 __attribute__((ext_vector_type(8)));
typedef float f32x4 __attribute__((ext_vector_type(4)));

DEV unsigned short f2bf(float f) {
  union { float f; unsigned u; } v; v.f = f;
  unsigned r = v.u + 0x7FFFu + ((v.u >> 16) & 1u);
  return (unsigned short)(r >> 16);
}
DEV float bf2f(unsigned short h) {
  union { float f; unsigned u; } v; v.u = ((unsigned)h) << 16;
  return v.f;
}

// async global->LDS, 16B per lane.
DEV void gload16(const void* g, void* l) {
  __builtin_amdgcn_global_load_lds(
      (__attribute__((address_space(1))) void*)(g),
      (__attribute__((address_space(3))) void*)(l), 16, 0, 0);
}

// ---------------------------------------------------------------------------
// GEMM: out[M][N] = lrelu(A[M][K] @ Bt[N][K]^T + bias[N]), bf16 in/out,
// fp32 accum via v_mfma_f32_16x16x32_bf16. BM=BN=128, BK=64, 256 thr.
// LDS tiles XOR-swizzled via pre-swizzled global source (rule #21).
// Per-z strides allow batching experts/towers on grid.z.
// ---------------------------------------------------------------------------
__global__ __launch_bounds__(256) void gemm_bl(
    const unsigned short* __restrict__ A,
    const unsigned short* __restrict__ Bt,
    const float* __restrict__ bias,
    unsigned short* __restrict__ Out,
    int M, int N, int K,
    long sA, long sB, long sBias, long sOut)
{
  A    += (size_t)blockIdx.z * sA;
  Bt   += (size_t)blockIdx.z * sB;
  bias += (size_t)blockIdx.z * sBias;
  Out  += (size_t)blockIdx.z * sOut;

  const int tid  = threadIdx.x;
  const int lane = tid & 63;
  const int wid  = tid >> 6;
  const int wm   = wid >> 1, wn = wid & 1;
  const int m0   = blockIdx.y * 128, n0 = blockIdx.x * 128;

  __shared__ alignas(16) char smA[16384];
  __shared__ alignas(16) char smB[16384];

  f32x4 acc[4][4];
  const f32x4 fz = {0.f, 0.f, 0.f, 0.f};
#pragma unroll
  for (int i = 0; i < 4; ++i)
#pragma unroll
    for (int j = 0; j < 4; ++j) acc[i][j] = fz;

  const size_t ldab = (size_t)K * 2;
  const int rr    = tid >> 3;
  const int chunk = (tid & 7) ^ (rr & 7);
  const char* gA = (const char*)A  + (size_t)(m0 + rr) * ldab + chunk * 16;
  const char* gB = (const char*)Bt + (size_t)(n0 + rr) * ldab + chunk * 16;
  char* lA = smA + tid * 16;
  char* lB = smB + tid * 16;
  const size_t rowStep = 32 * ldab;

  const int swz = (lane & 7) << 4;
  int aoff[4][2], boff[4][2];
#pragma unroll
  for (int f = 0; f < 4; ++f) {
    const int ra = wm * 64 + f * 16 + (lane & 15);
    const int rb = wn * 64 + f * 16 + (lane & 15);
#pragma unroll
    for (int ks = 0; ks < 2; ++ks) {
      const int kb = ks * 64 + ((lane >> 4) << 4);
      aoff[f][ks] = ra * 128 + (kb ^ swz);
      boff[f][ks] = rb * 128 + (kb ^ swz);
    }
  }

  const int nkt = K >> 6;
  for (int kt = 0; kt < nkt; ++kt) {
    const char* sa = gA + (size_t)kt * 128;
    const char* sb = gB + (size_t)kt * 128;
    gload16(sa,               lA);
    gload16(sa +     rowStep, lA + 4096);
    gload16(sa + 2 * rowStep, lA + 8192);
    gload16(sa + 3 * rowStep, lA + 12288);
    gload16(sb,               lB);
    gload16(sb +     rowStep, lB + 4096);
    gload16(sb + 2 * rowStep, lB + 8192);
    gload16(sb + 3 * rowStep, lB + 12288);
    __syncthreads();
#pragma unroll
    for (int ks = 0; ks < 2; ++ks) {
      bf16x8 af[4], bf[4];
#pragma unroll
      for (int f = 0; f < 4; ++f) af[f] = *(const bf16x8*)(smA + aoff[f][ks]);
#pragma unroll
      for (int f = 0; f < 4; ++f) bf[f] = *(const bf16x8*)(smB + boff[f][ks]);
#pragma unroll
      for (int mi = 0; mi < 4; ++mi)
#pragma unroll
        for (int ni = 0; ni < 4; ++ni)
          acc[mi][ni] = __builtin_amdgcn_mfma_f32_16x16x32_bf16(
              af[mi], bf[ni], acc[mi][ni], 0, 0, 0);
    }
    __syncthreads();
  }

#pragma unroll
  for (int ni = 0; ni < 4; ++ni) {
    const int c = n0 + wn * 64 + ni * 16 + (lane & 15);
    const float bv = bias[c];
#pragma unroll
    for (int mi = 0; mi < 4; ++mi) {
#pragma unroll
      for (int j = 0; j < 4; ++j) {
        const int r = m0 + wm * 64 + mi * 16 + ((lane >> 4) << 2) + j;
        float v = acc[mi][ni][j] + bv;
        v = v >= 0.f ? v : 0.1f * v;
        Out[(size_t)r * N + c] = f2bf(v);
      }
    }
  }
}

// ---------------------------------------------------------------------------
// fp32 [K][N] -> bf16 [N][K] (per-z slab), LDS-tiled transpose
// ---------------------------------------------------------------------------
__global__ __launch_bounds__(256) void conv_t(
    const float* __restrict__ src, unsigned short* __restrict__ dst, int K, int N)
{
  const size_t zo = (size_t)blockIdx.z * K * N;
  src += zo; dst += zo;
  const int k0 = blockIdx.x * 64, n0 = blockIdx.y * 64;
  __shared__ unsigned short lds[64][68];
  const int t = threadIdx.x;
  const int cr = t >> 4;
  const int cc = (t & 15) * 4;
#pragma unroll
  for (int i = 0; i < 4; ++i) {
    const int row = i * 16 + cr;
    const float4 v = *(const float4*)(src + (size_t)(k0 + row) * N + n0 + cc);
    lds[row][cc + 0] = f2bf(v.x); lds[row][cc + 1] = f2bf(v.y);
    lds[row][cc + 2] = f2bf(v.z); lds[row][cc + 3] = f2bf(v.w);
  }
  __syncthreads();
#pragma unroll
  for (int i = 0; i < 4; ++i) {
    const int nrow = i * 16 + cr;
    ushort4 u = make_ushort4(lds[cc + 0][nrow], lds[cc + 1][nrow],
                             lds[cc + 2][nrow], lds[cc + 3][nrow]);
    *(ushort4*)(dst + (size_t)(n0 + nrow) * K + k0 + cc) = u;
  }
}

// fp32 -> bf16, 8 elements/thread
__global__ __launch_bounds__(256) void conv_x(
    const float* __restrict__ src, unsigned short* __restrict__ dst, int n8)
{
  const int i = blockIdx.x * 256 + threadIdx.x;
  if (i >= n8) return;
  const float4* p = (const float4*)(src + (size_t)i * 8);
  const float4 a = p[0], b = p[1];
  ushort4 u0 = make_ushort4(f2bf(a.x), f2bf(a.y), f2bf(a.z), f2bf(a.w));
  ushort4 u1 = make_ushort4(f2bf(b.x), f2bf(b.y), f2bf(b.z), f2bf(b.w));
  *(ushort4*)(dst + (size_t)i * 8)     = u0;
  *(ushort4*)(dst + (size_t)i * 8 + 4) = u1;
}

// ---------------------------------------------------------------------------
// concat gate weights -> Wcat fp32 [1024][56] (col order: sh20|sa12|ra12|ea12)
// and bcat[64] (padded with zeros)
// ---------------------------------------------------------------------------
__global__ __launch_bounds__(256) void concat_g(
    const float* __restrict__ Wsh, const float* __restrict__ bsh,
    const float* __restrict__ Wsa, const float* __restrict__ bsa,
    const float* __restrict__ Wra, const float* __restrict__ bra,
    const float* __restrict__ Wea, const float* __restrict__ bea,
    float* __restrict__ Wc, float* __restrict__ bc)
{
  const int i = blockIdx.x * 256 + threadIdx.x;
  if (i < 1024 * 56) {
    const int k = i / 56, c = i % 56;
    float v;
    if (c < 20)      v = Wsh[(size_t)k * 20 + c];
    else if (c < 32) v = Wsa[(size_t)k * 12 + (c - 20)];
    else if (c < 44) v = Wra[(size_t)k * 12 + (c - 32)];
    else             v = Wea[(size_t)k * 12 + (c - 44)];
    Wc[i] = v;
  }
  if (i < 64) {
    float v = 0.f;
    if (i < 20)      v = bsh[i];
    else if (i < 32) v = bsa[i - 20];
    else if (i < 44) v = bra[i - 32];
    else if (i < 56) v = bea[i - 44];
    bc[i] = v;
  }
}

// ---------------------------------------------------------------------------
// gates logits: fp32 micro-GEMM  logits[B][64] = x[B][1024] @ Wcat[1024][56] + bcat
// block: 64 rows x 64 cols (56 real), 256 thr = 16x16, 4x4 outputs/thread
// W-tile staging: 512 chunks, 2 per thread (FIXED: was written for 512 threads)
// ---------------------------------------------------------------------------
__global__ __launch_bounds__(256) void gates_gemm(
    const float* __restrict__ x,
    const float* __restrict__ Wc,
    const float* __restrict__ bc,
    float* __restrict__ logits)
{
  const int b0 = blockIdx.x * 64;
  const int t = threadIdx.x;
  const int tr = t >> 4, tc = t & 15;
  __shared__ float sx[32][64];   // [k][row]
  __shared__ float sw[32][64];   // [k][col], cols 56..63 zero

  float acc[4][4] = {};

  for (int kt = 0; kt < 32; ++kt) {
    const int k0 = kt * 32;
    __syncthreads();
#pragma unroll
    for (int it = 0; it < 2; ++it) {
      const int idx = t + it * 256;
      const int r = idx >> 3, c4 = (idx & 7) * 4;
      const float4 v = *(const float4*)(x + (size_t)(b0 + r) * 1024 + k0 + c4);
      sx[c4 + 0][r] = v.x; sx[c4 + 1][r] = v.y;
      sx[c4 + 2][r] = v.z; sx[c4 + 3][r] = v.w;
    }
#pragma unroll
    for (int it = 0; it < 2; ++it) {
      const int idx = t + it * 256;           // 0..511
      const int row = idx >> 4;               // 0..31
      const int c4  = (idx & 15) * 4;         // 0..60
      float4 v = {0.f, 0.f, 0.f, 0.f};
      if (c4 < 56)                            // c4=52 reads cols 52..55, in-bounds
        v = *(const float4*)(Wc + (size_t)(k0 + row) * 56 + c4);
      *(float4*)&sw[row][c4] = v;
    }
    __syncthreads();
#pragma unroll
    for (int kk = 0; kk < 32; ++kk) {
      const float4 rx = *(const float4*)&sx[kk][tr * 4];
      const float4 wv = *(const float4*)&sw[kk][tc * 4];
#pragma unroll
      for (int i = 0; i < 4; ++i) {
        const float xv = (i == 0) ? rx.x : (i == 1) ? rx.y : (i == 2) ? rx.z : rx.w;
        acc[i][0] += xv * wv.x; acc[i][1] += xv * wv.y;
        acc[i][2] += xv * wv.z; acc[i][3] += xv * wv.w;
      }
    }
  }

  const float4 bv = *(const float4*)&bc[tc * 4];
#pragma unroll
  for (int i = 0; i < 4; ++i) {
    float4 o;
    o.x = acc[i][0] + bv.x; o.y = acc[i][1] + bv.y;
    o.z = acc[i][2] + bv.z; o.w = acc[i][3] + bv.w;
    *(float4*)&logits[(size_t)(b0 + tr * 4 + i) * 64 + tc * 4] = o;
  }
}

// ---------------------------------------------------------------------------
// combine: softmax over logits (inline, wave 0) + gate-weighted expert sums
// sections: 0=shared-gate(20), 1=SA, 2=RA, 3=EA (4 task + 8 shared each)
// ---------------------------------------------------------------------------
__global__ __launch_bounds__(256) void combine_k(
    const unsigned short* __restrict__ eo,   // [20][8192][512]
    const float* __restrict__ logits,        // [8192][64]
    unsigned short* __restrict__ tin)        // [8192][2048]
{
  const int b = blockIdx.x;
  const int t = threadIdx.x;
  __shared__ alignas(16) unsigned short lds[20][512];
  __shared__ float gsm[56];
#pragma unroll
  for (int i = 0; i < 5; ++i) {
    const int chunk = t + i * 256;
    const int e = chunk >> 6;
    const int h0 = (chunk & 63) * 8;
    *(uint4*)&lds[e][h0] = *(const uint4*)(eo + ((size_t)e * 8192 + b) * 512 + h0);
  }
  if (t < 64) {
    const float v0 = (t < 56) ? logits[(size_t)b * 64 + t] : 0.f;
    const int off[4] = {0, 20, 32, 44};
    const int wd[4]  = {20, 12, 12, 12};
    for (int g = 0; g < 4; ++g) {
      const bool in = (t >= off[g]) && (t < off[g] + wd[g]);
      float vv = in ? v0 : -1e30f;
      float m = vv;
#pragma unroll
      for (int o = 32; o; o >>= 1) m = fmaxf(m, __shfl_xor(m, o));
      float e = in ? __expf(vv - m) : 0.f;
      float s = e;
#pragma unroll
      for (int o = 32; o; o >>= 1) s += __shfl_xor(s, o);
      if (in) gsm[t] = e / s;
    }
  }
  __syncthreads();

  const int sec = t >> 6;
  const int h0 = (t & 63) * 8;
  float acc[8] = {0.f, 0.f, 0.f, 0.f, 0.f, 0.f, 0.f, 0.f};
  if (sec == 0) {
    for (int e = 0; e < 20; ++e) {
      const float w = gsm[e];
#pragma unroll
      for (int j = 0; j < 8; ++j) acc[j] += w * bf2f(lds[e][h0 + j]);
    }
  } else {
    const int goff = 20 + (sec - 1) * 12;
    const int ebase = 8 + (sec - 1) * 4;
    for (int tt = 0; tt < 4; ++tt) {
      const float w = gsm[goff + tt];
#pragma unroll
      for (int j = 0; j < 8; ++j) acc[j] += w * bf2f(lds[ebase + tt][h0 + j]);
    }
    for (int ss = 0; ss < 8; ++ss) {
      const float w = gsm[goff + 4 + ss];
#pragma unroll
      for (int j = 0; j < 8; ++j) acc[j] += w * bf2f(lds[ss][h0 + j]);
    }
  }
  unsigned short* ob = tin + (size_t)b * 2048 + sec * 512 + h0;
  ushort4 u0 = make_ushort4(f2bf(acc[0]), f2bf(acc[1]), f2bf(acc[2]), f2bf(acc[3]));
  ushort4 u1 = make_ushort4(f2bf(acc[4]), f2bf(acc[5]), f2bf(acc[6]), f2bf(acc[7]));
  *(ushort4*)ob = u0;
  *(ushort4*)(ob + 4) = u1;
}

// ---------------------------------------------------------------------------
// final dense: wave per (b, task); out0=[8192][6] then out1=[8192][4] flat fp32
// ---------------------------------------------------------------------------
__global__ __launch_bounds__(256) void outd_k(
    const unsigned short* __restrict__ t2,   // [2][8192][512]
    const float* __restrict__ Wd0, const float* __restrict__ bd0,
    const float* __restrict__ Wd1, const float* __restrict__ bd1,
    float* __restrict__ out)
{
  const int gid = blockIdx.x * 4 + (threadIdx.x >> 6);
  const int lane = threadIdx.x & 63;
  const int b = gid >> 1, task = gid & 1;
  const uint4 raw = *(const uint4*)(t2 + ((size_t)task * 8192 + b) * 512 + lane * 8);
  const unsigned short* rs = (const unsigned short*)&raw;
  float v[8];
#pragma unroll
  for (int j = 0; j < 8; ++j) v[j] = bf2f(rs[j]);
  const float* Wd = task ? Wd1 : Wd0;
  const float* bd = task ? bd1 : bd0;
  const int ncol = task ? 4 : 6;
  float* ob = task ? (out + (size_t)8192 * 6 + (size_t)b * 4) : (out + (size_t)b * 6);
  for (int c = 0; c < ncol; ++c) {
    float p = 0.f;
#pragma unroll
    for (int j = 0; j < 8; ++j) p += v[j] * Wd[(size_t)(lane * 8 + j) * ncol + c];
#pragma unroll
    for (int o = 32; o; o >>= 1) p += __shfl_xor(p, o);
    if (lane == 0) ob[c] = p + bd[c];
  }
}

// ---------------------------------------------------------------------------
extern "C" void kernel_launch(void* const* d_in, const int* in_sizes, int n_in,
                              void* d_out, int out_size, void* d_ws, size_t ws_size,
                              hipStream_t stream) {
  const float* x     = (const float*)d_in[0];
  const float* W1    = (const float*)d_in[1];
  const float* b1    = (const float*)d_in[2];
  const float* W2    = (const float*)d_in[3];
  const float* b2    = (const float*)d_in[4];
  const float* W3    = (const float*)d_in[5];
  const float* b3    = (const float*)d_in[6];
  const float* Wg_sh = (const float*)d_in[7];
  const float* bg_sh = (const float*)d_in[8];
  const float* Wg_sa = (const float*)d_in[9];
  const float* bg_sa = (const float*)d_in[10];
  const float* Wg_ra = (const float*)d_in[11];
  const float* bg_ra = (const float*)d_in[12];
  const float* Wg_ea = (const float*)d_in[13];
  const float* bg_ea = (const float*)d_in[14];
  const float* Wt1   = (const float*)d_in[15];
  const float* bt1   = (const float*)d_in[16];
  const float* Wt2   = (const float*)d_in[17];
  const float* bt2   = (const float*)d_in[18];
  const float* Wd0   = (const float*)d_in[19];
  const float* bd0   = (const float*)d_in[20];
  const float* Wd1   = (const float*)d_in[21];
  const float* bd1   = (const float*)d_in[22];
  float* out = (float*)d_out;

  const int B = 8192, D = 1024, H1 = 2048, H2 = 1024, H3 = 512;
  const int E = 20, TU1 = 1024, TU2 = 512, TIN = 2048;

  auto rnd = [](size_t n) { return (n + 255) & ~(size_t)255; };
  const size_t szXb   = rnd((size_t)B * D * 2);
  const size_t szW1t  = rnd((size_t)E * H1 * D * 2);
  const size_t szW2t  = rnd((size_t)E * H2 * H1 * 2);
  const size_t szW3t  = rnd((size_t)E * H3 * H2 * 2);
  const size_t szWt1t = rnd((size_t)2 * TU1 * TIN * 2);
  const size_t szWt2t = rnd((size_t)2 * TU2 * TU1 * 2);
  const size_t szWcat = rnd((size_t)1024 * 56 * 4);
  const size_t szBcat = rnd((size_t)64 * 4);
  const size_t szLog  = rnd((size_t)B * 64 * 4);
  const size_t szEo   = rnd((size_t)E * B * H3 * 2);
  const size_t szTin  = rnd((size_t)B * TIN * 2);
  const size_t szT1   = rnd((size_t)2 * B * TU1 * 2);
  const size_t szT2   = rnd((size_t)2 * B * TU2 * 2);
  const size_t fixed = szXb + szW1t + szW2t + szW3t + szWt1t + szWt2t +
                       szWcat + szBcat + szLog + szEo + szTin + szT1 + szT2;

  // pick the largest expert-batch G (divisor of 20) whose h1/h2 fit
  int G = 1;
  const int opts[6] = {20, 10, 5, 4, 2, 1};
  for (int i = 0; i < 6; ++i) {
    const size_t need = fixed + rnd((size_t)opts[i] * B * H1 * 2)
                              + rnd((size_t)opts[i] * B * H2 * 2);
    if (need <= ws_size) { G = opts[i]; break; }
  }

  char* w = (char*)d_ws;
  auto alloc = [&](size_t n) { char* p = w; w += rnd(n); return p; };
  unsigned short* xb   = (unsigned short*)alloc((size_t)B * D * 2);
  unsigned short* W1t  = (unsigned short*)alloc((size_t)E * H1 * D * 2);
  unsigned short* W2t  = (unsigned short*)alloc((size_t)E * H2 * H1 * 2);
  unsigned short* W3t  = (unsigned short*)alloc((size_t)E * H3 * H2 * 2);
  unsigned short* Wt1t = (unsigned short*)alloc((size_t)2 * TU1 * TIN * 2);
  unsigned short* Wt2t = (unsigned short*)alloc((size_t)2 * TU2 * TU1 * 2);
  float*          Wcat = (float*)alloc((size_t)1024 * 56 * 4);
  float*          bcat = (float*)alloc((size_t)64 * 4);
  float*          lgts = (float*)alloc((size_t)B * 64 * 4);
  unsigned short* eo   = (unsigned short*)alloc((size_t)E * B * H3 * 2);
  unsigned short* tin  = (unsigned short*)alloc((size_t)B * TIN * 2);
  unsigned short* t1   = (unsigned short*)alloc((size_t)2 * B * TU1 * 2);
  unsigned short* t2   = (unsigned short*)alloc((size_t)2 * B * TU2 * 2);
  unsigned short* h1   = (unsigned short*)alloc((size_t)G * B * H1 * 2);
  unsigned short* h2   = (unsigned short*)alloc((size_t)G * B * H2 * 2);
  (void)in_sizes; (void)n_in; (void)out_size;

  // conversions
  conv_x<<<dim3((B * D / 8) / 256), 256, 0, stream>>>(x, xb, B * D / 8);
  conv_t<<<dim3(D / 64,  H1 / 64, E), 256, 0, stream>>>(W1, W1t, D, H1);
  conv_t<<<dim3(H1 / 64, H2 / 64, E), 256, 0, stream>>>(W2, W2t, H1, H2);
  conv_t<<<dim3(H2 / 64, H3 / 64, E), 256, 0, stream>>>(W3, W3t, H2, H3);
  conv_t<<<dim3(TIN / 64, TU1 / 64, 2), 256, 0, stream>>>(Wt1, Wt1t, TIN, TU1);
  conv_t<<<dim3(TU1 / 64, TU2 / 64, 2), 256, 0, stream>>>(Wt2, Wt2t, TU1, TU2);

  // gates: concat -> fp32 micro-GEMM (softmax folded into combine_k)
  concat_g<<<dim3((1024 * 56 + 255) / 256), 256, 0, stream>>>(
      Wg_sh, bg_sh, Wg_sa, bg_sa, Wg_ra, bg_ra, Wg_ea, bg_ea, Wcat, bcat);
  gates_gemm<<<dim3(B / 64), 256, 0, stream>>>(x, Wcat, bcat, lgts);

  // experts, batched over grid.z in groups of G
  for (int e0 = 0; e0 < E; e0 += G) {
    gemm_bl<<<dim3(H1 / 128, B / 128, G), 256, 0, stream>>>(
        xb, W1t + (size_t)e0 * H1 * D, b1 + (size_t)e0 * H1, h1,
        B, H1, D, 0, (long)H1 * D, (long)H1, (long)B * H1);
    gemm_bl<<<dim3(H2 / 128, B / 128, G), 256, 0, stream>>>(
        h1, W2t + (size_t)e0 * H2 * H1, b2 + (size_t)e0 * H2, h2,
        B, H2, H1, (long)B * H1, (long)H2 * H1, (long)H2, (long)B * H2);
    gemm_bl<<<dim3(H3 / 128, B / 128, G), 256, 0, stream>>>(
        h2, W3t + (size_t)e0 * H3 * H2, b3 + (size_t)e0 * H3,
        eo + (size_t)e0 * B * H3,
        B, H3, H2, (long)B * H2, (long)H3 * H2, (long)H3, (long)B * H3);
  }

  combine_k<<<dim3(B), 256, 0, stream>>>(eo, lgts, tin);

  // towers (batched over z = task)
  gemm_bl<<<dim3(TU1 / 128, B / 128, 2), 256, 0, stream>>>(
      tin, Wt1t, bt1, t1, B, TU1, TIN,
      0, (long)TU1 * TIN, (long)TU1, (long)B * TU1);
  gemm_bl<<<dim3(TU2 / 128, B / 128, 2), 256, 0, stream>>>(
      t1, Wt2t, bt2, t2, B, TU2, TU1,
      (long)B * TU1, (long)TU2 * TU1, (long)TU2, (long)B * TU2);

  outd_k<<<dim3(B * 2 / 4), 256, 0, stream>>>(t2, Wd0, bd0, Wd1, bd1, out);
}

// Round 4
// 2339.410 us; speedup vs baseline: 1.5681x; 1.2570x over previous
//
#include <hip/hip_runtime.h>

#define DEV __device__ __forceinline__

typedef __bf16 bf16x8 __attribute__((ext_vector_type(8)));
typedef float f32x4 __attribute__((ext_vector_type(4)));

DEV unsigned short f2bf(float f) {
  union { float f; unsigned u; } v; v.f = f;
  unsigned r = v.u + 0x7FFFu + ((v.u >> 16) & 1u);
  return (unsigned short)(r >> 16);
}
DEV float bf2f(unsigned short h) {
  union { float f; unsigned u; } v; v.u = ((unsigned)h) << 16;
  return v.f;
}

// async global->LDS, 16B per lane.
DEV void gload16(const void* g, void* l) {
  __builtin_amdgcn_global_load_lds(
      (__attribute__((address_space(1))) void*)(g),
      (__attribute__((address_space(3))) void*)(l), 16, 0, 0);
}

// ---------------------------------------------------------------------------
// gemm256: out[M][N] = lrelu(A[M][K] @ Bt[N][K]^T + bias[N]), bf16 in/out.
// 256x256 tile, BK=64, 512 thr (8 waves 2Mx4N, each 128x64 out).
// Explicit LDS double-buffer + counted vmcnt(8) + raw s_barrier (T3+T4):
// next K-tile's global_load_lds stay in flight across the barrier.
// XOR-swizzled LDS via pre-swizzled global source (both-sides, rule #21).
// 1D grid with bijective XCD-chunked swizzle (T1). Requires M%256==0, N%256==0,
// K%64==0.
// ---------------------------------------------------------------------------
__global__ __launch_bounds__(512) void gemm256(
    const unsigned short* __restrict__ A,
    const unsigned short* __restrict__ Bt,
    const float* __restrict__ bias,
    unsigned short* __restrict__ Out,
    int N, int K, int nbx, int nby,
    long sA, long sB, long sBias, long sOut)
{
  // bijective chunked XCD swizzle (m204 form)
  int wg = blockIdx.x;
  {
    const int nwg = gridDim.x;
    const int q = nwg >> 3, r = nwg & 7;
    const int xcd = wg & 7, pos = wg >> 3;
    wg = (xcd < r ? xcd * (q + 1) : r * (q + 1) + (xcd - r) * q) + pos;
  }
  const int per_z = nbx * nby;
  const int z  = wg / per_z;
  const int rz = wg - z * per_z;
  const int by = rz / nbx;
  const int bx = rz - by * nbx;

  A    += (size_t)z * sA;
  Bt   += (size_t)z * sB;
  bias += (size_t)z * sBias;
  Out  += (size_t)z * sOut;

  const int tid  = threadIdx.x;
  const int lane = tid & 63;
  const int wid  = tid >> 6;
  const int wm   = wid >> 2, wn = wid & 3;   // 2 x 4 wave grid
  const int m0   = by * 256, n0 = bx * 256;

  __shared__ alignas(16) char sm[2][65536];  // per buf: A[256][128B] | B[256][128B]

  f32x4 acc[8][4];
  const f32x4 fz = {0.f, 0.f, 0.f, 0.f};
#pragma unroll
  for (int i = 0; i < 8; ++i)
#pragma unroll
    for (int j = 0; j < 4; ++j) acc[i][j] = fz;

  const size_t ldab = (size_t)K * 2;
  const int rr = tid >> 3;                   // 0..63
  const int ch = (tid & 7) ^ (rr & 7);       // pre-swizzled 16B chunk in 128B row
  const char* gA = (const char*)A  + (size_t)(m0 + rr) * ldab + ch * 16;
  const char* gB = (const char*)Bt + (size_t)(n0 + rr) * ldab + ch * 16;
  const size_t rowStep = 64 * ldab;

  // fragment read offsets: swizzle covers bits 4..6 of the 128B row
  const int swz   = (lane & 7) << 4;
  const int kbase = (lane >> 4) << 4;        // 0,16,32,48
  const int koff0 = kbase ^ swz;             // ks=0 byte offset in row
  const int aRow  = wm * 128 + (lane & 15);
  const int bRow  = wn * 64  + (lane & 15);

  const int nkt = K >> 6;

  auto STAGE = [&](int buf, int kt) {
    const char* sa = gA + (size_t)kt * 128;
    const char* sb = gB + (size_t)kt * 128;
    char* la = sm[buf] + tid * 16;
    char* lb = sm[buf] + 32768 + tid * 16;
#pragma unroll
    for (int j = 0; j < 4; ++j) {
      gload16(sa + j * rowStep, la + j * 8192);
      gload16(sb + j * rowStep, lb + j * 8192);
    }
  };

  STAGE(0, 0);
  int cur = 0;
  for (int kt = 0; kt < nkt; ++kt) {
    if (kt + 1 < nkt) {
      STAGE(cur ^ 1, kt + 1);
      asm volatile("s_waitcnt vmcnt(8)" ::: "memory");  // tile kt landed; 8 in flight
    } else {
      asm volatile("s_waitcnt vmcnt(0)" ::: "memory");
    }
    __builtin_amdgcn_s_barrier();            // raw: no vmcnt drain
    __builtin_amdgcn_sched_barrier(0);
    const char* pA = sm[cur] + aRow * 128;
    const char* pB = sm[cur] + 32768 + bRow * 128;
#pragma unroll
    for (int ks = 0; ks < 2; ++ks) {
      const int ko = koff0 ^ (ks * 64);
      bf16x8 af[8], bfr[4];
#pragma unroll
      for (int mi = 0; mi < 8; ++mi) af[mi] = *(const bf16x8*)(pA + mi * 2048 + ko);
#pragma unroll
      for (int ni = 0; ni < 4; ++ni) bfr[ni] = *(const bf16x8*)(pB + ni * 2048 + ko);
#pragma unroll
      for (int mi = 0; mi < 8; ++mi)
#pragma unroll
        for (int ni = 0; ni < 4; ++ni)
          acc[mi][ni] = __builtin_amdgcn_mfma_f32_16x16x32_bf16(
              af[mi], bfr[ni], acc[mi][ni], 0, 0, 0);
    }
    __builtin_amdgcn_sched_barrier(0);
    __builtin_amdgcn_s_barrier();            // all waves done reading buf[cur]
    cur ^= 1;
  }

  // epilogue: bias + lrelu + bf16 store (C/D: col=lane&15, row=(lane>>4)*4+j)
#pragma unroll
  for (int ni = 0; ni < 4; ++ni) {
    const int c = n0 + wn * 64 + ni * 16 + (lane & 15);
    const float bv = bias[c];
#pragma unroll
    for (int mi = 0; mi < 8; ++mi) {
      const int r0 = m0 + wm * 128 + mi * 16 + ((lane >> 4) << 2);
#pragma unroll
      for (int j = 0; j < 4; ++j) {
        float v = acc[mi][ni][j] + bv;
        v = v >= 0.f ? v : 0.1f * v;
        Out[(size_t)(r0 + j) * N + c] = f2bf(v);
      }
    }
  }
}

// ---------------------------------------------------------------------------
// gemm_bl: 128x128 tile fallback for small grids (proven round-3 kernel)
// ---------------------------------------------------------------------------
__global__ __launch_bounds__(256) void gemm_bl(
    const unsigned short* __restrict__ A,
    const unsigned short* __restrict__ Bt,
    const float* __restrict__ bias,
    unsigned short* __restrict__ Out,
    int M, int N, int K,
    long sA, long sB, long sBias, long sOut)
{
  A    += (size_t)blockIdx.z * sA;
  Bt   += (size_t)blockIdx.z * sB;
  bias += (size_t)blockIdx.z * sBias;
  Out  += (size_t)blockIdx.z * sOut;

  const int tid  = threadIdx.x;
  const int lane = tid & 63;
  const int wid  = tid >> 6;
  const int wm   = wid >> 1, wn = wid & 1;
  const int m0   = blockIdx.y * 128, n0 = blockIdx.x * 128;

  __shared__ alignas(16) char smA[16384];
  __shared__ alignas(16) char smB[16384];

  f32x4 acc[4][4];
  const f32x4 fz = {0.f, 0.f, 0.f, 0.f};
#pragma unroll
  for (int i = 0; i < 4; ++i)
#pragma unroll
    for (int j = 0; j < 4; ++j) acc[i][j] = fz;

  const size_t ldab = (size_t)K * 2;
  const int rr    = tid >> 3;
  const int chunk = (tid & 7) ^ (rr & 7);
  const char* gA = (const char*)A  + (size_t)(m0 + rr) * ldab + chunk * 16;
  const char* gB = (const char*)Bt + (size_t)(n0 + rr) * ldab + chunk * 16;
  char* lA = smA + tid * 16;
  char* lB = smB + tid * 16;
  const size_t rowStep = 32 * ldab;

  const int swz = (lane & 7) << 4;
  int aoff[4][2], boff[4][2];
#pragma unroll
  for (int f = 0; f < 4; ++f) {
    const int ra = wm * 64 + f * 16 + (lane & 15);
    const int rb = wn * 64 + f * 16 + (lane & 15);
#pragma unroll
    for (int ks = 0; ks < 2; ++ks) {
      const int kb = ks * 64 + ((lane >> 4) << 4);
      aoff[f][ks] = ra * 128 + (kb ^ swz);
      boff[f][ks] = rb * 128 + (kb ^ swz);
    }
  }

  const int nkt = K >> 6;
  for (int kt = 0; kt < nkt; ++kt) {
    const char* sa = gA + (size_t)kt * 128;
    const char* sb = gB + (size_t)kt * 128;
    gload16(sa,               lA);
    gload16(sa +     rowStep, lA + 4096);
    gload16(sa + 2 * rowStep, lA + 8192);
    gload16(sa + 3 * rowStep, lA + 12288);
    gload16(sb,               lB);
    gload16(sb +     rowStep, lB + 4096);
    gload16(sb + 2 * rowStep, lB + 8192);
    gload16(sb + 3 * rowStep, lB + 12288);
    __syncthreads();
#pragma unroll
    for (int ks = 0; ks < 2; ++ks) {
      bf16x8 af[4], bf[4];
#pragma unroll
      for (int f = 0; f < 4; ++f) af[f] = *(const bf16x8*)(smA + aoff[f][ks]);
#pragma unroll
      for (int f = 0; f < 4; ++f) bf[f] = *(const bf16x8*)(smB + boff[f][ks]);
#pragma unroll
      for (int mi = 0; mi < 4; ++mi)
#pragma unroll
        for (int ni = 0; ni < 4; ++ni)
          acc[mi][ni] = __builtin_amdgcn_mfma_f32_16x16x32_bf16(
              af[mi], bf[ni], acc[mi][ni], 0, 0, 0);
    }
    __syncthreads();
  }

#pragma unroll
  for (int ni = 0; ni < 4; ++ni) {
    const int c = n0 + wn * 64 + ni * 16 + (lane & 15);
    const float bv = bias[c];
#pragma unroll
    for (int mi = 0; mi < 4; ++mi) {
#pragma unroll
      for (int j = 0; j < 4; ++j) {
        const int r = m0 + wm * 64 + mi * 16 + ((lane >> 4) << 2) + j;
        float v = acc[mi][ni][j] + bv;
        v = v >= 0.f ? v : 0.1f * v;
        Out[(size_t)r * N + c] = f2bf(v);
      }
    }
  }
}

// ---------------------------------------------------------------------------
// fp32 [K][N] -> bf16 [N][K] (per-z slab), LDS-tiled transpose
// ---------------------------------------------------------------------------
__global__ __launch_bounds__(256) void conv_t(
    const float* __restrict__ src, unsigned short* __restrict__ dst, int K, int N)
{
  const size_t zo = (size_t)blockIdx.z * K * N;
  src += zo; dst += zo;
  const int k0 = blockIdx.x * 64, n0 = blockIdx.y * 64;
  __shared__ unsigned short lds[64][68];
  const int t = threadIdx.x;
  const int cr = t >> 4;
  const int cc = (t & 15) * 4;
#pragma unroll
  for (int i = 0; i < 4; ++i) {
    const int row = i * 16 + cr;
    const float4 v = *(const float4*)(src + (size_t)(k0 + row) * N + n0 + cc);
    lds[row][cc + 0] = f2bf(v.x); lds[row][cc + 1] = f2bf(v.y);
    lds[row][cc + 2] = f2bf(v.z); lds[row][cc + 3] = f2bf(v.w);
  }
  __syncthreads();
#pragma unroll
  for (int i = 0; i < 4; ++i) {
    const int nrow = i * 16 + cr;
    ushort4 u = make_ushort4(lds[cc + 0][nrow], lds[cc + 1][nrow],
                             lds[cc + 2][nrow], lds[cc + 3][nrow]);
    *(ushort4*)(dst + (size_t)(n0 + nrow) * K + k0 + cc) = u;
  }
}

// fp32 -> bf16, 8 elements/thread
__global__ __launch_bounds__(256) void conv_x(
    const float* __restrict__ src, unsigned short* __restrict__ dst, int n8)
{
  const int i = blockIdx.x * 256 + threadIdx.x;
  if (i >= n8) return;
  const float4* p = (const float4*)(src + (size_t)i * 8);
  const float4 a = p[0], b = p[1];
  ushort4 u0 = make_ushort4(f2bf(a.x), f2bf(a.y), f2bf(a.z), f2bf(a.w));
  ushort4 u1 = make_ushort4(f2bf(b.x), f2bf(b.y), f2bf(b.z), f2bf(b.w));
  *(ushort4*)(dst + (size_t)i * 8)     = u0;
  *(ushort4*)(dst + (size_t)i * 8 + 4) = u1;
}

// ---------------------------------------------------------------------------
// concat gate weights -> Wcat fp32 [1024][56] + bcat[64]
// ---------------------------------------------------------------------------
__global__ __launch_bounds__(256) void concat_g(
    const float* __restrict__ Wsh, const float* __restrict__ bsh,
    const float* __restrict__ Wsa, const float* __restrict__ bsa,
    const float* __restrict__ Wra, const float* __restrict__ bra,
    const float* __restrict__ Wea, const float* __restrict__ bea,
    float* __restrict__ Wc, float* __restrict__ bc)
{
  const int i = blockIdx.x * 256 + threadIdx.x;
  if (i < 1024 * 56) {
    const int k = i / 56, c = i % 56;
    float v;
    if (c < 20)      v = Wsh[(size_t)k * 20 + c];
    else if (c < 32) v = Wsa[(size_t)k * 12 + (c - 20)];
    else if (c < 44) v = Wra[(size_t)k * 12 + (c - 32)];
    else             v = Wea[(size_t)k * 12 + (c - 44)];
    Wc[i] = v;
  }
  if (i < 64) {
    float v = 0.f;
    if (i < 20)      v = bsh[i];
    else if (i < 32) v = bsa[i - 20];
    else if (i < 44) v = bra[i - 32];
    else if (i < 56) v = bea[i - 44];
    bc[i] = v;
  }
}

// ---------------------------------------------------------------------------
// gates logits: fp32 micro-GEMM  logits[B][64] = x @ Wcat + bcat
// ---------------------------------------------------------------------------
__global__ __launch_bounds__(256) void gates_gemm(
    const float* __restrict__ x,
    const float* __restrict__ Wc,
    const float* __restrict__ bc,
    float* __restrict__ logits)
{
  const int b0 = blockIdx.x * 64;
  const int t = threadIdx.x;
  const int tr = t >> 4, tc = t & 15;
  __shared__ float sx[32][64];
  __shared__ float sw[32][64];

  float acc[4][4] = {};

  for (int kt = 0; kt < 32; ++kt) {
    const int k0 = kt * 32;
    __syncthreads();
#pragma unroll
    for (int it = 0; it < 2; ++it) {
      const int idx = t + it * 256;
      const int r = idx >> 3, c4 = (idx & 7) * 4;
      const float4 v = *(const float4*)(x + (size_t)(b0 + r) * 1024 + k0 + c4);
      sx[c4 + 0][r] = v.x; sx[c4 + 1][r] = v.y;
      sx[c4 + 2][r] = v.z; sx[c4 + 3][r] = v.w;
    }
#pragma unroll
    for (int it = 0; it < 2; ++it) {
      const int idx = t + it * 256;
      const int row = idx >> 4;
      const int c4  = (idx & 15) * 4;
      float4 v = {0.f, 0.f, 0.f, 0.f};
      if (c4 < 56)
        v = *(const float4*)(Wc + (size_t)(k0 + row) * 56 + c4);
      *(float4*)&sw[row][c4] = v;
    }
    __syncthreads();
#pragma unroll
    for (int kk = 0; kk < 32; ++kk) {
      const float4 rx = *(const float4*)&sx[kk][tr * 4];
      const float4 wv = *(const float4*)&sw[kk][tc * 4];
#pragma unroll
      for (int i = 0; i < 4; ++i) {
        const float xv = (i == 0) ? rx.x : (i == 1) ? rx.y : (i == 2) ? rx.z : rx.w;
        acc[i][0] += xv * wv.x; acc[i][1] += xv * wv.y;
        acc[i][2] += xv * wv.z; acc[i][3] += xv * wv.w;
      }
    }
  }

  const float4 bv = *(const float4*)&bc[tc * 4];
#pragma unroll
  for (int i = 0; i < 4; ++i) {
    float4 o;
    o.x = acc[i][0] + bv.x; o.y = acc[i][1] + bv.y;
    o.z = acc[i][2] + bv.z; o.w = acc[i][3] + bv.w;
    *(float4*)&logits[(size_t)(b0 + tr * 4 + i) * 64 + tc * 4] = o;
  }
}

// ---------------------------------------------------------------------------
// combine: inline softmax (wave 0) + gate-weighted expert sums
// ---------------------------------------------------------------------------
__global__ __launch_bounds__(256) void combine_k(
    const unsigned short* __restrict__ eo,   // [20][8192][512]
    const float* __restrict__ logits,        // [8192][64]
    unsigned short* __restrict__ tin)        // [8192][2048]
{
  const int b = blockIdx.x;
  const int t = threadIdx.x;
  __shared__ alignas(16) unsigned short lds[20][512];
  __shared__ float gsm[56];
#pragma unroll
  for (int i = 0; i < 5; ++i) {
    const int chunk = t + i * 256;
    const int e = chunk >> 6;
    const int h0 = (chunk & 63) * 8;
    *(uint4*)&lds[e][h0] = *(const uint4*)(eo + ((size_t)e * 8192 + b) * 512 + h0);
  }
  if (t < 64) {
    const float v0 = (t < 56) ? logits[(size_t)b * 64 + t] : 0.f;
    const int off[4] = {0, 20, 32, 44};
    const int wd[4]  = {20, 12, 12, 12};
    for (int g = 0; g < 4; ++g) {
      const bool in = (t >= off[g]) && (t < off[g] + wd[g]);
      float vv = in ? v0 : -1e30f;
      float m = vv;
#pragma unroll
      for (int o = 32; o; o >>= 1) m = fmaxf(m, __shfl_xor(m, o));
      float e = in ? __expf(vv - m) : 0.f;
      float s = e;
#pragma unroll
      for (int o = 32; o; o >>= 1) s += __shfl_xor(s, o);
      if (in) gsm[t] = e / s;
    }
  }
  __syncthreads();

  const int sec = t >> 6;
  const int h0 = (t & 63) * 8;
  float acc[8] = {0.f, 0.f, 0.f, 0.f, 0.f, 0.f, 0.f, 0.f};
  if (sec == 0) {
    for (int e = 0; e < 20; ++e) {
      const float w = gsm[e];
#pragma unroll
      for (int j = 0; j < 8; ++j) acc[j] += w * bf2f(lds[e][h0 + j]);
    }
  } else {
    const int goff = 20 + (sec - 1) * 12;
    const int ebase = 8 + (sec - 1) * 4;
    for (int tt = 0; tt < 4; ++tt) {
      const float w = gsm[goff + tt];
#pragma unroll
      for (int j = 0; j < 8; ++j) acc[j] += w * bf2f(lds[ebase + tt][h0 + j]);
    }
    for (int ss = 0; ss < 8; ++ss) {
      const float w = gsm[goff + 4 + ss];
#pragma unroll
      for (int j = 0; j < 8; ++j) acc[j] += w * bf2f(lds[ss][h0 + j]);
    }
  }
  unsigned short* ob = tin + (size_t)b * 2048 + sec * 512 + h0;
  ushort4 u0 = make_ushort4(f2bf(acc[0]), f2bf(acc[1]), f2bf(acc[2]), f2bf(acc[3]));
  ushort4 u1 = make_ushort4(f2bf(acc[4]), f2bf(acc[5]), f2bf(acc[6]), f2bf(acc[7]));
  *(ushort4*)ob = u0;
  *(ushort4*)(ob + 4) = u1;
}

// ---------------------------------------------------------------------------
// final dense: wave per (b, task)
// ---------------------------------------------------------------------------
__global__ __launch_bounds__(256) void outd_k(
    const unsigned short* __restrict__ t2,   // [2][8192][512]
    const float* __restrict__ Wd0, const float* __restrict__ bd0,
    const float* __restrict__ Wd1, const float* __restrict__ bd1,
    float* __restrict__ out)
{
  const int gid = blockIdx.x * 4 + (threadIdx.x >> 6);
  const int lane = threadIdx.x & 63;
  const int b = gid >> 1, task = gid & 1;
  const uint4 raw = *(const uint4*)(t2 + ((size_t)task * 8192 + b) * 512 + lane * 8);
  const unsigned short* rs = (const unsigned short*)&raw;
  float v[8];
#pragma unroll
  for (int j = 0; j < 8; ++j) v[j] = bf2f(rs[j]);
  const float* Wd = task ? Wd1 : Wd0;
  const float* bd = task ? bd1 : bd0;
  const int ncol = task ? 4 : 6;
  float* ob = task ? (out + (size_t)8192 * 6 + (size_t)b * 4) : (out + (size_t)b * 6);
  for (int c = 0; c < ncol; ++c) {
    float p = 0.f;
#pragma unroll
    for (int j = 0; j < 8; ++j) p += v[j] * Wd[(size_t)(lane * 8 + j) * ncol + c];
#pragma unroll
    for (int o = 32; o; o >>= 1) p += __shfl_xor(p, o);
    if (lane == 0) ob[c] = p + bd[c];
  }
}

// ---------------------------------------------------------------------------
extern "C" void kernel_launch(void* const* d_in, const int* in_sizes, int n_in,
                              void* d_out, int out_size, void* d_ws, size_t ws_size,
                              hipStream_t stream) {
  const float* x     = (const float*)d_in[0];
  const float* W1    = (const float*)d_in[1];
  const float* b1    = (const float*)d_in[2];
  const float* W2    = (const float*)d_in[3];
  const float* b2    = (const float*)d_in[4];
  const float* W3    = (const float*)d_in[5];
  const float* b3    = (const float*)d_in[6];
  const float* Wg_sh = (const float*)d_in[7];
  const float* bg_sh = (const float*)d_in[8];
  const float* Wg_sa = (const float*)d_in[9];
  const float* bg_sa = (const float*)d_in[10];
  const float* Wg_ra = (const float*)d_in[11];
  const float* bg_ra = (const float*)d_in[12];
  const float* Wg_ea = (const float*)d_in[13];
  const float* bg_ea = (const float*)d_in[14];
  const float* Wt1   = (const float*)d_in[15];
  const float* bt1   = (const float*)d_in[16];
  const float* Wt2   = (const float*)d_in[17];
  const float* bt2   = (const float*)d_in[18];
  const float* Wd0   = (const float*)d_in[19];
  const float* bd0   = (const float*)d_in[20];
  const float* Wd1   = (const float*)d_in[21];
  const float* bd1   = (const float*)d_in[22];
  float* out = (float*)d_out;

  const int B = 8192, D = 1024, H1 = 2048, H2 = 1024, H3 = 512;
  const int E = 20, TU1 = 1024, TU2 = 512, TIN = 2048;

  auto rnd = [](size_t n) { return (n + 255) & ~(size_t)255; };
  const size_t szXb   = rnd((size_t)B * D * 2);
  const size_t szW1t  = rnd((size_t)E * H1 * D * 2);
  const size_t szW2t  = rnd((size_t)E * H2 * H1 * 2);
  const size_t szW3t  = rnd((size_t)E * H3 * H2 * 2);
  const size_t szWt1t = rnd((size_t)2 * TU1 * TIN * 2);
  const size_t szWt2t = rnd((size_t)2 * TU2 * TU1 * 2);
  const size_t szWcat = rnd((size_t)1024 * 56 * 4);
  const size_t szBcat = rnd((size_t)64 * 4);
  const size_t szLog  = rnd((size_t)B * 64 * 4);
  const size_t szEo   = rnd((size_t)E * B * H3 * 2);
  const size_t szTin  = rnd((size_t)B * TIN * 2);
  const size_t szT1   = rnd((size_t)2 * B * TU1 * 2);
  const size_t szT2   = rnd((size_t)2 * B * TU2 * 2);
  const size_t szH1e  = rnd((size_t)B * H1 * 2);      // per-expert h1 slab
  const size_t szH2e  = rnd((size_t)B * H2 * 2);      // per-expert h2 slab
  const size_t fixed = szXb + szW1t + szW2t + szW3t + szWt1t + szWt2t +
                       szWcat + szBcat + szLog + szEo;
  const size_t tNeed = szTin + szT1 + szT2;            // aliased onto h-region

  // pick the largest expert-batch G (divisor of 20) that fits
  int G = 1;
  const int opts[6] = {20, 10, 5, 4, 2, 1};
  for (int i = 0; i < 6; ++i) {
    size_t hNeed = (size_t)opts[i] * (szH1e + szH2e);
    if (hNeed < tNeed) hNeed = tNeed;
    if (fixed + hNeed <= ws_size) { G = opts[i]; break; }
  }

  char* w = (char*)d_ws;
  auto alloc = [&](size_t n) { char* p = w; w += rnd(n); return p; };
  unsigned short* xb   = (unsigned short*)alloc((size_t)B * D * 2);
  unsigned short* W1t  = (unsigned short*)alloc((size_t)E * H1 * D * 2);
  unsigned short* W2t  = (unsigned short*)alloc((size_t)E * H2 * H1 * 2);
  unsigned short* W3t  = (unsigned short*)alloc((size_t)E * H3 * H2 * 2);
  unsigned short* Wt1t = (unsigned short*)alloc((size_t)2 * TU1 * TIN * 2);
  unsigned short* Wt2t = (unsigned short*)alloc((size_t)2 * TU2 * TU1 * 2);
  float*          Wcat = (float*)alloc((size_t)1024 * 56 * 4);
  float*          bcat = (float*)alloc((size_t)64 * 4);
  float*          lgts = (float*)alloc((size_t)B * 64 * 4);
  unsigned short* eo   = (unsigned short*)alloc((size_t)E * B * H3 * 2);
  // h-region: h1/h2 (experts phase) aliased with tin/t1/t2 (tower phase)
  char* hreg = w;
  unsigned short* h1  = (unsigned short*)hreg;
  unsigned short* h2  = (unsigned short*)(hreg + (size_t)G * szH1e);
  unsigned short* tin = (unsigned short*)hreg;
  unsigned short* t1  = (unsigned short*)(hreg + szTin);
  unsigned short* t2  = (unsigned short*)(hreg + szTin + szT1);
  (void)in_sizes; (void)n_in; (void)out_size;

  // choose 256^2 kernel when the grid is big enough, else 128^2 fallback
  auto launch_gemm = [&](const unsigned short* Ap, const unsigned short* Btp,
                         const float* biasp, unsigned short* Outp,
                         int M, int N, int K, int Gz,
                         long sA, long sB, long sBias, long sOut) {
    const int nbx = N / 256, nby = M / 256;
    if (nbx > 0 && (M % 256) == 0 && nbx * nby * Gz >= 200) {
      gemm256<<<dim3(nbx * nby * Gz), 512, 0, stream>>>(
          Ap, Btp, biasp, Outp, N, K, nbx, nby, sA, sB, sBias, sOut);
    } else {
      gemm_bl<<<dim3(N / 128, M / 128, Gz), 256, 0, stream>>>(
          Ap, Btp, biasp, Outp, M, N, K, sA, sB, sBias, sOut);
    }
  };

  // conversions
  conv_x<<<dim3((B * D / 8) / 256), 256, 0, stream>>>(x, xb, B * D / 8);
  conv_t<<<dim3(D / 64,  H1 / 64, E), 256, 0, stream>>>(W1, W1t, D, H1);
  conv_t<<<dim3(H1 / 64, H2 / 64, E), 256, 0, stream>>>(W2, W2t, H1, H2);
  conv_t<<<dim3(H2 / 64, H3 / 64, E), 256, 0, stream>>>(W3, W3t, H2, H3);
  conv_t<<<dim3(TIN / 64, TU1 / 64, 2), 256, 0, stream>>>(Wt1, Wt1t, TIN, TU1);
  conv_t<<<dim3(TU1 / 64, TU2 / 64, 2), 256, 0, stream>>>(Wt2, Wt2t, TU1, TU2);

  // gates
  concat_g<<<dim3((1024 * 56 + 255) / 256), 256, 0, stream>>>(
      Wg_sh, bg_sh, Wg_sa, bg_sa, Wg_ra, bg_ra, Wg_ea, bg_ea, Wcat, bcat);
  gates_gemm<<<dim3(B / 64), 256, 0, stream>>>(x, Wcat, bcat, lgts);

  // experts, batched over z in groups of G
  for (int e0 = 0; e0 < E; e0 += G) {
    launch_gemm(xb, W1t + (size_t)e0 * H1 * D, b1 + (size_t)e0 * H1, h1,
                B, H1, D, G, 0, (long)H1 * D, (long)H1, (long)B * H1);
    launch_gemm(h1, W2t + (size_t)e0 * H2 * H1, b2 + (size_t)e0 * H2, h2,
                B, H2, H1, G, (long)B * H1, (long)H2 * H1, (long)H2, (long)B * H2);
    launch_gemm(h2, W3t + (size_t)e0 * H3 * H2, b3 + (size_t)e0 * H3,
                eo + (size_t)e0 * B * H3,
                B, H3, H2, G, (long)B * H2, (long)H3 * H2, (long)H3, (long)B * H3);
  }

  combine_k<<<dim3(B), 256, 0, stream>>>(eo, lgts, tin);

  // towers (z = task)
  launch_gemm(tin, Wt1t, bt1, t1, B, TU1, TIN, 2,
              0, (long)TU1 * TIN, (long)TU1, (long)B * TU1);
  launch_gemm(t1, Wt2t, bt2, t2, B, TU2, TU1, 2,
              (long)B * TU1, (long)TU2 * TU1, (long)TU2, (long)B * TU2);

  outd_k<<<dim3(B * 2 / 4), 256, 0, stream>>>(t2, Wd0, bd0, Wd1, bd1, out);
}

// Round 5
// 2196.956 us; speedup vs baseline: 1.6698x; 1.0648x over previous
//
#include <hip/hip_runtime.h>

#define DEV __device__ __forceinline__

typedef __bf16 bf16x8 __attribute__((ext_vector_type(8)));
typedef float f32x4 __attribute__((ext_vector_type(4)));

DEV unsigned short f2bf(float f) {
  union { float f; unsigned u; } v; v.f = f;
  unsigned r = v.u + 0x7FFFu + ((v.u >> 16) & 1u);
  return (unsigned short)(r >> 16);
}
DEV float bf2f(unsigned short h) {
  union { float f; unsigned u; } v; v.u = ((unsigned)h) << 16;
  return v.f;
}

// async global->LDS, 16B per lane.
DEV void gload16(const void* g, void* l) {
  __builtin_amdgcn_global_load_lds(
      (__attribute__((address_space(1))) void*)(g),
      (__attribute__((address_space(3))) void*)(l), 16, 0, 0);
}

#define MFMA16(a, b, c) __builtin_amdgcn_mfma_f32_16x16x32_bf16((a), (b), (c), 0, 0, 0)

// ---------------------------------------------------------------------------
// gemm256: Out[r*ldo+c] = lrelu(A[r*lda+k] @ Bt[N][K]^T + bias), bf16 in/out.
// 256x256 tile, BK=64, 512 thr (8 waves 2Mx4N, 128x64 out each).
// 4-phase/K-tile interleave (T3) + counted vmcnt (T4) + setprio (T5) +
// XOR-swizzled LDS via pre-swizzled global source (T2, rule #21) +
// bijective XCD swizzle (T1). M=nby*256 rows, N=nbx*256 cols per z-slab.
// ---------------------------------------------------------------------------
__global__ __launch_bounds__(512) void gemm256(
    const unsigned short* __restrict__ A,
    const unsigned short* __restrict__ Bt,
    const float* __restrict__ bias,
    unsigned short* __restrict__ Out,
    int K, int lda, int ldo, int nbx, int nby,
    long sA, long sB, long sBias, long sOut)
{
  int wg = blockIdx.x;
  {
    const int nwg = gridDim.x;
    const int q = nwg >> 3, r = nwg & 7;
    const int xcd = wg & 7, pos = wg >> 3;
    wg = (xcd < r ? xcd * (q + 1) : r * (q + 1) + (xcd - r) * q) + pos;
  }
  const int per_z = nbx * nby;
  const int z  = wg / per_z;
  const int rz = wg - z * per_z;
  const int by = rz / nbx;
  const int bx = rz - by * nbx;

  A    += (size_t)z * sA;
  Bt   += (size_t)z * sB;
  bias += (size_t)z * sBias;
  Out  += (size_t)z * sOut;

  const int tid  = threadIdx.x;
  const int lane = tid & 63;
  const int wid  = tid >> 6;
  const int wm   = wid >> 2, wn = wid & 3;   // 2 x 4 wave grid
  const int m0   = by * 256, n0 = bx * 256;

  __shared__ alignas(16) char sm[2][65536];  // per buf: A[256][128B] | B[256][128B]

  f32x4 acc[8][4];
  const f32x4 fz = {0.f, 0.f, 0.f, 0.f};
#pragma unroll
  for (int i = 0; i < 8; ++i)
#pragma unroll
    for (int j = 0; j < 4; ++j) acc[i][j] = fz;

  const int rr = tid >> 3;                   // 0..63
  const int ch = (tid & 7) ^ (rr & 7);       // pre-swizzled 16B chunk in 128B row
  const char* gA = (const char*)A  + ((size_t)(m0 + rr) * lda) * 2 + ch * 16;
  const char* gB = (const char*)Bt + ((size_t)(n0 + rr) * K)   * 2 + ch * 16;
  const size_t stepA = (size_t)64 * lda * 2;
  const size_t stepB = (size_t)64 * K * 2;

  // fragment read offsets (swizzle bits 4..6 of the 128B row)
  const int koff0 = (((lane >> 4) << 4) ^ ((lane & 7) << 4)); // ks=0; ks=1 -> ^64
  const int aRow  = wm * 128 + (lane & 15);
  const int bRow  = wn * 64  + (lane & 15);

  const int nkt = K >> 6;

  auto SA = [&](int buf, int kt, int jh) {   // A rows [128*jh, 128*jh+128)
    const char* s = gA + (size_t)kt * 128 + (2 * jh) * stepA;
    char* l = sm[buf] + tid * 16 + (2 * jh) * 8192;
    gload16(s, l);
    gload16(s + stepA, l + 8192);
  };
  auto SB = [&](int buf, int kt, int jh) {   // B rows [128*jh, 128*jh+128)
    const char* s = gB + (size_t)kt * 128 + (2 * jh) * stepB;
    char* l = sm[buf] + 32768 + tid * 16 + (2 * jh) * 8192;
    gload16(s, l);
    gload16(s + stepB, l + 8192);
  };

  // prologue: stage tile 0 fully (8 loads, FIFO)
  SA(0, 0, 0); SA(0, 0, 1); SB(0, 0, 0); SB(0, 0, 1);

  for (int kt = 0; kt < nkt; ++kt) {
    const int cur = kt & 1, nb = cur ^ 1;
    const bool pre = (kt + 1 < nkt);
    if (pre) {
      SA(nb, kt + 1, 0);                                  // 2 newer in flight
      asm volatile("s_waitcnt vmcnt(2)" ::: "memory");    // tile kt landed
    } else {
      asm volatile("s_waitcnt vmcnt(0)" ::: "memory");
    }
    __builtin_amdgcn_s_barrier();                         // tile kt visible to all
    __builtin_amdgcn_sched_barrier(0);

    const char* pA = sm[cur] + aRow * 128;
    const char* pB = sm[cur] + 32768 + bRow * 128;
    bf16x8 a0[4], a1[4], b0[4], b1[4];

    // ---- phase 0: mi 0-3, ks0 (loads b0)
    {
#pragma unroll
      for (int i = 0; i < 4; ++i) a0[i] = *(const bf16x8*)(pA + i * 2048 + koff0);
#pragma unroll
      for (int n = 0; n < 4; ++n) b0[n] = *(const bf16x8*)(pB + n * 2048 + koff0);
      if (pre) SA(nb, kt + 1, 1);
      asm volatile("s_waitcnt lgkmcnt(0)" ::: "memory");
      __builtin_amdgcn_sched_barrier(0);
      __builtin_amdgcn_s_setprio(1);
#pragma unroll
      for (int i = 0; i < 4; ++i)
#pragma unroll
        for (int n = 0; n < 4; ++n) acc[i][n] = MFMA16(a0[i], b0[n], acc[i][n]);
      __builtin_amdgcn_s_setprio(0);
      __builtin_amdgcn_sched_barrier(0);
      __builtin_amdgcn_s_barrier();
      __builtin_amdgcn_sched_barrier(0);
    }
    // ---- phase 1: mi 4-7, ks0 (reuses b0)
    {
#pragma unroll
      for (int i = 0; i < 4; ++i) a1[i] = *(const bf16x8*)(pA + (i + 4) * 2048 + koff0);
      if (pre) SB(nb, kt + 1, 0);
      asm volatile("s_waitcnt lgkmcnt(0)" ::: "memory");
      __builtin_amdgcn_sched_barrier(0);
      __builtin_amdgcn_s_setprio(1);
#pragma unroll
      for (int i = 0; i < 4; ++i)
#pragma unroll
        for (int n = 0; n < 4; ++n) acc[i + 4][n] = MFMA16(a1[i], b0[n], acc[i + 4][n]);
      __builtin_amdgcn_s_setprio(0);
      __builtin_amdgcn_sched_barrier(0);
      __builtin_amdgcn_s_barrier();
      __builtin_amdgcn_sched_barrier(0);
    }
    // ---- phase 2: mi 0-3, ks1 (loads b1)
    {
      const int ko = koff0 ^ 64;
#pragma unroll
      for (int i = 0; i < 4; ++i) a0[i] = *(const bf16x8*)(pA + i * 2048 + ko);
#pragma unroll
      for (int n = 0; n < 4; ++n) b1[n] = *(const bf16x8*)(pB + n * 2048 + ko);
      if (pre) SB(nb, kt + 1, 1);
      asm volatile("s_waitcnt lgkmcnt(0)" ::: "memory");
      __builtin_amdgcn_sched_barrier(0);
      __builtin_amdgcn_s_setprio(1);
#pragma unroll
      for (int i = 0; i < 4; ++i)
#pragma unroll
        for (int n = 0; n < 4; ++n) acc[i][n] = MFMA16(a0[i], b1[n], acc[i][n]);
      __builtin_amdgcn_s_setprio(0);
      __builtin_amdgcn_sched_barrier(0);
      __builtin_amdgcn_s_barrier();
      __builtin_amdgcn_sched_barrier(0);
    }
    // ---- phase 3: mi 4-7, ks1
    {
      const int ko = koff0 ^ 64;
#pragma unroll
      for (int i = 0; i < 4; ++i) a1[i] = *(const bf16x8*)(pA + (i + 4) * 2048 + ko);
      asm volatile("s_waitcnt lgkmcnt(0)" ::: "memory");
      __builtin_amdgcn_sched_barrier(0);
      __builtin_amdgcn_s_setprio(1);
#pragma unroll
      for (int i = 0; i < 4; ++i)
#pragma unroll
        for (int n = 0; n < 4; ++n) acc[i + 4][n] = MFMA16(a1[i], b1[n], acc[i + 4][n]);
      __builtin_amdgcn_s_setprio(0);
      __builtin_amdgcn_sched_barrier(0);
      __builtin_amdgcn_s_barrier();   // all reads of buf[cur] done before next SA
      __builtin_amdgcn_sched_barrier(0);
    }
  }

  // epilogue: bias + lrelu + bf16 store (C/D: col=lane&15, row=(lane>>4)*4+j)
#pragma unroll
  for (int ni = 0; ni < 4; ++ni) {
    const int c = n0 + wn * 64 + ni * 16 + (lane & 15);
    const float bv = bias[c];
#pragma unroll
    for (int mi = 0; mi < 8; ++mi) {
      const int r0 = m0 + wm * 128 + mi * 16 + ((lane >> 4) << 2);
#pragma unroll
      for (int j = 0; j < 4; ++j) {
        float v = acc[mi][ni][j] + bv;
        v = v >= 0.f ? v : 0.1f * v;
        Out[(size_t)(r0 + j) * ldo + c] = f2bf(v);
      }
    }
  }
}

// ---------------------------------------------------------------------------
// fp32 [K][N] -> bf16 [N][K] (per-z slab), LDS-tiled transpose
// ---------------------------------------------------------------------------
__global__ __launch_bounds__(256) void conv_t(
    const float* __restrict__ src, unsigned short* __restrict__ dst, int K, int N)
{
  const size_t zo = (size_t)blockIdx.z * K * N;
  src += zo; dst += zo;
  const int k0 = blockIdx.x * 64, n0 = blockIdx.y * 64;
  __shared__ unsigned short lds[64][68];
  const int t = threadIdx.x;
  const int cr = t >> 4;
  const int cc = (t & 15) * 4;
#pragma unroll
  for (int i = 0; i < 4; ++i) {
    const int row = i * 16 + cr;
    const float4 v = *(const float4*)(src + (size_t)(k0 + row) * N + n0 + cc);
    lds[row][cc + 0] = f2bf(v.x); lds[row][cc + 1] = f2bf(v.y);
    lds[row][cc + 2] = f2bf(v.z); lds[row][cc + 3] = f2bf(v.w);
  }
  __syncthreads();
#pragma unroll
  for (int i = 0; i < 4; ++i) {
    const int nrow = i * 16 + cr;
    ushort4 u = make_ushort4(lds[cc + 0][nrow], lds[cc + 1][nrow],
                             lds[cc + 2][nrow], lds[cc + 3][nrow]);
    *(ushort4*)(dst + (size_t)(n0 + nrow) * K + k0 + cc) = u;
  }
}

// fp32 -> bf16, 8 elements/thread
__global__ __launch_bounds__(256) void conv_x(
    const float* __restrict__ src, unsigned short* __restrict__ dst, int n8)
{
  const int i = blockIdx.x * 256 + threadIdx.x;
  if (i >= n8) return;
  const float4* p = (const float4*)(src + (size_t)i * 8);
  const float4 a = p[0], b = p[1];
  ushort4 u0 = make_ushort4(f2bf(a.x), f2bf(a.y), f2bf(a.z), f2bf(a.w));
  ushort4 u1 = make_ushort4(f2bf(b.x), f2bf(b.y), f2bf(b.z), f2bf(b.w));
  *(ushort4*)(dst + (size_t)i * 8)     = u0;
  *(ushort4*)(dst + (size_t)i * 8 + 4) = u1;
}

// ---------------------------------------------------------------------------
// concat gate weights -> Wcat fp32 [1024][56] + bcat[64]
// ---------------------------------------------------------------------------
__global__ __launch_bounds__(256) void concat_g(
    const float* __restrict__ Wsh, const float* __restrict__ bsh,
    const float* __restrict__ Wsa, const float* __restrict__ bsa,
    const float* __restrict__ Wra, const float* __restrict__ bra,
    const float* __restrict__ Wea, const float* __restrict__ bea,
    float* __restrict__ Wc, float* __restrict__ bc)
{
  const int i = blockIdx.x * 256 + threadIdx.x;
  if (i < 1024 * 56) {
    const int k = i / 56, c = i % 56;
    float v;
    if (c < 20)      v = Wsh[(size_t)k * 20 + c];
    else if (c < 32) v = Wsa[(size_t)k * 12 + (c - 20)];
    else if (c < 44) v = Wra[(size_t)k * 12 + (c - 32)];
    else             v = Wea[(size_t)k * 12 + (c - 44)];
    Wc[i] = v;
  }
  if (i < 64) {
    float v = 0.f;
    if (i < 20)      v = bsh[i];
    else if (i < 32) v = bsa[i - 20];
    else if (i < 44) v = bra[i - 32];
    else if (i < 56) v = bea[i - 44];
    bc[i] = v;
  }
}

// ---------------------------------------------------------------------------
// gates logits: fp32 micro-GEMM  logits[B][64] = x @ Wcat + bcat
// ---------------------------------------------------------------------------
__global__ __launch_bounds__(256) void gates_gemm(
    const float* __restrict__ x,
    const float* __restrict__ Wc,
    const float* __restrict__ bc,
    float* __restrict__ logits)
{
  const int b0 = blockIdx.x * 64;
  const int t = threadIdx.x;
  const int tr = t >> 4, tc = t & 15;
  __shared__ float sx[32][64];
  __shared__ float sw[32][64];

  float acc[4][4] = {};

  for (int kt = 0; kt < 32; ++kt) {
    const int k0 = kt * 32;
    __syncthreads();
#pragma unroll
    for (int it = 0; it < 2; ++it) {
      const int idx = t + it * 256;
      const int r = idx >> 3, c4 = (idx & 7) * 4;
      const float4 v = *(const float4*)(x + (size_t)(b0 + r) * 1024 + k0 + c4);
      sx[c4 + 0][r] = v.x; sx[c4 + 1][r] = v.y;
      sx[c4 + 2][r] = v.z; sx[c4 + 3][r] = v.w;
    }
#pragma unroll
    for (int it = 0; it < 2; ++it) {
      const int idx = t + it * 256;
      const int row = idx >> 4;
      const int c4  = (idx & 15) * 4;
      float4 v = {0.f, 0.f, 0.f, 0.f};
      if (c4 < 56)
        v = *(const float4*)(Wc + (size_t)(k0 + row) * 56 + c4);
      *(float4*)&sw[row][c4] = v;
    }
    __syncthreads();
#pragma unroll
    for (int kk = 0; kk < 32; ++kk) {
      const float4 rx = *(const float4*)&sx[kk][tr * 4];
      const float4 wv = *(const float4*)&sw[kk][tc * 4];
#pragma unroll
      for (int i = 0; i < 4; ++i) {
        const float xv = (i == 0) ? rx.x : (i == 1) ? rx.y : (i == 2) ? rx.z : rx.w;
        acc[i][0] += xv * wv.x; acc[i][1] += xv * wv.y;
        acc[i][2] += xv * wv.z; acc[i][3] += xv * wv.w;
      }
    }
  }

  const float4 bv = *(const float4*)&bc[tc * 4];
#pragma unroll
  for (int i = 0; i < 4; ++i) {
    float4 o;
    o.x = acc[i][0] + bv.x; o.y = acc[i][1] + bv.y;
    o.z = acc[i][2] + bv.z; o.w = acc[i][3] + bv.w;
    *(float4*)&logits[(size_t)(b0 + tr * 4 + i) * 64 + tc * 4] = o;
  }
}

// ---------------------------------------------------------------------------
// combine: inline softmax (wave 0) + gate-weighted expert sums.
// eo layout: [B][20*512] (expert e at columns e*512..e*512+511) -> row-contig.
// ---------------------------------------------------------------------------
__global__ __launch_bounds__(256) void combine_k(
    const unsigned short* __restrict__ eo,   // [8192][10240]
    const float* __restrict__ logits,        // [8192][64]
    unsigned short* __restrict__ tin)        // [8192][2048]
{
  const int b = blockIdx.x;
  const int t = threadIdx.x;
  __shared__ alignas(16) unsigned short lds[20][512];
  __shared__ float gsm[56];
  const unsigned short* er = eo + (size_t)b * 10240;
  unsigned short* ldsf = &lds[0][0];
#pragma unroll
  for (int i = 0; i < 5; ++i) {
    const int c = t + i * 256;               // 0..1279 16B chunks, contiguous
    *(uint4*)&ldsf[c * 8] = *(const uint4*)(er + c * 8);
  }
  if (t < 64) {
    const float v0 = (t < 56) ? logits[(size_t)b * 64 + t] : 0.f;
    const int off[4] = {0, 20, 32, 44};
    const int wd[4]  = {20, 12, 12, 12};
    for (int g = 0; g < 4; ++g) {
      const bool in = (t >= off[g]) && (t < off[g] + wd[g]);
      float vv = in ? v0 : -1e30f;
      float m = vv;
#pragma unroll
      for (int o = 32; o; o >>= 1) m = fmaxf(m, __shfl_xor(m, o));
      float e = in ? __expf(vv - m) : 0.f;
      float s = e;
#pragma unroll
      for (int o = 32; o; o >>= 1) s += __shfl_xor(s, o);
      if (in) gsm[t] = e / s;
    }
  }
  __syncthreads();

  const int sec = t >> 6;
  const int h0 = (t & 63) * 8;
  float acc[8] = {0.f, 0.f, 0.f, 0.f, 0.f, 0.f, 0.f, 0.f};
  if (sec == 0) {
    for (int e = 0; e < 20; ++e) {
      const float w = gsm[e];
#pragma unroll
      for (int j = 0; j < 8; ++j) acc[j] += w * bf2f(lds[e][h0 + j]);
    }
  } else {
    const int goff = 20 + (sec - 1) * 12;
    const int ebase = 8 + (sec - 1) * 4;
    for (int tt = 0; tt < 4; ++tt) {
      const float w = gsm[goff + tt];
#pragma unroll
      for (int j = 0; j < 8; ++j) acc[j] += w * bf2f(lds[ebase + tt][h0 + j]);
    }
    for (int ss = 0; ss < 8; ++ss) {
      const float w = gsm[goff + 4 + ss];
#pragma unroll
      for (int j = 0; j < 8; ++j) acc[j] += w * bf2f(lds[ss][h0 + j]);
    }
  }
  unsigned short* ob = tin + (size_t)b * 2048 + sec * 512 + h0;
  ushort4 u0 = make_ushort4(f2bf(acc[0]), f2bf(acc[1]), f2bf(acc[2]), f2bf(acc[3]));
  ushort4 u1 = make_ushort4(f2bf(acc[4]), f2bf(acc[5]), f2bf(acc[6]), f2bf(acc[7]));
  *(ushort4*)ob = u0;
  *(ushort4*)(ob + 4) = u1;
}

// ---------------------------------------------------------------------------
// final dense: wave per (b, task)
// ---------------------------------------------------------------------------
__global__ __launch_bounds__(256) void outd_k(
    const unsigned short* __restrict__ t2,   // [2][8192][512]
    const float* __restrict__ Wd0, const float* __restrict__ bd0,
    const float* __restrict__ Wd1, const float* __restrict__ bd1,
    float* __restrict__ out)
{
  const int gid = blockIdx.x * 4 + (threadIdx.x >> 6);
  const int lane = threadIdx.x & 63;
  const int b = gid >> 1, task = gid & 1;
  const uint4 raw = *(const uint4*)(t2 + ((size_t)task * 8192 + b) * 512 + lane * 8);
  const unsigned short* rs = (const unsigned short*)&raw;
  float v[8];
#pragma unroll
  for (int j = 0; j < 8; ++j) v[j] = bf2f(rs[j]);
  const float* Wd = task ? Wd1 : Wd0;
  const float* bd = task ? bd1 : bd0;
  const int ncol = task ? 4 : 6;
  float* ob = task ? (out + (size_t)8192 * 6 + (size_t)b * 4) : (out + (size_t)b * 6);
  for (int c = 0; c < ncol; ++c) {
    float p = 0.f;
#pragma unroll
    for (int j = 0; j < 8; ++j) p += v[j] * Wd[(size_t)(lane * 8 + j) * ncol + c];
#pragma unroll
    for (int o = 32; o; o >>= 1) p += __shfl_xor(p, o);
    if (lane == 0) ob[c] = p + bd[c];
  }
}

// ---------------------------------------------------------------------------
extern "C" void kernel_launch(void* const* d_in, const int* in_sizes, int n_in,
                              void* d_out, int out_size, void* d_ws, size_t ws_size,
                              hipStream_t stream) {
  const float* x     = (const float*)d_in[0];
  const float* W1    = (const float*)d_in[1];
  const float* b1    = (const float*)d_in[2];
  const float* W2    = (const float*)d_in[3];
  const float* b2    = (const float*)d_in[4];
  const float* W3    = (const float*)d_in[5];
  const float* b3    = (const float*)d_in[6];
  const float* Wg_sh = (const float*)d_in[7];
  const float* bg_sh = (const float*)d_in[8];
  const float* Wg_sa = (const float*)d_in[9];
  const float* bg_sa = (const float*)d_in[10];
  const float* Wg_ra = (const float*)d_in[11];
  const float* bg_ra = (const float*)d_in[12];
  const float* Wg_ea = (const float*)d_in[13];
  const float* bg_ea = (const float*)d_in[14];
  const float* Wt1   = (const float*)d_in[15];
  const float* bt1   = (const float*)d_in[16];
  const float* Wt2   = (const float*)d_in[17];
  const float* bt2   = (const float*)d_in[18];
  const float* Wd0   = (const float*)d_in[19];
  const float* bd0   = (const float*)d_in[20];
  const float* Wd1   = (const float*)d_in[21];
  const float* bd1   = (const float*)d_in[22];
  float* out = (float*)d_out;

  const int B = 8192, D = 1024, H1 = 2048, H2 = 1024, H3 = 512;
  const int E = 20, TU1 = 1024, TU2 = 512, TIN = 2048;

  auto rnd = [](size_t n) { return (n + 255) & ~(size_t)255; };
  const size_t szXb   = rnd((size_t)B * D * 2);
  const size_t szW1t  = rnd((size_t)E * H1 * D * 2);
  const size_t szW2t  = rnd((size_t)E * H2 * H1 * 2);
  const size_t szW3t  = rnd((size_t)E * H3 * H2 * 2);
  const size_t szWt1t = rnd((size_t)2 * TU1 * TIN * 2);
  const size_t szWt2t = rnd((size_t)2 * TU2 * TU1 * 2);
  const size_t szWcat = rnd((size_t)1024 * 56 * 4);
  const size_t szBcat = rnd((size_t)64 * 4);
  const size_t szLog  = rnd((size_t)B * 64 * 4);
  const size_t szEo   = rnd((size_t)E * B * H3 * 2);
  const size_t szTin  = rnd((size_t)B * TIN * 2);
  const size_t szT1   = rnd((size_t)2 * B * TU1 * 2);
  const size_t szT2   = rnd((size_t)2 * B * TU2 * 2);
  const size_t szH1e  = rnd((size_t)B * H1 * 2);      // per-expert h1 slab
  const size_t szH2e  = rnd((size_t)B * H2 * 2);      // per-expert h2 slab
  const size_t fixed = szXb + szW1t + szW2t + szW3t + szWt1t + szWt2t +
                       szWcat + szBcat + szLog + szEo;
  const size_t tNeed = szTin + szT1 + szT2;            // aliased onto h-region

  // pick the largest expert-batch G (divisor of 20) that fits
  int G = 1;
  const int opts[6] = {20, 10, 5, 4, 2, 1};
  for (int i = 0; i < 6; ++i) {
    size_t hNeed = (size_t)opts[i] * (szH1e + szH2e);
    if (hNeed < tNeed) hNeed = tNeed;
    if (fixed + hNeed <= ws_size) { G = opts[i]; break; }
  }

  char* w = (char*)d_ws;
  auto alloc = [&](size_t n) { char* p = w; w += rnd(n); return p; };
  unsigned short* xb   = (unsigned short*)alloc((size_t)B * D * 2);
  unsigned short* W1t  = (unsigned short*)alloc((size_t)E * H1 * D * 2);
  unsigned short* W2t  = (unsigned short*)alloc((size_t)E * H2 * H1 * 2);
  unsigned short* W3t  = (unsigned short*)alloc((size_t)E * H3 * H2 * 2);
  unsigned short* Wt1t = (unsigned short*)alloc((size_t)2 * TU1 * TIN * 2);
  unsigned short* Wt2t = (unsigned short*)alloc((size_t)2 * TU2 * TU1 * 2);
  float*          Wcat = (float*)alloc((size_t)1024 * 56 * 4);
  float*          bcat = (float*)alloc((size_t)64 * 4);
  float*          lgts = (float*)alloc((size_t)B * 64 * 4);
  unsigned short* eo   = (unsigned short*)alloc((size_t)E * B * H3 * 2);
  // h-region: h1g/h2g (experts) aliased with tin/t1/t2 (towers)
  char* hreg = w;
  unsigned short* h1  = (unsigned short*)hreg;                       // [B][G*H1]
  unsigned short* h2  = (unsigned short*)(hreg + (size_t)G * szH1e); // [B][G*H2]
  unsigned short* tin = (unsigned short*)hreg;
  unsigned short* t1  = (unsigned short*)(hreg + szTin);
  unsigned short* t2  = (unsigned short*)(hreg + szTin + szT1);
  (void)in_sizes; (void)n_in; (void)out_size;

  auto launch256 = [&](const unsigned short* Ap, int lda, long sA,
                       const unsigned short* Btp, long sB,
                       const float* biasp, long sBias,
                       unsigned short* Outp, int ldo, long sOut,
                       int N, int K, int nz) {
    const int nbx = N / 256, nby = B / 256;
    gemm256<<<dim3(nbx * nby * nz), 512, 0, stream>>>(
        Ap, Btp, biasp, Outp, K, lda, ldo, nbx, nby, sA, sB, sBias, sOut);
  };

  // conversions
  conv_x<<<dim3((B * D / 8) / 256), 256, 0, stream>>>(x, xb, B * D / 8);
  conv_t<<<dim3(D / 64,  H1 / 64, E), 256, 0, stream>>>(W1, W1t, D, H1);
  conv_t<<<dim3(H1 / 64, H2 / 64, E), 256, 0, stream>>>(W2, W2t, H1, H2);
  conv_t<<<dim3(H2 / 64, H3 / 64, E), 256, 0, stream>>>(W3, W3t, H2, H3);
  conv_t<<<dim3(TIN / 64, TU1 / 64, 2), 256, 0, stream>>>(Wt1, Wt1t, TIN, TU1);
  conv_t<<<dim3(TU1 / 64, TU2 / 64, 2), 256, 0, stream>>>(Wt2, Wt2t, TU1, TU2);

  // gates
  concat_g<<<dim3((1024 * 56 + 255) / 256), 256, 0, stream>>>(
      Wg_sh, bg_sh, Wg_sa, bg_sa, Wg_ra, bg_ra, Wg_ea, bg_ea, Wcat, bcat);
  gates_gemm<<<dim3(B / 64), 256, 0, stream>>>(x, Wcat, bcat, lgts);

  // experts, grouped over z (strided interleaved layouts)
  for (int e0 = 0; e0 < E; e0 += G) {
    launch256(xb, D, 0,
              W1t + (size_t)e0 * H1 * D, (long)H1 * D,
              b1 + (size_t)e0 * H1, H1,
              h1, G * H1, H1, H1, D, G);
    launch256(h1, G * H1, H1,
              W2t + (size_t)e0 * H2 * H1, (long)H2 * H1,
              b2 + (size_t)e0 * H2, H2,
              h2, G * H2, H2, H2, H1, G);
    launch256(h2, G * H2, H2,
              W3t + (size_t)e0 * H3 * H2, (long)H3 * H2,
              b3 + (size_t)e0 * H3, H3,
              eo + (size_t)e0 * H3, E * H3, H3, H3, H2, G);
  }

  combine_k<<<dim3(B), 256, 0, stream>>>(eo, lgts, tin);

  // towers (z = task)
  launch256(tin, TIN, 0, Wt1t, (long)TU1 * TIN, bt1, TU1,
            t1, TU1, (long)B * TU1, TU1, TIN, 2);
  launch256(t1, TU1, (long)B * TU1, Wt2t, (long)TU2 * TU1, bt2, TU2,
            t2, TU2, (long)B * TU2, TU2, TU1, 2);

  outd_k<<<dim3(B * 2 / 4), 256, 0, stream>>>(t2, Wd0, bd0, Wd1, bd1, out);
}

// Round 6
// 2196.722 us; speedup vs baseline: 1.6700x; 1.0001x over previous
//
#include <hip/hip_runtime.h>

#define DEV __device__ __forceinline__

typedef __bf16 bf16x8 __attribute__((ext_vector_type(8)));
typedef float f32x4 __attribute__((ext_vector_type(4)));

DEV unsigned short f2bf(float f) {
  union { float f; unsigned u; } v; v.f = f;
  unsigned r = v.u + 0x7FFFu + ((v.u >> 16) & 1u);
  return (unsigned short)(r >> 16);
}
DEV float bf2f(unsigned short h) {
  union { float f; unsigned u; } v; v.u = ((unsigned)h) << 16;
  return v.f;
}

// async global->LDS, 16B per lane.
DEV void gload16(const void* g, void* l) {
  __builtin_amdgcn_global_load_lds(
      (__attribute__((address_space(1))) void*)(g),
      (__attribute__((address_space(3))) void*)(l), 16, 0, 0);
}

#define MFMA16(a, b, c) __builtin_amdgcn_mfma_f32_16x16x32_bf16((a), (b), (c), 0, 0, 0)

// ---------------------------------------------------------------------------
// gemm256: Out[r*ldo+c] = lrelu(A[r*lda+k] @ Bt[N][K]^T + bias), bf16 in/out.
// 256x256 tile, BK=64, 512 thr (8 waves 2Mx4N, 128x64 out each).
// 4-phase/K-tile interleave (T3) + counted vmcnt (T4) + setprio (T5) +
// XOR-swizzled LDS via pre-swizzled global source (T2, rule #21) +
// bijective XCD swizzle (T1). M=nby*256 rows, N=nbx*256 cols per z-slab.
// ---------------------------------------------------------------------------
__global__ __launch_bounds__(512) void gemm256(
    const unsigned short* __restrict__ A,
    const unsigned short* __restrict__ Bt,
    const float* __restrict__ bias,
    unsigned short* __restrict__ Out,
    int K, int lda, int ldo, int nbx, int nby,
    long sA, long sB, long sBias, long sOut)
{
  int wg = blockIdx.x;
  {
    const int nwg = gridDim.x;
    const int q = nwg >> 3, r = nwg & 7;
    const int xcd = wg & 7, pos = wg >> 3;
    wg = (xcd < r ? xcd * (q + 1) : r * (q + 1) + (xcd - r) * q) + pos;
  }
  const int per_z = nbx * nby;
  const int z  = wg / per_z;
  const int rz = wg - z * per_z;
  const int by = rz / nbx;
  const int bx = rz - by * nbx;

  A    += (size_t)z * sA;
  Bt   += (size_t)z * sB;
  bias += (size_t)z * sBias;
  Out  += (size_t)z * sOut;

  const int tid  = threadIdx.x;
  const int lane = tid & 63;
  const int wid  = tid >> 6;
  const int wm   = wid >> 2, wn = wid & 3;   // 2 x 4 wave grid
  const int m0   = by * 256, n0 = bx * 256;

  __shared__ alignas(16) char sm[2][65536];  // per buf: A[256][128B] | B[256][128B]

  f32x4 acc[8][4];
  const f32x4 fz = {0.f, 0.f, 0.f, 0.f};
#pragma unroll
  for (int i = 0; i < 8; ++i)
#pragma unroll
    for (int j = 0; j < 4; ++j) acc[i][j] = fz;

  const int rr = tid >> 3;                   // 0..63
  const int ch = (tid & 7) ^ (rr & 7);       // pre-swizzled 16B chunk in 128B row
  const char* gA = (const char*)A  + ((size_t)(m0 + rr) * lda) * 2 + ch * 16;
  const char* gB = (const char*)Bt + ((size_t)(n0 + rr) * K)   * 2 + ch * 16;
  const size_t stepA = (size_t)64 * lda * 2;
  const size_t stepB = (size_t)64 * K * 2;

  // fragment read offsets (swizzle bits 4..6 of the 128B row)
  const int koff0 = (((lane >> 4) << 4) ^ ((lane & 7) << 4)); // ks=0; ks=1 -> ^64
  const int aRow  = wm * 128 + (lane & 15);
  const int bRow  = wn * 64  + (lane & 15);

  const int nkt = K >> 6;

  auto SA = [&](int buf, int kt, int jh) {   // A rows [128*jh, 128*jh+128)
    const char* s = gA + (size_t)kt * 128 + (2 * jh) * stepA;
    char* l = sm[buf] + tid * 16 + (2 * jh) * 8192;
    gload16(s, l);
    gload16(s + stepA, l + 8192);
  };
  auto SB = [&](int buf, int kt, int jh) {   // B rows [128*jh, 128*jh+128)
    const char* s = gB + (size_t)kt * 128 + (2 * jh) * stepB;
    char* l = sm[buf] + 32768 + tid * 16 + (2 * jh) * 8192;
    gload16(s, l);
    gload16(s + stepB, l + 8192);
  };

  // prologue: stage tile 0 fully (8 loads, FIFO)
  SA(0, 0, 0); SA(0, 0, 1); SB(0, 0, 0); SB(0, 0, 1);

  for (int kt = 0; kt < nkt; ++kt) {
    const int cur = kt & 1, nb = cur ^ 1;
    const bool pre = (kt + 1 < nkt);
    if (pre) {
      SA(nb, kt + 1, 0);                                  // 2 newer in flight
      asm volatile("s_waitcnt vmcnt(2)" ::: "memory");    // tile kt landed
    } else {
      asm volatile("s_waitcnt vmcnt(0)" ::: "memory");
    }
    __builtin_amdgcn_s_barrier();                         // tile kt visible to all
    __builtin_amdgcn_sched_barrier(0);

    const char* pA = sm[cur] + aRow * 128;
    const char* pB = sm[cur] + 32768 + bRow * 128;
    bf16x8 a0[4], a1[4], b0[4], b1[4];

    // ---- phase 0: mi 0-3, ks0 (loads b0)
    {
#pragma unroll
      for (int i = 0; i < 4; ++i) a0[i] = *(const bf16x8*)(pA + i * 2048 + koff0);
#pragma unroll
      for (int n = 0; n < 4; ++n) b0[n] = *(const bf16x8*)(pB + n * 2048 + koff0);
      if (pre) SA(nb, kt + 1, 1);
      asm volatile("s_waitcnt lgkmcnt(0)" ::: "memory");
      __builtin_amdgcn_sched_barrier(0);
      __builtin_amdgcn_s_setprio(1);
#pragma unroll
      for (int i = 0; i < 4; ++i)
#pragma unroll
        for (int n = 0; n < 4; ++n) acc[i][n] = MFMA16(a0[i], b0[n], acc[i][n]);
      __builtin_amdgcn_s_setprio(0);
      __builtin_amdgcn_sched_barrier(0);
      __builtin_amdgcn_s_barrier();
      __builtin_amdgcn_sched_barrier(0);
    }
    // ---- phase 1: mi 4-7, ks0 (reuses b0); stage BOTH B-halves for kt+1
    {
#pragma unroll
      for (int i = 0; i < 4; ++i) a1[i] = *(const bf16x8*)(pA + (i + 4) * 2048 + koff0);
      if (pre) { SB(nb, kt + 1, 0); SB(nb, kt + 1, 1); }
      asm volatile("s_waitcnt lgkmcnt(0)" ::: "memory");
      __builtin_amdgcn_sched_barrier(0);
      __builtin_amdgcn_s_setprio(1);
#pragma unroll
      for (int i = 0; i < 4; ++i)
#pragma unroll
        for (int n = 0; n < 4; ++n) acc[i + 4][n] = MFMA16(a1[i], b0[n], acc[i + 4][n]);
      __builtin_amdgcn_s_setprio(0);
      __builtin_amdgcn_sched_barrier(0);
      __builtin_amdgcn_s_barrier();
      __builtin_amdgcn_sched_barrier(0);
    }
    // ---- phase 2: mi 0-3, ks1 (loads b1)
    {
      const int ko = koff0 ^ 64;
#pragma unroll
      for (int i = 0; i < 4; ++i) a0[i] = *(const bf16x8*)(pA + i * 2048 + ko);
#pragma unroll
      for (int n = 0; n < 4; ++n) b1[n] = *(const bf16x8*)(pB + n * 2048 + ko);
      asm volatile("s_waitcnt lgkmcnt(0)" ::: "memory");
      __builtin_amdgcn_sched_barrier(0);
      __builtin_amdgcn_s_setprio(1);
#pragma unroll
      for (int i = 0; i < 4; ++i)
#pragma unroll
        for (int n = 0; n < 4; ++n) acc[i][n] = MFMA16(a0[i], b1[n], acc[i][n]);
      __builtin_amdgcn_s_setprio(0);
      __builtin_amdgcn_sched_barrier(0);
      __builtin_amdgcn_s_barrier();
      __builtin_amdgcn_sched_barrier(0);
    }
    // ---- phase 3: mi 4-7, ks1
    {
      const int ko = koff0 ^ 64;
#pragma unroll
      for (int i = 0; i < 4; ++i) a1[i] = *(const bf16x8*)(pA + (i + 4) * 2048 + ko);
      asm volatile("s_waitcnt lgkmcnt(0)" ::: "memory");
      __builtin_amdgcn_sched_barrier(0);
      __builtin_amdgcn_s_setprio(1);
#pragma unroll
      for (int i = 0; i < 4; ++i)
#pragma unroll
        for (int n = 0; n < 4; ++n) acc[i + 4][n] = MFMA16(a1[i], b1[n], acc[i + 4][n]);
      __builtin_amdgcn_s_setprio(0);
      __builtin_amdgcn_sched_barrier(0);
      __builtin_amdgcn_s_barrier();   // all reads of buf[cur] done before next SA
      __builtin_amdgcn_sched_barrier(0);
    }
  }

  // epilogue: bias + lrelu + bf16 store (C/D: col=lane&15, row=(lane>>4)*4+j)
#pragma unroll
  for (int ni = 0; ni < 4; ++ni) {
    const int c = n0 + wn * 64 + ni * 16 + (lane & 15);
    const float bv = bias[c];
#pragma unroll
    for (int mi = 0; mi < 8; ++mi) {
      const int r0 = m0 + wm * 128 + mi * 16 + ((lane >> 4) << 2);
#pragma unroll
      for (int j = 0; j < 4; ++j) {
        float v = acc[mi][ni][j] + bv;
        v = v >= 0.f ? v : 0.1f * v;
        Out[(size_t)(r0 + j) * ldo + c] = f2bf(v);
      }
    }
  }
}

// ---------------------------------------------------------------------------
// fp32 [K][N] -> bf16 [N][K] (per-z slab), LDS-tiled transpose
// ---------------------------------------------------------------------------
__global__ __launch_bounds__(256) void conv_t(
    const float* __restrict__ src, unsigned short* __restrict__ dst, int K, int N)
{
  const size_t zo = (size_t)blockIdx.z * K * N;
  src += zo; dst += zo;
  const int k0 = blockIdx.x * 64, n0 = blockIdx.y * 64;
  __shared__ unsigned short lds[64][68];
  const int t = threadIdx.x;
  const int cr = t >> 4;
  const int cc = (t & 15) * 4;
#pragma unroll
  for (int i = 0; i < 4; ++i) {
    const int row = i * 16 + cr;
    const float4 v = *(const float4*)(src + (size_t)(k0 + row) * N + n0 + cc);
    lds[row][cc + 0] = f2bf(v.x); lds[row][cc + 1] = f2bf(v.y);
    lds[row][cc + 2] = f2bf(v.z); lds[row][cc + 3] = f2bf(v.w);
  }
  __syncthreads();
#pragma unroll
  for (int i = 0; i < 4; ++i) {
    const int nrow = i * 16 + cr;
    ushort4 u = make_ushort4(lds[cc + 0][nrow], lds[cc + 1][nrow],
                             lds[cc + 2][nrow], lds[cc + 3][nrow]);
    *(ushort4*)(dst + (size_t)(n0 + nrow) * K + k0 + cc) = u;
  }
}

// fp32 -> bf16, 8 elements/thread
__global__ __launch_bounds__(256) void conv_x(
    const float* __restrict__ src, unsigned short* __restrict__ dst, int n8)
{
  const int i = blockIdx.x * 256 + threadIdx.x;
  if (i >= n8) return;
  const float4* p = (const float4*)(src + (size_t)i * 8);
  const float4 a = p[0], b = p[1];
  ushort4 u0 = make_ushort4(f2bf(a.x), f2bf(a.y), f2bf(a.z), f2bf(a.w));
  ushort4 u1 = make_ushort4(f2bf(b.x), f2bf(b.y), f2bf(b.z), f2bf(b.w));
  *(ushort4*)(dst + (size_t)i * 8)     = u0;
  *(ushort4*)(dst + (size_t)i * 8 + 4) = u1;
}

// ---------------------------------------------------------------------------
// concat gate weights -> Wcat fp32 [1024][56] + bcat[64]
// ---------------------------------------------------------------------------
__global__ __launch_bounds__(256) void concat_g(
    const float* __restrict__ Wsh, const float* __restrict__ bsh,
    const float* __restrict__ Wsa, const float* __restrict__ bsa,
    const float* __restrict__ Wra, const float* __restrict__ bra,
    const float* __restrict__ Wea, const float* __restrict__ bea,
    float* __restrict__ Wc, float* __restrict__ bc)
{
  const int i = blockIdx.x * 256 + threadIdx.x;
  if (i < 1024 * 56) {
    const int k = i / 56, c = i % 56;
    float v;
    if (c < 20)      v = Wsh[(size_t)k * 20 + c];
    else if (c < 32) v = Wsa[(size_t)k * 12 + (c - 20)];
    else if (c < 44) v = Wra[(size_t)k * 12 + (c - 32)];
    else             v = Wea[(size_t)k * 12 + (c - 44)];
    Wc[i] = v;
  }
  if (i < 64) {
    float v = 0.f;
    if (i < 20)      v = bsh[i];
    else if (i < 32) v = bsa[i - 20];
    else if (i < 44) v = bra[i - 32];
    else if (i < 56) v = bea[i - 44];
    bc[i] = v;
  }
}

// ---------------------------------------------------------------------------
// gates logits: fp32 micro-GEMM  logits[B][64] = x @ Wcat + bcat
// ---------------------------------------------------------------------------
__global__ __launch_bounds__(256) void gates_gemm(
    const float* __restrict__ x,
    const float* __restrict__ Wc,
    const float* __restrict__ bc,
    float* __restrict__ logits)
{
  const int b0 = blockIdx.x * 64;
  const int t = threadIdx.x;
  const int tr = t >> 4, tc = t & 15;
  __shared__ float sx[32][64];
  __shared__ float sw[32][64];

  float acc[4][4] = {};

  for (int kt = 0; kt < 32; ++kt) {
    const int k0 = kt * 32;
    __syncthreads();
#pragma unroll
    for (int it = 0; it < 2; ++it) {
      const int idx = t + it * 256;
      const int r = idx >> 3, c4 = (idx & 7) * 4;
      const float4 v = *(const float4*)(x + (size_t)(b0 + r) * 1024 + k0 + c4);
      sx[c4 + 0][r] = v.x; sx[c4 + 1][r] = v.y;
      sx[c4 + 2][r] = v.z; sx[c4 + 3][r] = v.w;
    }
#pragma unroll
    for (int it = 0; it < 2; ++it) {
      const int idx = t + it * 256;
      const int row = idx >> 4;
      const int c4  = (idx & 15) * 4;
      float4 v = {0.f, 0.f, 0.f, 0.f};
      if (c4 < 56)
        v = *(const float4*)(Wc + (size_t)(k0 + row) * 56 + c4);
      *(float4*)&sw[row][c4] = v;
    }
    __syncthreads();
#pragma unroll
    for (int kk = 0; kk < 32; ++kk) {
      const float4 rx = *(const float4*)&sx[kk][tr * 4];
      const float4 wv = *(const float4*)&sw[kk][tc * 4];
#pragma unroll
      for (int i = 0; i < 4; ++i) {
        const float xv = (i == 0) ? rx.x : (i == 1) ? rx.y : (i == 2) ? rx.z : rx.w;
        acc[i][0] += xv * wv.x; acc[i][1] += xv * wv.y;
        acc[i][2] += xv * wv.z; acc[i][3] += xv * wv.w;
      }
    }
  }

  const float4 bv = *(const float4*)&bc[tc * 4];
#pragma unroll
  for (int i = 0; i < 4; ++i) {
    float4 o;
    o.x = acc[i][0] + bv.x; o.y = acc[i][1] + bv.y;
    o.z = acc[i][2] + bv.z; o.w = acc[i][3] + bv.w;
    *(float4*)&logits[(size_t)(b0 + tr * 4 + i) * 64 + tc * 4] = o;
  }
}

// ---------------------------------------------------------------------------
// combine: inline softmax (wave 0) + gate-weighted expert sums.
// eo layout: [B][20*512] (expert e at columns e*512..e*512+511) -> row-contig.
// ---------------------------------------------------------------------------
__global__ __launch_bounds__(256) void combine_k(
    const unsigned short* __restrict__ eo,   // [8192][10240]
    const float* __restrict__ logits,        // [8192][64]
    unsigned short* __restrict__ tin)        // [8192][2048]
{
  const int b = blockIdx.x;
  const int t = threadIdx.x;
  __shared__ alignas(16) unsigned short lds[20][512];
  __shared__ float gsm[56];
  const unsigned short* er = eo + (size_t)b * 10240;
  unsigned short* ldsf = &lds[0][0];
#pragma unroll
  for (int i = 0; i < 5; ++i) {
    const int c = t + i * 256;               // 0..1279 16B chunks, contiguous
    *(uint4*)&ldsf[c * 8] = *(const uint4*)(er + c * 8);
  }
  if (t < 64) {
    const float v0 = (t < 56) ? logits[(size_t)b * 64 + t] : 0.f;
    const int off[4] = {0, 20, 32, 44};
    const int wd[4]  = {20, 12, 12, 12};
    for (int g = 0; g < 4; ++g) {
      const bool in = (t >= off[g]) && (t < off[g] + wd[g]);
      float vv = in ? v0 : -1e30f;
      float m = vv;
#pragma unroll
      for (int o = 32; o; o >>= 1) m = fmaxf(m, __shfl_xor(m, o));
      float e = in ? __expf(vv - m) : 0.f;
      float s = e;
#pragma unroll
      for (int o = 32; o; o >>= 1) s += __shfl_xor(s, o);
      if (in) gsm[t] = e / s;
    }
  }
  __syncthreads();

  const int sec = t >> 6;
  const int h0 = (t & 63) * 8;
  float acc[8] = {0.f, 0.f, 0.f, 0.f, 0.f, 0.f, 0.f, 0.f};
  if (sec == 0) {
    for (int e = 0; e < 20; ++e) {
      const float w = gsm[e];
#pragma unroll
      for (int j = 0; j < 8; ++j) acc[j] += w * bf2f(lds[e][h0 + j]);
    }
  } else {
    const int goff = 20 + (sec - 1) * 12;
    const int ebase = 8 + (sec - 1) * 4;
    for (int tt = 0; tt < 4; ++tt) {
      const float w = gsm[goff + tt];
#pragma unroll
      for (int j = 0; j < 8; ++j) acc[j] += w * bf2f(lds[ebase + tt][h0 + j]);
    }
    for (int ss = 0; ss < 8; ++ss) {
      const float w = gsm[goff + 4 + ss];
#pragma unroll
      for (int j = 0; j < 8; ++j) acc[j] += w * bf2f(lds[ss][h0 + j]);
    }
  }
  unsigned short* ob = tin + (size_t)b * 2048 + sec * 512 + h0;
  ushort4 u0 = make_ushort4(f2bf(acc[0]), f2bf(acc[1]), f2bf(acc[2]), f2bf(acc[3]));
  ushort4 u1 = make_ushort4(f2bf(acc[4]), f2bf(acc[5]), f2bf(acc[6]), f2bf(acc[7]));
  *(ushort4*)ob = u0;
  *(ushort4*)(ob + 4) = u1;
}

// ---------------------------------------------------------------------------
// final dense: wave per (b, task)
// ---------------------------------------------------------------------------
__global__ __launch_bounds__(256) void outd_k(
    const unsigned short* __restrict__ t2,   // [2][8192][512]
    const float* __restrict__ Wd0, const float* __restrict__ bd0,
    const float* __restrict__ Wd1, const float* __restrict__ bd1,
    float* __restrict__ out)
{
  const int gid = blockIdx.x * 4 + (threadIdx.x >> 6);
  const int lane = threadIdx.x & 63;
  const int b = gid >> 1, task = gid & 1;
  const uint4 raw = *(const uint4*)(t2 + ((size_t)task * 8192 + b) * 512 + lane * 8);
  const unsigned short* rs = (const unsigned short*)&raw;
  float v[8];
#pragma unroll
  for (int j = 0; j < 8; ++j) v[j] = bf2f(rs[j]);
  const float* Wd = task ? Wd1 : Wd0;
  const float* bd = task ? bd1 : bd0;
  const int ncol = task ? 4 : 6;
  float* ob = task ? (out + (size_t)8192 * 6 + (size_t)b * 4) : (out + (size_t)b * 6);
  for (int c = 0; c < ncol; ++c) {
    float p = 0.f;
#pragma unroll
    for (int j = 0; j < 8; ++j) p += v[j] * Wd[(size_t)(lane * 8 + j) * ncol + c];
#pragma unroll
    for (int o = 32; o; o >>= 1) p += __shfl_xor(p, o);
    if (lane == 0) ob[c] = p + bd[c];
  }
}

// ---------------------------------------------------------------------------
extern "C" void kernel_launch(void* const* d_in, const int* in_sizes, int n_in,
                              void* d_out, int out_size, void* d_ws, size_t ws_size,
                              hipStream_t stream) {
  const float* x     = (const float*)d_in[0];
  const float* W1    = (const float*)d_in[1];
  const float* b1    = (const float*)d_in[2];
  const float* W2    = (const float*)d_in[3];
  const float* b2    = (const float*)d_in[4];
  const float* W3    = (const float*)d_in[5];
  const float* b3    = (const float*)d_in[6];
  const float* Wg_sh = (const float*)d_in[7];
  const float* bg_sh = (const float*)d_in[8];
  const float* Wg_sa = (const float*)d_in[9];
  const float* bg_sa = (const float*)d_in[10];
  const float* Wg_ra = (const float*)d_in[11];
  const float* bg_ra = (const float*)d_in[12];
  const float* Wg_ea = (const float*)d_in[13];
  const float* bg_ea = (const float*)d_in[14];
  const float* Wt1   = (const float*)d_in[15];
  const float* bt1   = (const float*)d_in[16];
  const float* Wt2   = (const float*)d_in[17];
  const float* bt2   = (const float*)d_in[18];
  const float* Wd0   = (const float*)d_in[19];
  const float* bd0   = (const float*)d_in[20];
  const float* Wd1   = (const float*)d_in[21];
  const float* bd1   = (const float*)d_in[22];
  float* out = (float*)d_out;

  const int B = 8192, D = 1024, H1 = 2048, H2 = 1024, H3 = 512;
  const int E = 20, TU1 = 1024, TU2 = 512, TIN = 2048;

  auto rnd = [](size_t n) { return (n + 255) & ~(size_t)255; };
  const size_t szXb   = rnd((size_t)B * D * 2);
  const size_t szW1t  = rnd((size_t)E * H1 * D * 2);
  const size_t szW2t  = rnd((size_t)E * H2 * H1 * 2);
  const size_t szW3t  = rnd((size_t)E * H3 * H2 * 2);
  const size_t szWt1t = rnd((size_t)2 * TU1 * TIN * 2);
  const size_t szWt2t = rnd((size_t)2 * TU2 * TU1 * 2);
  const size_t szWcat = rnd((size_t)1024 * 56 * 4);
  const size_t szBcat = rnd((size_t)64 * 4);
  const size_t szLog  = rnd((size_t)B * 64 * 4);
  const size_t szEo   = rnd((size_t)E * B * H3 * 2);
  const size_t szTin  = rnd((size_t)B * TIN * 2);
  const size_t szT1   = rnd((size_t)2 * B * TU1 * 2);
  const size_t szT2   = rnd((size_t)2 * B * TU2 * 2);
  const size_t szH1e  = rnd((size_t)B * H1 * 2);      // per-expert h1 slab
  const size_t szH2e  = rnd((size_t)B * H2 * 2);      // per-expert h2 slab
  const size_t fixed = szXb + szW1t + szW2t + szW3t + szWt1t + szWt2t +
                       szWcat + szBcat + szLog + szEo;
  const size_t tNeed = szTin + szT1 + szT2;            // aliased onto h-region

  // pick the largest expert-batch G (divisor of 20) that fits
  int G = 1;
  const int opts[6] = {20, 10, 5, 4, 2, 1};
  for (int i = 0; i < 6; ++i) {
    size_t hNeed = (size_t)opts[i] * (szH1e + szH2e);
    if (hNeed < tNeed) hNeed = tNeed;
    if (fixed + hNeed <= ws_size) { G = opts[i]; break; }
  }

  char* w = (char*)d_ws;
  auto alloc = [&](size_t n) { char* p = w; w += rnd(n); return p; };
  unsigned short* xb   = (unsigned short*)alloc((size_t)B * D * 2);
  unsigned short* W1t  = (unsigned short*)alloc((size_t)E * H1 * D * 2);
  unsigned short* W2t  = (unsigned short*)alloc((size_t)E * H2 * H1 * 2);
  unsigned short* W3t  = (unsigned short*)alloc((size_t)E * H3 * H2 * 2);
  unsigned short* Wt1t = (unsigned short*)alloc((size_t)2 * TU1 * TIN * 2);
  unsigned short* Wt2t = (unsigned short*)alloc((size_t)2 * TU2 * TU1 * 2);
  float*          Wcat = (float*)alloc((size_t)1024 * 56 * 4);
  float*          bcat = (float*)alloc((size_t)64 * 4);
  float*          lgts = (float*)alloc((size_t)B * 64 * 4);
  unsigned short* eo   = (unsigned short*)alloc((size_t)E * B * H3 * 2);
  // h-region: h1/h2 (experts, contiguous per-expert slabs) aliased with towers
  char* hreg = w;
  unsigned short* h1  = (unsigned short*)hreg;                       // [G][B][H1]
  unsigned short* h2  = (unsigned short*)(hreg + (size_t)G * szH1e); // [G][B][H2]
  unsigned short* tin = (unsigned short*)hreg;
  unsigned short* t1  = (unsigned short*)(hreg + szTin);
  unsigned short* t2  = (unsigned short*)(hreg + szTin + szT1);
  (void)in_sizes; (void)n_in; (void)out_size;

  auto launch256 = [&](const unsigned short* Ap, int lda, long sA,
                       const unsigned short* Btp, long sB,
                       const float* biasp, long sBias,
                       unsigned short* Outp, int ldo, long sOut,
                       int N, int K, int nz) {
    const int nbx = N / 256, nby = B / 256;
    gemm256<<<dim3(nbx * nby * nz), 512, 0, stream>>>(
        Ap, Btp, biasp, Outp, K, lda, ldo, nbx, nby, sA, sB, sBias, sOut);
  };

  // conversions
  conv_x<<<dim3((B * D / 8) / 256), 256, 0, stream>>>(x, xb, B * D / 8);
  conv_t<<<dim3(D / 64,  H1 / 64, E), 256, 0, stream>>>(W1, W1t, D, H1);
  conv_t<<<dim3(H1 / 64, H2 / 64, E), 256, 0, stream>>>(W2, W2t, H1, H2);
  conv_t<<<dim3(H2 / 64, H3 / 64, E), 256, 0, stream>>>(W3, W3t, H2, H3);
  conv_t<<<dim3(TIN / 64, TU1 / 64, 2), 256, 0, stream>>>(Wt1, Wt1t, TIN, TU1);
  conv_t<<<dim3(TU1 / 64, TU2 / 64, 2), 256, 0, stream>>>(Wt2, Wt2t, TU1, TU2);

  // gates
  concat_g<<<dim3((1024 * 56 + 255) / 256), 256, 0, stream>>>(
      Wg_sh, bg_sh, Wg_sa, bg_sa, Wg_ra, bg_ra, Wg_ea, bg_ea, Wcat, bcat);
  gates_gemm<<<dim3(B / 64), 256, 0, stream>>>(x, Wcat, bcat, lgts);

  // experts, grouped over z; h1/h2 contiguous per-expert, eo strided for combine
  for (int e0 = 0; e0 < E; e0 += G) {
    launch256(xb, D, 0,
              W1t + (size_t)e0 * H1 * D, (long)H1 * D,
              b1 + (size_t)e0 * H1, H1,
              h1, H1, (long)B * H1, H1, D, G);
    launch256(h1, H1, (long)B * H1,
              W2t + (size_t)e0 * H2 * H1, (long)H2 * H1,
              b2 + (size_t)e0 * H2, H2,
              h2, H2, (long)B * H2, H2, H1, G);
    launch256(h2, H2, (long)B * H2,
              W3t + (size_t)e0 * H3 * H2, (long)H3 * H2,
              b3 + (size_t)e0 * H3, H3,
              eo + (size_t)e0 * H3, E * H3, H3, H3, H2, G);
  }

  combine_k<<<dim3(B), 256, 0, stream>>>(eo, lgts, tin);

  // towers (z = task)
  launch256(tin, TIN, 0, Wt1t, (long)TU1 * TIN, bt1, TU1,
            t1, TU1, (long)B * TU1, TU1, TIN, 2);
  launch256(t1, TU1, (long)B * TU1, Wt2t, (long)TU2 * TU1, bt2, TU2,
            t2, TU2, (long)B * TU2, TU2, TU1, 2);

  outd_k<<<dim3(B * 2 / 4), 256, 0, stream>>>(t2, Wd0, bd0, Wd1, bd1, out);
}

// Round 7
// 2174.107 us; speedup vs baseline: 1.6873x; 1.0104x over previous
//
#include <hip/hip_runtime.h>

#define DEV __device__ __forceinline__

typedef __bf16 bf16x8 __attribute__((ext_vector_type(8)));
typedef float f32x4 __attribute__((ext_vector_type(4)));

DEV unsigned short f2bf(float f) {
  union { float f; unsigned u; } v; v.f = f;
  unsigned r = v.u + 0x7FFFu + ((v.u >> 16) & 1u);
  return (unsigned short)(r >> 16);
}
DEV float bf2f(unsigned short h) {
  union { float f; unsigned u; } v; v.u = ((unsigned)h) << 16;
  return v.f;
}

// async global->LDS, 16B per lane.
DEV void gload16(const void* g, void* l) {
  __builtin_amdgcn_global_load_lds(
      (__attribute__((address_space(1))) void*)(g),
      (__attribute__((address_space(3))) void*)(l), 16, 0, 0);
}

#define MFMA16(a, b, c) __builtin_amdgcn_mfma_f32_16x16x32_bf16((a), (b), (c), 0, 0, 0)

// ---------------------------------------------------------------------------
// gemm256: Out[r*ldo+c] = lrelu(A[r*lda+k] @ Bt[N][K]^T + bias), bf16 in/out.
// 256x256 tile, BK=64, 512 thr (8 waves 2Mx4N, 128x64 out each).
// 4-phase/K-tile interleave (T3) + counted vmcnt (T4) + setprio (T5) +
// XOR-swizzled LDS via pre-swizzled global source (T2, rule #21) +
// bijective XCD swizzle (T1). M=nby*256 rows, N=nbx*256 cols per z-slab.
// ---------------------------------------------------------------------------
__global__ __launch_bounds__(512) void gemm256(
    const unsigned short* __restrict__ A,
    const unsigned short* __restrict__ Bt,
    const float* __restrict__ bias,
    unsigned short* __restrict__ Out,
    int K, int lda, int ldo, int nbx, int nby,
    long sA, long sB, long sBias, long sOut)
{
  int wg = blockIdx.x;
  {
    const int nwg = gridDim.x;
    const int q = nwg >> 3, r = nwg & 7;
    const int xcd = wg & 7, pos = wg >> 3;
    wg = (xcd < r ? xcd * (q + 1) : r * (q + 1) + (xcd - r) * q) + pos;
  }
  const int per_z = nbx * nby;
  const int z  = wg / per_z;
  const int rz = wg - z * per_z;
  const int by = rz / nbx;
  const int bx = rz - by * nbx;

  A    += (size_t)z * sA;
  Bt   += (size_t)z * sB;
  bias += (size_t)z * sBias;
  Out  += (size_t)z * sOut;

  const int tid  = threadIdx.x;
  const int lane = tid & 63;
  const int wid  = tid >> 6;
  const int wm   = wid >> 2, wn = wid & 3;   // 2 x 4 wave grid
  const int m0   = by * 256, n0 = bx * 256;

  __shared__ alignas(16) char sm[2][65536];  // per buf: A[256][128B] | B[256][128B]

  f32x4 acc[8][4];
  const f32x4 fz = {0.f, 0.f, 0.f, 0.f};
#pragma unroll
  for (int i = 0; i < 8; ++i)
#pragma unroll
    for (int j = 0; j < 4; ++j) acc[i][j] = fz;

  const int rr = tid >> 3;                   // 0..63
  const int ch = (tid & 7) ^ (rr & 7);       // pre-swizzled 16B chunk in 128B row
  const char* gA = (const char*)A  + ((size_t)(m0 + rr) * lda) * 2 + ch * 16;
  const char* gB = (const char*)Bt + ((size_t)(n0 + rr) * K)   * 2 + ch * 16;
  const size_t stepA = (size_t)64 * lda * 2;
  const size_t stepB = (size_t)64 * K * 2;

  // fragment read offsets (swizzle bits 4..6 of the 128B row)
  const int koff0 = (((lane >> 4) << 4) ^ ((lane & 7) << 4)); // ks=0; ks=1 -> ^64
  const int aRow  = wm * 128 + (lane & 15);
  const int bRow  = wn * 64  + (lane & 15);

  const int nkt = K >> 6;

  auto SA = [&](int buf, int kt, int jh) {   // A rows [128*jh, 128*jh+128)
    const char* s = gA + (size_t)kt * 128 + (2 * jh) * stepA;
    char* l = sm[buf] + tid * 16 + (2 * jh) * 8192;
    gload16(s, l);
    gload16(s + stepA, l + 8192);
  };
  auto SB = [&](int buf, int kt, int jh) {   // B rows [128*jh, 128*jh+128)
    const char* s = gB + (size_t)kt * 128 + (2 * jh) * stepB;
    char* l = sm[buf] + 32768 + tid * 16 + (2 * jh) * 8192;
    gload16(s, l);
    gload16(s + stepB, l + 8192);
  };

  // prologue: stage tile 0 fully (8 loads, FIFO)
  SA(0, 0, 0); SA(0, 0, 1); SB(0, 0, 0); SB(0, 0, 1);

  for (int kt = 0; kt < nkt; ++kt) {
    const int cur = kt & 1, nb = cur ^ 1;
    const bool pre = (kt + 1 < nkt);
    if (pre) {
      SA(nb, kt + 1, 0);                                  // 2 newer in flight
      asm volatile("s_waitcnt vmcnt(2)" ::: "memory");    // tile kt landed
    } else {
      asm volatile("s_waitcnt vmcnt(0)" ::: "memory");
    }
    __builtin_amdgcn_s_barrier();                         // tile kt visible to all
    __builtin_amdgcn_sched_barrier(0);

    const char* pA = sm[cur] + aRow * 128;
    const char* pB = sm[cur] + 32768 + bRow * 128;
    bf16x8 a0[4], a1[4], b0[4], b1[4];

    // ---- phase 0: mi 0-3, ks0 (loads b0)
    {
#pragma unroll
      for (int i = 0; i < 4; ++i) a0[i] = *(const bf16x8*)(pA + i * 2048 + koff0);
#pragma unroll
      for (int n = 0; n < 4; ++n) b0[n] = *(const bf16x8*)(pB + n * 2048 + koff0);
      if (pre) SA(nb, kt + 1, 1);
      asm volatile("s_waitcnt lgkmcnt(0)" ::: "memory");
      __builtin_amdgcn_sched_barrier(0);
      __builtin_amdgcn_s_setprio(1);
#pragma unroll
      for (int i = 0; i < 4; ++i)
#pragma unroll
        for (int n = 0; n < 4; ++n) acc[i][n] = MFMA16(a0[i], b0[n], acc[i][n]);
      __builtin_amdgcn_s_setprio(0);
      __builtin_amdgcn_sched_barrier(0);
      __builtin_amdgcn_s_barrier();
      __builtin_amdgcn_sched_barrier(0);
    }
    // ---- phase 1: mi 4-7, ks0 (reuses b0); stage BOTH B-halves for kt+1
    {
#pragma unroll
      for (int i = 0; i < 4; ++i) a1[i] = *(const bf16x8*)(pA + (i + 4) * 2048 + koff0);
      if (pre) { SB(nb, kt + 1, 0); SB(nb, kt + 1, 1); }
      asm volatile("s_waitcnt lgkmcnt(0)" ::: "memory");
      __builtin_amdgcn_sched_barrier(0);
      __builtin_amdgcn_s_setprio(1);
#pragma unroll
      for (int i = 0; i < 4; ++i)
#pragma unroll
        for (int n = 0; n < 4; ++n) acc[i + 4][n] = MFMA16(a1[i], b0[n], acc[i + 4][n]);
      __builtin_amdgcn_s_setprio(0);
      __builtin_amdgcn_sched_barrier(0);
      __builtin_amdgcn_s_barrier();
      __builtin_amdgcn_sched_barrier(0);
    }
    // ---- phase 2: mi 0-3, ks1 (loads b1)
    {
      const int ko = koff0 ^ 64;
#pragma unroll
      for (int i = 0; i < 4; ++i) a0[i] = *(const bf16x8*)(pA + i * 2048 + ko);
#pragma unroll
      for (int n = 0; n < 4; ++n) b1[n] = *(const bf16x8*)(pB + n * 2048 + ko);
      asm volatile("s_waitcnt lgkmcnt(0)" ::: "memory");
      __builtin_amdgcn_sched_barrier(0);
      __builtin_amdgcn_s_setprio(1);
#pragma unroll
      for (int i = 0; i < 4; ++i)
#pragma unroll
        for (int n = 0; n < 4; ++n) acc[i][n] = MFMA16(a0[i], b1[n], acc[i][n]);
      __builtin_amdgcn_s_setprio(0);
      __builtin_amdgcn_sched_barrier(0);
      __builtin_amdgcn_s_barrier();
      __builtin_amdgcn_sched_barrier(0);
    }
    // ---- phase 3: mi 4-7, ks1
    {
      const int ko = koff0 ^ 64;
#pragma unroll
      for (int i = 0; i < 4; ++i) a1[i] = *(const bf16x8*)(pA + (i + 4) * 2048 + ko);
      asm volatile("s_waitcnt lgkmcnt(0)" ::: "memory");
      __builtin_amdgcn_sched_barrier(0);
      __builtin_amdgcn_s_setprio(1);
#pragma unroll
      for (int i = 0; i < 4; ++i)
#pragma unroll
        for (int n = 0; n < 4; ++n) acc[i + 4][n] = MFMA16(a1[i], b1[n], acc[i + 4][n]);
      __builtin_amdgcn_s_setprio(0);
      __builtin_amdgcn_sched_barrier(0);
      __builtin_amdgcn_s_barrier();   // all reads of buf[cur] done before next SA
      __builtin_amdgcn_sched_barrier(0);
    }
  }

  // epilogue: bias + lrelu + bf16 store (C/D: col=lane&15, row=(lane>>4)*4+j)
#pragma unroll
  for (int ni = 0; ni < 4; ++ni) {
    const int c = n0 + wn * 64 + ni * 16 + (lane & 15);
    const float bv = bias[c];
#pragma unroll
    for (int mi = 0; mi < 8; ++mi) {
      const int r0 = m0 + wm * 128 + mi * 16 + ((lane >> 4) << 2);
#pragma unroll
      for (int j = 0; j < 4; ++j) {
        float v = acc[mi][ni][j] + bv;
        v = v >= 0.f ? v : 0.1f * v;
        Out[(size_t)(r0 + j) * ldo + c] = f2bf(v);
      }
    }
  }
}

// ---------------------------------------------------------------------------
// conv_all: ALL fp32->bf16 conversions in one launch.
// Segments (hardcoded for this problem):
//   0: W1  [20][1024][2048] -> W1t  [20][2048][1024] (transpose)  tiles 10240
//   1: W2  [20][2048][1024] -> W2t  [20][1024][2048]              tiles 10240
//   2: W3  [20][1024][512]  -> W3t  [20][512][1024]               tiles  2560
//   3: Wt1 [2][2048][1024]  -> Wt1t [2][1024][2048]               tiles  1024
//   4: Wt2 [2][1024][512]   -> Wt2t [2][512][1024]                tiles   256
//   5: x   [8192][1024]     -> xb (straight convert)              tiles  2048
// total grid = 26368 blocks x 256 thr
// ---------------------------------------------------------------------------
__global__ __launch_bounds__(256) void conv_all(
    const float* __restrict__ W1,  const float* __restrict__ W2,
    const float* __restrict__ W3,  const float* __restrict__ Wt1,
    const float* __restrict__ Wt2, const float* __restrict__ x,
    unsigned short* __restrict__ W1t,  unsigned short* __restrict__ W2t,
    unsigned short* __restrict__ W3t,  unsigned short* __restrict__ Wt1t,
    unsigned short* __restrict__ Wt2t, unsigned short* __restrict__ xb)
{
  const int id = blockIdx.x;
  const int t  = threadIdx.x;

  if (id >= 24320) {                 // segment 5: straight convert of x
    const int local = id - 24320;    // 0..2047; x is [8192][1024], 64x64 tiles
    const int r0 = (local >> 4) * 64, c0 = (local & 15) * 64;
#pragma unroll
    for (int i = 0; i < 4; ++i) {
      const int row = r0 + i * 16 + (t >> 4);
      const int col = c0 + (t & 15) * 4;
      const float4 v = *(const float4*)(x + (size_t)row * 1024 + col);
      ushort4 u = make_ushort4(f2bf(v.x), f2bf(v.y), f2bf(v.z), f2bf(v.w));
      *(ushort4*)(xb + (size_t)row * 1024 + col) = u;
    }
    return;
  }

  const float* src; unsigned short* dst; int K, N, local;
  if (id < 10240)      { src = W1;  dst = W1t;  K = 1024; N = 2048; local = id; }
  else if (id < 20480) { src = W2;  dst = W2t;  K = 2048; N = 1024; local = id - 10240; }
  else if (id < 23040) { src = W3;  dst = W3t;  K = 1024; N = 512;  local = id - 20480; }
  else if (id < 24064) { src = Wt1; dst = Wt1t; K = 2048; N = 1024; local = id - 23040; }
  else                 { src = Wt2; dst = Wt2t; K = 1024; N = 512;  local = id - 24064; }

  const int nkt = K >> 6, nnt = N >> 6;
  const int per_z = nkt * nnt;
  const int z   = local / per_z;
  const int rem = local - z * per_z;
  const int k0  = (rem % nkt) * 64;
  const int n0  = (rem / nkt) * 64;
  src += (size_t)z * K * N;
  dst += (size_t)z * K * N;

  __shared__ unsigned short lds[64][68];
  const int cr = t >> 4;
  const int cc = (t & 15) * 4;
#pragma unroll
  for (int i = 0; i < 4; ++i) {
    const int row = i * 16 + cr;
    const float4 v = *(const float4*)(src + (size_t)(k0 + row) * N + n0 + cc);
    lds[row][cc + 0] = f2bf(v.x); lds[row][cc + 1] = f2bf(v.y);
    lds[row][cc + 2] = f2bf(v.z); lds[row][cc + 3] = f2bf(v.w);
  }
  __syncthreads();
#pragma unroll
  for (int i = 0; i < 4; ++i) {
    const int nrow = i * 16 + cr;
    ushort4 u = make_ushort4(lds[cc + 0][nrow], lds[cc + 1][nrow],
                             lds[cc + 2][nrow], lds[cc + 3][nrow]);
    *(ushort4*)(dst + (size_t)(n0 + nrow) * K + k0 + cc) = u;
  }
}

// ---------------------------------------------------------------------------
// concat gate weights -> Wcat fp32 [1024][56] + bcat[64]
// ---------------------------------------------------------------------------
__global__ __launch_bounds__(256) void concat_g(
    const float* __restrict__ Wsh, const float* __restrict__ bsh,
    const float* __restrict__ Wsa, const float* __restrict__ bsa,
    const float* __restrict__ Wra, const float* __restrict__ bra,
    const float* __restrict__ Wea, const float* __restrict__ bea,
    float* __restrict__ Wc, float* __restrict__ bc)
{
  const int i = blockIdx.x * 256 + threadIdx.x;
  if (i < 1024 * 56) {
    const int k = i / 56, c = i % 56;
    float v;
    if (c < 20)      v = Wsh[(size_t)k * 20 + c];
    else if (c < 32) v = Wsa[(size_t)k * 12 + (c - 20)];
    else if (c < 44) v = Wra[(size_t)k * 12 + (c - 32)];
    else             v = Wea[(size_t)k * 12 + (c - 44)];
    Wc[i] = v;
  }
  if (i < 64) {
    float v = 0.f;
    if (i < 20)      v = bsh[i];
    else if (i < 32) v = bsa[i - 20];
    else if (i < 44) v = bra[i - 32];
    else if (i < 56) v = bea[i - 44];
    bc[i] = v;
  }
}

// ---------------------------------------------------------------------------
// gates logits: fp32 micro-GEMM  logits[B][64] = x @ Wcat + bcat
// ---------------------------------------------------------------------------
__global__ __launch_bounds__(256) void gates_gemm(
    const float* __restrict__ x,
    const float* __restrict__ Wc,
    const float* __restrict__ bc,
    float* __restrict__ logits)
{
  const int b0 = blockIdx.x * 64;
  const int t = threadIdx.x;
  const int tr = t >> 4, tc = t & 15;
  __shared__ float sx[32][64];
  __shared__ float sw[32][64];

  float acc[4][4] = {};

  for (int kt = 0; kt < 32; ++kt) {
    const int k0 = kt * 32;
    __syncthreads();
#pragma unroll
    for (int it = 0; it < 2; ++it) {
      const int idx = t + it * 256;
      const int r = idx >> 3, c4 = (idx & 7) * 4;
      const float4 v = *(const float4*)(x + (size_t)(b0 + r) * 1024 + k0 + c4);
      sx[c4 + 0][r] = v.x; sx[c4 + 1][r] = v.y;
      sx[c4 + 2][r] = v.z; sx[c4 + 3][r] = v.w;
    }
#pragma unroll
    for (int it = 0; it < 2; ++it) {
      const int idx = t + it * 256;
      const int row = idx >> 4;
      const int c4  = (idx & 15) * 4;
      float4 v = {0.f, 0.f, 0.f, 0.f};
      if (c4 < 56)
        v = *(const float4*)(Wc + (size_t)(k0 + row) * 56 + c4);
      *(float4*)&sw[row][c4] = v;
    }
    __syncthreads();
#pragma unroll
    for (int kk = 0; kk < 32; ++kk) {
      const float4 rx = *(const float4*)&sx[kk][tr * 4];
      const float4 wv = *(const float4*)&sw[kk][tc * 4];
#pragma unroll
      for (int i = 0; i < 4; ++i) {
        const float xv = (i == 0) ? rx.x : (i == 1) ? rx.y : (i == 2) ? rx.z : rx.w;
        acc[i][0] += xv * wv.x; acc[i][1] += xv * wv.y;
        acc[i][2] += xv * wv.z; acc[i][3] += xv * wv.w;
      }
    }
  }

  const float4 bv = *(const float4*)&bc[tc * 4];
#pragma unroll
  for (int i = 0; i < 4; ++i) {
    float4 o;
    o.x = acc[i][0] + bv.x; o.y = acc[i][1] + bv.y;
    o.z = acc[i][2] + bv.z; o.w = acc[i][3] + bv.w;
    *(float4*)&logits[(size_t)(b0 + tr * 4 + i) * 64 + tc * 4] = o;
  }
}

// ---------------------------------------------------------------------------
// combine: inline softmax (wave 0) + gate-weighted expert sums.
// eo layout: [B][20*512] (expert e at columns e*512..e*512+511) -> row-contig.
// ---------------------------------------------------------------------------
__global__ __launch_bounds__(256) void combine_k(
    const unsigned short* __restrict__ eo,   // [8192][10240]
    const float* __restrict__ logits,        // [8192][64]
    unsigned short* __restrict__ tin)        // [8192][2048]
{
  const int b = blockIdx.x;
  const int t = threadIdx.x;
  __shared__ alignas(16) unsigned short lds[20][512];
  __shared__ float gsm[56];
  const unsigned short* er = eo + (size_t)b * 10240;
  unsigned short* ldsf = &lds[0][0];
#pragma unroll
  for (int i = 0; i < 5; ++i) {
    const int c = t + i * 256;               // 0..1279 16B chunks, contiguous
    *(uint4*)&ldsf[c * 8] = *(const uint4*)(er + c * 8);
  }
  if (t < 64) {
    const float v0 = (t < 56) ? logits[(size_t)b * 64 + t] : 0.f;
    const int off[4] = {0, 20, 32, 44};
    const int wd[4]  = {20, 12, 12, 12};
    for (int g = 0; g < 4; ++g) {
      const bool in = (t >= off[g]) && (t < off[g] + wd[g]);
      float vv = in ? v0 : -1e30f;
      float m = vv;
#pragma unroll
      for (int o = 32; o; o >>= 1) m = fmaxf(m, __shfl_xor(m, o));
      float e = in ? __expf(vv - m) : 0.f;
      float s = e;
#pragma unroll
      for (int o = 32; o; o >>= 1) s += __shfl_xor(s, o);
      if (in) gsm[t] = e / s;
    }
  }
  __syncthreads();

  const int sec = t >> 6;
  const int h0 = (t & 63) * 8;
  float acc[8] = {0.f, 0.f, 0.f, 0.f, 0.f, 0.f, 0.f, 0.f};
  if (sec == 0) {
    for (int e = 0; e < 20; ++e) {
      const float w = gsm[e];
#pragma unroll
      for (int j = 0; j < 8; ++j) acc[j] += w * bf2f(lds[e][h0 + j]);
    }
  } else {
    const int goff = 20 + (sec - 1) * 12;
    const int ebase = 8 + (sec - 1) * 4;
    for (int tt = 0; tt < 4; ++tt) {
      const float w = gsm[goff + tt];
#pragma unroll
      for (int j = 0; j < 8; ++j) acc[j] += w * bf2f(lds[ebase + tt][h0 + j]);
    }
    for (int ss = 0; ss < 8; ++ss) {
      const float w = gsm[goff + 4 + ss];
#pragma unroll
      for (int j = 0; j < 8; ++j) acc[j] += w * bf2f(lds[ss][h0 + j]);
    }
  }
  unsigned short* ob = tin + (size_t)b * 2048 + sec * 512 + h0;
  ushort4 u0 = make_ushort4(f2bf(acc[0]), f2bf(acc[1]), f2bf(acc[2]), f2bf(acc[3]));
  ushort4 u1 = make_ushort4(f2bf(acc[4]), f2bf(acc[5]), f2bf(acc[6]), f2bf(acc[7]));
  *(ushort4*)ob = u0;
  *(ushort4*)(ob + 4) = u1;
}

// ---------------------------------------------------------------------------
// final dense: wave per (b, task)
// ---------------------------------------------------------------------------
__global__ __launch_bounds__(256) void outd_k(
    const unsigned short* __restrict__ t2,   // [2][8192][512]
    const float* __restrict__ Wd0, const float* __restrict__ bd0,
    const float* __restrict__ Wd1, const float* __restrict__ bd1,
    float* __restrict__ out)
{
  const int gid = blockIdx.x * 4 + (threadIdx.x >> 6);
  const int lane = threadIdx.x & 63;
  const int b = gid >> 1, task = gid & 1;
  const uint4 raw = *(const uint4*)(t2 + ((size_t)task * 8192 + b) * 512 + lane * 8);
  const unsigned short* rs = (const unsigned short*)&raw;
  float v[8];
#pragma unroll
  for (int j = 0; j < 8; ++j) v[j] = bf2f(rs[j]);
  const float* Wd = task ? Wd1 : Wd0;
  const float* bd = task ? bd1 : bd0;
  const int ncol = task ? 4 : 6;
  float* ob = task ? (out + (size_t)8192 * 6 + (size_t)b * 4) : (out + (size_t)b * 6);
  for (int c = 0; c < ncol; ++c) {
    float p = 0.f;
#pragma unroll
    for (int j = 0; j < 8; ++j) p += v[j] * Wd[(size_t)(lane * 8 + j) * ncol + c];
#pragma unroll
    for (int o = 32; o; o >>= 1) p += __shfl_xor(p, o);
    if (lane == 0) ob[c] = p + bd[c];
  }
}

// ---------------------------------------------------------------------------
extern "C" void kernel_launch(void* const* d_in, const int* in_sizes, int n_in,
                              void* d_out, int out_size, void* d_ws, size_t ws_size,
                              hipStream_t stream) {
  const float* x     = (const float*)d_in[0];
  const float* W1    = (const float*)d_in[1];
  const float* b1    = (const float*)d_in[2];
  const float* W2    = (const float*)d_in[3];
  const float* b2    = (const float*)d_in[4];
  const float* W3    = (const float*)d_in[5];
  const float* b3    = (const float*)d_in[6];
  const float* Wg_sh = (const float*)d_in[7];
  const float* bg_sh = (const float*)d_in[8];
  const float* Wg_sa = (const float*)d_in[9];
  const float* bg_sa = (const float*)d_in[10];
  const float* Wg_ra = (const float*)d_in[11];
  const float* bg_ra = (const float*)d_in[12];
  const float* Wg_ea = (const float*)d_in[13];
  const float* bg_ea = (const float*)d_in[14];
  const float* Wt1   = (const float*)d_in[15];
  const float* bt1   = (const float*)d_in[16];
  const float* Wt2   = (const float*)d_in[17];
  const float* bt2   = (const float*)d_in[18];
  const float* Wd0   = (const float*)d_in[19];
  const float* bd0   = (const float*)d_in[20];
  const float* Wd1   = (const float*)d_in[21];
  const float* bd1   = (const float*)d_in[22];
  float* out = (float*)d_out;

  const int B = 8192, D = 1024, H1 = 2048, H2 = 1024, H3 = 512;
  const int E = 20, TU1 = 1024, TU2 = 512, TIN = 2048;

  auto rnd = [](size_t n) { return (n + 255) & ~(size_t)255; };
  const size_t szXb   = rnd((size_t)B * D * 2);
  const size_t szW1t  = rnd((size_t)E * H1 * D * 2);
  const size_t szW2t  = rnd((size_t)E * H2 * H1 * 2);
  const size_t szW3t  = rnd((size_t)E * H3 * H2 * 2);
  const size_t szWt1t = rnd((size_t)2 * TU1 * TIN * 2);
  const size_t szWt2t = rnd((size_t)2 * TU2 * TU1 * 2);
  const size_t szWcat = rnd((size_t)1024 * 56 * 4);
  const size_t szBcat = rnd((size_t)64 * 4);
  const size_t szLog  = rnd((size_t)B * 64 * 4);
  const size_t szEo   = rnd((size_t)E * B * H3 * 2);
  const size_t szTin  = rnd((size_t)B * TIN * 2);
  const size_t szT1   = rnd((size_t)2 * B * TU1 * 2);
  const size_t szT2   = rnd((size_t)2 * B * TU2 * 2);
  const size_t szH1e  = rnd((size_t)B * H1 * 2);      // per-expert h1 slab
  const size_t szH2e  = rnd((size_t)B * H2 * 2);      // per-expert h2 slab
  const size_t fixed = szXb + szW1t + szW2t + szW3t + szWt1t + szWt2t +
                       szWcat + szBcat + szLog + szEo;
  const size_t tNeed = szTin + szT1 + szT2;            // tower bufs (alias h-region)

  // config ladder: G = expert group size; fullh2 = keep all-20 h2 -> single L3
  int G = 1; bool fullh2 = false;
  {
    const int  gOpt[8]  = {20, 10, 10, 5, 5, 4, 2, 1};
    const bool fOpt[8]  = {true, true, false, true, false, false, false, false};
    for (int i = 0; i < 8; ++i) {
      const size_t h2cnt = fOpt[i] ? (size_t)E : (size_t)gOpt[i];
      size_t hNeed = (size_t)gOpt[i] * szH1e + h2cnt * szH2e;
      if (hNeed < tNeed) hNeed = tNeed;
      if (fixed + hNeed <= ws_size) { G = gOpt[i]; fullh2 = fOpt[i]; break; }
    }
  }

  char* w = (char*)d_ws;
  auto alloc = [&](size_t n) { char* p = w; w += rnd(n); return p; };
  unsigned short* xb   = (unsigned short*)alloc((size_t)B * D * 2);
  unsigned short* W1t  = (unsigned short*)alloc((size_t)E * H1 * D * 2);
  unsigned short* W2t  = (unsigned short*)alloc((size_t)E * H2 * H1 * 2);
  unsigned short* W3t  = (unsigned short*)alloc((size_t)E * H3 * H2 * 2);
  unsigned short* Wt1t = (unsigned short*)alloc((size_t)2 * TU1 * TIN * 2);
  unsigned short* Wt2t = (unsigned short*)alloc((size_t)2 * TU2 * TU1 * 2);
  float*          Wcat = (float*)alloc((size_t)1024 * 56 * 4);
  float*          bcat = (float*)alloc((size_t)64 * 4);
  float*          lgts = (float*)alloc((size_t)B * 64 * 4);
  unsigned short* eo   = (unsigned short*)alloc((size_t)E * B * H3 * 2);
  // h-region: h1 rotating slab + h2 (full-20 or per-group); towers alias whole region
  char* hreg = w;
  unsigned short* h1  = (unsigned short*)hreg;
  unsigned short* h2  = (unsigned short*)(hreg + (size_t)G * szH1e);
  unsigned short* tin = (unsigned short*)hreg;
  unsigned short* t1  = (unsigned short*)(hreg + szTin);
  unsigned short* t2  = (unsigned short*)(hreg + szTin + szT1);
  (void)in_sizes; (void)n_in; (void)out_size;

  auto launch256 = [&](const unsigned short* Ap, int lda, long sA,
                       const unsigned short* Btp, long sB,
                       const float* biasp, long sBias,
                       unsigned short* Outp, int ldo, long sOut,
                       int N, int K, int nz) {
    const int nbx = N / 256, nby = B / 256;
    gemm256<<<dim3(nbx * nby * nz), 512, 0, stream>>>(
        Ap, Btp, biasp, Outp, K, lda, ldo, nbx, nby, sA, sB, sBias, sOut);
  };

  // all conversions in one launch
  conv_all<<<dim3(26368), 256, 0, stream>>>(
      W1, W2, W3, Wt1, Wt2, x, W1t, W2t, W3t, Wt1t, Wt2t, xb);

  // gates
  concat_g<<<dim3((1024 * 56 + 255) / 256), 256, 0, stream>>>(
      Wg_sh, bg_sh, Wg_sa, bg_sa, Wg_ra, bg_ra, Wg_ea, bg_ea, Wcat, bcat);
  gates_gemm<<<dim3(B / 64), 256, 0, stream>>>(x, Wcat, bcat, lgts);

  // experts
  for (int e0 = 0; e0 < E; e0 += G) {
    // L1: xb @ W1 -> h1 (rotating G-slab)
    launch256(xb, D, 0,
              W1t + (size_t)e0 * H1 * D, (long)H1 * D,
              b1 + (size_t)e0 * H1, H1,
              h1, H1, (long)B * H1, H1, D, G);
    // L2: h1 @ W2 -> h2 (absolute slab when fullh2, rotating otherwise)
    unsigned short* h2dst = fullh2 ? (h2 + (size_t)e0 * B * H2) : h2;
    launch256(h1, H1, (long)B * H1,
              W2t + (size_t)e0 * H2 * H1, (long)H2 * H1,
              b2 + (size_t)e0 * H2, H2,
              h2dst, H2, (long)B * H2, H2, H1, G);
    if (!fullh2) {
      // L3 per group
      launch256(h2, H2, (long)B * H2,
                W3t + (size_t)e0 * H3 * H2, (long)H3 * H2,
                b3 + (size_t)e0 * H3, H3,
                eo + (size_t)e0 * H3, E * H3, H3, H3, H2, G);
    }
  }
  if (fullh2) {
    // single L3 over all 20 experts: grid 2*32*20 = 1280 (exactly 5 rounds)
    launch256(h2, H2, (long)B * H2,
              W3t, (long)H3 * H2,
              b3, H3,
              eo, E * H3, H3, H3, H2, E);
  }

  combine_k<<<dim3(B), 256, 0, stream>>>(eo, lgts, tin);

  // towers (z = task)
  launch256(tin, TIN, 0, Wt1t, (long)TU1 * TIN, bt1, TU1,
            t1, TU1, (long)B * TU1, TU1, TIN, 2);
  launch256(t1, TU1, (long)B * TU1, Wt2t, (long)TU2 * TU1, bt2, TU2,
            t2, TU2, (long)B * TU2, TU2, TU1, 2);

  outd_k<<<dim3(B * 2 / 4), 256, 0, stream>>>(t2, Wd0, bd0, Wd1, bd1, out);
}

// Round 8
// 2163.807 us; speedup vs baseline: 1.6954x; 1.0048x over previous
//
#include <hip/hip_runtime.h>

#define DEV __device__ __forceinline__

typedef __bf16 bf16x8 __attribute__((ext_vector_type(8)));
typedef float f32x4 __attribute__((ext_vector_type(4)));

DEV unsigned short f2bf(float f) {
  union { float f; unsigned u; } v; v.f = f;
  unsigned r = v.u + 0x7FFFu + ((v.u >> 16) & 1u);
  return (unsigned short)(r >> 16);
}
DEV float bf2f(unsigned short h) {
  union { float f; unsigned u; } v; v.u = ((unsigned)h) << 16;
  return v.f;
}

// async global->LDS, 16B per lane.
DEV void gload16(const void* g, void* l) {
  __builtin_amdgcn_global_load_lds(
      (__attribute__((address_space(1))) void*)(g),
      (__attribute__((address_space(3))) void*)(l), 16, 0, 0);
}

#define MFMA16(a, b, c) __builtin_amdgcn_mfma_f32_16x16x32_bf16((a), (b), (c), 0, 0, 0)

// ---------------------------------------------------------------------------
// gemm256: Out[r*ldo+c] = lrelu(A[r*lda+k] @ Bt[N][K]^T + bias), bf16 in/out.
// 256x256 tile, BK=64, 512 thr (8 waves 2Mx4N, 128x64 out each).
// 4-phase/K-tile interleave (T3) + counted vmcnt (T4) + setprio (T5) +
// XOR-swizzled LDS via pre-swizzled global source (T2, rule #21) +
// bijective XCD swizzle (T1). PROVEN — do not touch.
// ---------------------------------------------------------------------------
__global__ __launch_bounds__(512) void gemm256(
    const unsigned short* __restrict__ A,
    const unsigned short* __restrict__ Bt,
    const float* __restrict__ bias,
    unsigned short* __restrict__ Out,
    int K, int lda, int ldo, int nbx, int nby,
    long sA, long sB, long sBias, long sOut)
{
  int wg = blockIdx.x;
  {
    const int nwg = gridDim.x;
    const int q = nwg >> 3, r = nwg & 7;
    const int xcd = wg & 7, pos = wg >> 3;
    wg = (xcd < r ? xcd * (q + 1) : r * (q + 1) + (xcd - r) * q) + pos;
  }
  const int per_z = nbx * nby;
  const int z  = wg / per_z;
  const int rz = wg - z * per_z;
  const int by = rz / nbx;
  const int bx = rz - by * nbx;

  A    += (size_t)z * sA;
  Bt   += (size_t)z * sB;
  bias += (size_t)z * sBias;
  Out  += (size_t)z * sOut;

  const int tid  = threadIdx.x;
  const int lane = tid & 63;
  const int wid  = tid >> 6;
  const int wm   = wid >> 2, wn = wid & 3;   // 2 x 4 wave grid
  const int m0   = by * 256, n0 = bx * 256;

  __shared__ alignas(16) char sm[2][65536];  // per buf: A[256][128B] | B[256][128B]

  f32x4 acc[8][4];
  const f32x4 fz = {0.f, 0.f, 0.f, 0.f};
#pragma unroll
  for (int i = 0; i < 8; ++i)
#pragma unroll
    for (int j = 0; j < 4; ++j) acc[i][j] = fz;

  const int rr = tid >> 3;                   // 0..63
  const int ch = (tid & 7) ^ (rr & 7);       // pre-swizzled 16B chunk in 128B row
  const char* gA = (const char*)A  + ((size_t)(m0 + rr) * lda) * 2 + ch * 16;
  const char* gB = (const char*)Bt + ((size_t)(n0 + rr) * K)   * 2 + ch * 16;
  const size_t stepA = (size_t)64 * lda * 2;
  const size_t stepB = (size_t)64 * K * 2;

  // fragment read offsets (swizzle bits 4..6 of the 128B row)
  const int koff0 = (((lane >> 4) << 4) ^ ((lane & 7) << 4)); // ks=0; ks=1 -> ^64
  const int aRow  = wm * 128 + (lane & 15);
  const int bRow  = wn * 64  + (lane & 15);

  const int nkt = K >> 6;

  auto SA = [&](int buf, int kt, int jh) {   // A rows [128*jh, 128*jh+128)
    const char* s = gA + (size_t)kt * 128 + (2 * jh) * stepA;
    char* l = sm[buf] + tid * 16 + (2 * jh) * 8192;
    gload16(s, l);
    gload16(s + stepA, l + 8192);
  };
  auto SB = [&](int buf, int kt, int jh) {   // B rows [128*jh, 128*jh+128)
    const char* s = gB + (size_t)kt * 128 + (2 * jh) * stepB;
    char* l = sm[buf] + 32768 + tid * 16 + (2 * jh) * 8192;
    gload16(s, l);
    gload16(s + stepB, l + 8192);
  };

  // prologue: stage tile 0 fully (8 loads, FIFO)
  SA(0, 0, 0); SA(0, 0, 1); SB(0, 0, 0); SB(0, 0, 1);

  for (int kt = 0; kt < nkt; ++kt) {
    const int cur = kt & 1, nb = cur ^ 1;
    const bool pre = (kt + 1 < nkt);
    if (pre) {
      SA(nb, kt + 1, 0);                                  // 2 newer in flight
      asm volatile("s_waitcnt vmcnt(2)" ::: "memory");    // tile kt landed
    } else {
      asm volatile("s_waitcnt vmcnt(0)" ::: "memory");
    }
    __builtin_amdgcn_s_barrier();                         // tile kt visible to all
    __builtin_amdgcn_sched_barrier(0);

    const char* pA = sm[cur] + aRow * 128;
    const char* pB = sm[cur] + 32768 + bRow * 128;
    bf16x8 a0[4], a1[4], b0[4], b1[4];

    // ---- phase 0: mi 0-3, ks0 (loads b0)
    {
#pragma unroll
      for (int i = 0; i < 4; ++i) a0[i] = *(const bf16x8*)(pA + i * 2048 + koff0);
#pragma unroll
      for (int n = 0; n < 4; ++n) b0[n] = *(const bf16x8*)(pB + n * 2048 + koff0);
      if (pre) SA(nb, kt + 1, 1);
      asm volatile("s_waitcnt lgkmcnt(0)" ::: "memory");
      __builtin_amdgcn_sched_barrier(0);
      __builtin_amdgcn_s_setprio(1);
#pragma unroll
      for (int i = 0; i < 4; ++i)
#pragma unroll
        for (int n = 0; n < 4; ++n) acc[i][n] = MFMA16(a0[i], b0[n], acc[i][n]);
      __builtin_amdgcn_s_setprio(0);
      __builtin_amdgcn_sched_barrier(0);
      __builtin_amdgcn_s_barrier();
      __builtin_amdgcn_sched_barrier(0);
    }
    // ---- phase 1: mi 4-7, ks0 (reuses b0); stage BOTH B-halves for kt+1
    {
#pragma unroll
      for (int i = 0; i < 4; ++i) a1[i] = *(const bf16x8*)(pA + (i + 4) * 2048 + koff0);
      if (pre) { SB(nb, kt + 1, 0); SB(nb, kt + 1, 1); }
      asm volatile("s_waitcnt lgkmcnt(0)" ::: "memory");
      __builtin_amdgcn_sched_barrier(0);
      __builtin_amdgcn_s_setprio(1);
#pragma unroll
      for (int i = 0; i < 4; ++i)
#pragma unroll
        for (int n = 0; n < 4; ++n) acc[i + 4][n] = MFMA16(a1[i], b0[n], acc[i + 4][n]);
      __builtin_amdgcn_s_setprio(0);
      __builtin_amdgcn_sched_barrier(0);
      __builtin_amdgcn_s_barrier();
      __builtin_amdgcn_sched_barrier(0);
    }
    // ---- phase 2: mi 0-3, ks1 (loads b1)
    {
      const int ko = koff0 ^ 64;
#pragma unroll
      for (int i = 0; i < 4; ++i) a0[i] = *(const bf16x8*)(pA + i * 2048 + ko);
#pragma unroll
      for (int n = 0; n < 4; ++n) b1[n] = *(const bf16x8*)(pB + n * 2048 + ko);
      asm volatile("s_waitcnt lgkmcnt(0)" ::: "memory");
      __builtin_amdgcn_sched_barrier(0);
      __builtin_amdgcn_s_setprio(1);
#pragma unroll
      for (int i = 0; i < 4; ++i)
#pragma unroll
        for (int n = 0; n < 4; ++n) acc[i][n] = MFMA16(a0[i], b1[n], acc[i][n]);
      __builtin_amdgcn_s_setprio(0);
      __builtin_amdgcn_sched_barrier(0);
      __builtin_amdgcn_s_barrier();
      __builtin_amdgcn_sched_barrier(0);
    }
    // ---- phase 3: mi 4-7, ks1
    {
      const int ko = koff0 ^ 64;
#pragma unroll
      for (int i = 0; i < 4; ++i) a1[i] = *(const bf16x8*)(pA + (i + 4) * 2048 + ko);
      asm volatile("s_waitcnt lgkmcnt(0)" ::: "memory");
      __builtin_amdgcn_sched_barrier(0);
      __builtin_amdgcn_s_setprio(1);
#pragma unroll
      for (int i = 0; i < 4; ++i)
#pragma unroll
        for (int n = 0; n < 4; ++n) acc[i + 4][n] = MFMA16(a1[i], b1[n], acc[i + 4][n]);
      __builtin_amdgcn_s_setprio(0);
      __builtin_amdgcn_sched_barrier(0);
      __builtin_amdgcn_s_barrier();   // all reads of buf[cur] done before next SA
      __builtin_amdgcn_sched_barrier(0);
    }
  }

  // epilogue: bias + lrelu + bf16 store (C/D: col=lane&15, row=(lane>>4)*4+j)
#pragma unroll
  for (int ni = 0; ni < 4; ++ni) {
    const int c = n0 + wn * 64 + ni * 16 + (lane & 15);
    const float bv = bias[c];
#pragma unroll
    for (int mi = 0; mi < 8; ++mi) {
      const int r0 = m0 + wm * 128 + mi * 16 + ((lane >> 4) << 2);
#pragma unroll
      for (int j = 0; j < 4; ++j) {
        float v = acc[mi][ni][j] + bv;
        v = v >= 0.f ? v : 0.1f * v;
        Out[(size_t)(r0 + j) * ldo + c] = f2bf(v);
      }
    }
  }
}

// ---------------------------------------------------------------------------
// gate weight/bias gather (concatenated column space: sh20|sa12|ra12|ea12, pad 0)
// ---------------------------------------------------------------------------
DEV float gateW(const float* Wsh, const float* Wsa, const float* Wra,
                const float* Wea, int k, int c) {
  if (c < 20) return Wsh[(size_t)k * 20 + c];
  if (c < 32) return Wsa[(size_t)k * 12 + (c - 20)];
  if (c < 44) return Wra[(size_t)k * 12 + (c - 32)];
  if (c < 56) return Wea[(size_t)k * 12 + (c - 44)];
  return 0.f;
}
DEV float gateB(const float* bsh, const float* bsa, const float* bra,
                const float* bea, int c) {
  if (c < 20) return bsh[c];
  if (c < 32) return bsa[c - 20];
  if (c < 44) return bra[c - 32];
  if (c < 56) return bea[c - 44];
  return 0.f;
}

// ---------------------------------------------------------------------------
// prep_all: ONE launch for gate logits + all fp32->bf16 conversions.
// Segments by blockIdx.x:
//   [0,128):        gate logits, 64 rows/block (fp32 micro-GEMM, reads raw W/b)
//   [128,24448):    weight transposes (W1,W2,W3,Wt1,Wt2), 64x64 tiles
//   [24448,26496):  x straight convert
// ---------------------------------------------------------------------------
__global__ __launch_bounds__(256) void prep_all(
    const float* __restrict__ W1,  const float* __restrict__ W2,
    const float* __restrict__ W3,  const float* __restrict__ Wt1,
    const float* __restrict__ Wt2, const float* __restrict__ x,
    const float* __restrict__ Wsh, const float* __restrict__ bsh,
    const float* __restrict__ Wsa, const float* __restrict__ bsa,
    const float* __restrict__ Wra, const float* __restrict__ bra,
    const float* __restrict__ Wea, const float* __restrict__ bea,
    unsigned short* __restrict__ W1t,  unsigned short* __restrict__ W2t,
    unsigned short* __restrict__ W3t,  unsigned short* __restrict__ Wt1t,
    unsigned short* __restrict__ Wt2t, unsigned short* __restrict__ xb,
    float* __restrict__ logits)
{
  __shared__ alignas(16) char smem[16384];
  const int id = blockIdx.x;
  const int t  = threadIdx.x;

  if (id < 128) {
    // ---- gates segment: logits[b0+0..63][0..63]
    float (*sx)[64] = (float (*)[64])smem;            // [32][64] k-major x
    float (*sw)[64] = (float (*)[64])(smem + 8192);   // [32][64] k-major W
    const int b0 = id * 64;
    const int tr = t >> 4, tc = t & 15;
    float acc[4][4] = {};

    for (int kt = 0; kt < 32; ++kt) {
      const int k0 = kt * 32;
      __syncthreads();
#pragma unroll
      for (int it = 0; it < 2; ++it) {
        const int idx = t + it * 256;
        const int r = idx >> 3, c4 = (idx & 7) * 4;
        const float4 v = *(const float4*)(x + (size_t)(b0 + r) * 1024 + k0 + c4);
        sx[c4 + 0][r] = v.x; sx[c4 + 1][r] = v.y;
        sx[c4 + 2][r] = v.z; sx[c4 + 3][r] = v.w;
      }
#pragma unroll
      for (int it = 0; it < 2; ++it) {
        const int idx = t + it * 256;     // 0..511
        const int row = idx >> 4;         // 0..31
        const int c4  = (idx & 15) * 4;   // 0..60
#pragma unroll
        for (int j = 0; j < 4; ++j)
          sw[row][c4 + j] = gateW(Wsh, Wsa, Wra, Wea, k0 + row, c4 + j);
      }
      __syncthreads();
#pragma unroll
      for (int kk = 0; kk < 32; ++kk) {
        const float4 rx = *(const float4*)&sx[kk][tr * 4];
        const float4 wv = *(const float4*)&sw[kk][tc * 4];
#pragma unroll
        for (int i = 0; i < 4; ++i) {
          const float xv = (i == 0) ? rx.x : (i == 1) ? rx.y : (i == 2) ? rx.z : rx.w;
          acc[i][0] += xv * wv.x; acc[i][1] += xv * wv.y;
          acc[i][2] += xv * wv.z; acc[i][3] += xv * wv.w;
        }
      }
    }
    float bv[4];
#pragma unroll
    for (int j = 0; j < 4; ++j) bv[j] = gateB(bsh, bsa, bra, bea, tc * 4 + j);
#pragma unroll
    for (int i = 0; i < 4; ++i) {
      float4 o;
      o.x = acc[i][0] + bv[0]; o.y = acc[i][1] + bv[1];
      o.z = acc[i][2] + bv[2]; o.w = acc[i][3] + bv[3];
      *(float4*)&logits[(size_t)(b0 + tr * 4 + i) * 64 + tc * 4] = o;
    }
    return;
  }

  if (id >= 24448) {                 // x straight convert
    const int local = id - 24448;    // 0..2047; x is [8192][1024]
    const int r0 = (local >> 4) * 64, c0 = (local & 15) * 64;
#pragma unroll
    for (int i = 0; i < 4; ++i) {
      const int row = r0 + i * 16 + (t >> 4);
      const int col = c0 + (t & 15) * 4;
      const float4 v = *(const float4*)(x + (size_t)row * 1024 + col);
      ushort4 u = make_ushort4(f2bf(v.x), f2bf(v.y), f2bf(v.z), f2bf(v.w));
      *(ushort4*)(xb + (size_t)row * 1024 + col) = u;
    }
    return;
  }

  // ---- weight transposes
  const int wid2 = id - 128;
  const float* src; unsigned short* dst; int K, N, local;
  if (wid2 < 10240)      { src = W1;  dst = W1t;  K = 1024; N = 2048; local = wid2; }
  else if (wid2 < 20480) { src = W2;  dst = W2t;  K = 2048; N = 1024; local = wid2 - 10240; }
  else if (wid2 < 23040) { src = W3;  dst = W3t;  K = 1024; N = 512;  local = wid2 - 20480; }
  else if (wid2 < 24064) { src = Wt1; dst = Wt1t; K = 2048; N = 1024; local = wid2 - 23040; }
  else                   { src = Wt2; dst = Wt2t; K = 1024; N = 512;  local = wid2 - 24064; }

  const int nkt = K >> 6, nnt = N >> 6;
  const int per_z = nkt * nnt;
  const int z   = local / per_z;
  const int rem = local - z * per_z;
  const int k0  = (rem % nkt) * 64;
  const int n0  = (rem / nkt) * 64;
  src += (size_t)z * K * N;
  dst += (size_t)z * K * N;

  unsigned short (*lds)[68] = (unsigned short (*)[68])smem;  // [64][68]
  const int cr = t >> 4;
  const int cc = (t & 15) * 4;
#pragma unroll
  for (int i = 0; i < 4; ++i) {
    const int row = i * 16 + cr;
    const float4 v = *(const float4*)(src + (size_t)(k0 + row) * N + n0 + cc);
    lds[row][cc + 0] = f2bf(v.x); lds[row][cc + 1] = f2bf(v.y);
    lds[row][cc + 2] = f2bf(v.z); lds[row][cc + 3] = f2bf(v.w);
  }
  __syncthreads();
#pragma unroll
  for (int i = 0; i < 4; ++i) {
    const int nrow = i * 16 + cr;
    ushort4 u = make_ushort4(lds[cc + 0][nrow], lds[cc + 1][nrow],
                             lds[cc + 2][nrow], lds[cc + 3][nrow]);
    *(ushort4*)(dst + (size_t)(n0 + nrow) * K + k0 + cc) = u;
  }
}

// ---------------------------------------------------------------------------
// combine: async eo-row staging (global_load_lds) overlapped with softmax,
// then gate-weighted expert sums.
// eo layout: [B][20*512] (expert e at columns e*512..) -> row-contiguous.
// ---------------------------------------------------------------------------
__global__ __launch_bounds__(256) void combine_k(
    const unsigned short* __restrict__ eo,   // [8192][10240]
    const float* __restrict__ logits,        // [8192][64]
    unsigned short* __restrict__ tin)        // [8192][2048]
{
  const int b = blockIdx.x;
  const int t = threadIdx.x;
  __shared__ alignas(16) unsigned short lds[20][512];
  __shared__ float gsm[56];
  const unsigned short* er = eo + (size_t)b * 10240;
  unsigned short* ldsf = &lds[0][0];
  // async stage: 5 x (256 lanes x 16B) = 20480B, linear dest (wave-uniform+lane*16)
#pragma unroll
  for (int i = 0; i < 5; ++i)
    gload16(er + (i * 256 + t) * 8, ldsf + (i * 256 + t) * 8);

  // softmax while the staging loads are in flight
  if (t < 64) {
    const float v0 = (t < 56) ? logits[(size_t)b * 64 + t] : 0.f;
    const int off[4] = {0, 20, 32, 44};
    const int wd[4]  = {20, 12, 12, 12};
    for (int g = 0; g < 4; ++g) {
      const bool in = (t >= off[g]) && (t < off[g] + wd[g]);
      float vv = in ? v0 : -1e30f;
      float m = vv;
#pragma unroll
      for (int o = 32; o; o >>= 1) m = fmaxf(m, __shfl_xor(m, o));
      float e = in ? __expf(vv - m) : 0.f;
      float s = e;
#pragma unroll
      for (int o = 32; o; o >>= 1) s += __shfl_xor(s, o);
      if (in) gsm[t] = e / s;
    }
  }
  __syncthreads();   // drains vmcnt (gload_lds) + lgkm and barriers

  const int sec = t >> 6;
  const int h0 = (t & 63) * 8;
  float acc[8] = {0.f, 0.f, 0.f, 0.f, 0.f, 0.f, 0.f, 0.f};
  if (sec == 0) {
    for (int e = 0; e < 20; ++e) {
      const float w = gsm[e];
#pragma unroll
      for (int j = 0; j < 8; ++j) acc[j] += w * bf2f(lds[e][h0 + j]);
    }
  } else {
    const int goff = 20 + (sec - 1) * 12;
    const int ebase = 8 + (sec - 1) * 4;
    for (int tt = 0; tt < 4; ++tt) {
      const float w = gsm[goff + tt];
#pragma unroll
      for (int j = 0; j < 8; ++j) acc[j] += w * bf2f(lds[ebase + tt][h0 + j]);
    }
    for (int ss = 0; ss < 8; ++ss) {
      const float w = gsm[goff + 4 + ss];
#pragma unroll
      for (int j = 0; j < 8; ++j) acc[j] += w * bf2f(lds[ss][h0 + j]);
    }
  }
  unsigned short* ob = tin + (size_t)b * 2048 + sec * 512 + h0;
  ushort4 u0 = make_ushort4(f2bf(acc[0]), f2bf(acc[1]), f2bf(acc[2]), f2bf(acc[3]));
  ushort4 u1 = make_ushort4(f2bf(acc[4]), f2bf(acc[5]), f2bf(acc[6]), f2bf(acc[7]));
  *(ushort4*)ob = u0;
  *(ushort4*)(ob + 4) = u1;
}

// ---------------------------------------------------------------------------
// final dense: wave per (b, task)
// ---------------------------------------------------------------------------
__global__ __launch_bounds__(256) void outd_k(
    const unsigned short* __restrict__ t2,   // [2][8192][512]
    const float* __restrict__ Wd0, const float* __restrict__ bd0,
    const float* __restrict__ Wd1, const float* __restrict__ bd1,
    float* __restrict__ out)
{
  const int gid = blockIdx.x * 4 + (threadIdx.x >> 6);
  const int lane = threadIdx.x & 63;
  const int b = gid >> 1, task = gid & 1;
  const uint4 raw = *(const uint4*)(t2 + ((size_t)task * 8192 + b) * 512 + lane * 8);
  const unsigned short* rs = (const unsigned short*)&raw;
  float v[8];
#pragma unroll
  for (int j = 0; j < 8; ++j) v[j] = bf2f(rs[j]);
  const float* Wd = task ? Wd1 : Wd0;
  const float* bd = task ? bd1 : bd0;
  const int ncol = task ? 4 : 6;
  float* ob = task ? (out + (size_t)8192 * 6 + (size_t)b * 4) : (out + (size_t)b * 6);
  for (int c = 0; c < ncol; ++c) {
    float p = 0.f;
#pragma unroll
    for (int j = 0; j < 8; ++j) p += v[j] * Wd[(size_t)(lane * 8 + j) * ncol + c];
#pragma unroll
    for (int o = 32; o; o >>= 1) p += __shfl_xor(p, o);
    if (lane == 0) ob[c] = p + bd[c];
  }
}

// ---------------------------------------------------------------------------
extern "C" void kernel_launch(void* const* d_in, const int* in_sizes, int n_in,
                              void* d_out, int out_size, void* d_ws, size_t ws_size,
                              hipStream_t stream) {
  const float* x     = (const float*)d_in[0];
  const float* W1    = (const float*)d_in[1];
  const float* b1    = (const float*)d_in[2];
  const float* W2    = (const float*)d_in[3];
  const float* b2    = (const float*)d_in[4];
  const float* W3    = (const float*)d_in[5];
  const float* b3    = (const float*)d_in[6];
  const float* Wg_sh = (const float*)d_in[7];
  const float* bg_sh = (const float*)d_in[8];
  const float* Wg_sa = (const float*)d_in[9];
  const float* bg_sa = (const float*)d_in[10];
  const float* Wg_ra = (const float*)d_in[11];
  const float* bg_ra = (const float*)d_in[12];
  const float* Wg_ea = (const float*)d_in[13];
  const float* bg_ea = (const float*)d_in[14];
  const float* Wt1   = (const float*)d_in[15];
  const float* bt1   = (const float*)d_in[16];
  const float* Wt2   = (const float*)d_in[17];
  const float* bt2   = (const float*)d_in[18];
  const float* Wd0   = (const float*)d_in[19];
  const float* bd0   = (const float*)d_in[20];
  const float* Wd1   = (const float*)d_in[21];
  const float* bd1   = (const float*)d_in[22];
  float* out = (float*)d_out;

  const int B = 8192, D = 1024, H1 = 2048, H2 = 1024, H3 = 512;
  const int E = 20, TU1 = 1024, TU2 = 512, TIN = 2048;

  auto rnd = [](size_t n) { return (n + 255) & ~(size_t)255; };
  const size_t szXb   = rnd((size_t)B * D * 2);
  const size_t szW1t  = rnd((size_t)E * H1 * D * 2);
  const size_t szW2t  = rnd((size_t)E * H2 * H1 * 2);
  const size_t szW3t  = rnd((size_t)E * H3 * H2 * 2);
  const size_t szWt1t = rnd((size_t)2 * TU1 * TIN * 2);
  const size_t szWt2t = rnd((size_t)2 * TU2 * TU1 * 2);
  const size_t szLog  = rnd((size_t)B * 64 * 4);
  const size_t szEo   = rnd((size_t)E * B * H3 * 2);
  const size_t szTin  = rnd((size_t)B * TIN * 2);
  const size_t szT1   = rnd((size_t)2 * B * TU1 * 2);
  const size_t szT2   = rnd((size_t)2 * B * TU2 * 2);
  const size_t szH1e  = rnd((size_t)B * H1 * 2);
  const size_t szH2e  = rnd((size_t)B * H2 * 2);
  const size_t fixed = szXb + szW1t + szW2t + szW3t + szWt1t + szWt2t +
                       szLog + szEo;
  const size_t tNeed = szTin + szT1 + szT2;

  // config ladder: G = expert group size; fullh2 -> single L3 launch
  int G = 1; bool fullh2 = false;
  {
    const int  gOpt[8]  = {20, 10, 10, 5, 5, 4, 2, 1};
    const bool fOpt[8]  = {true, true, false, true, false, false, false, false};
    for (int i = 0; i < 8; ++i) {
      const size_t h2cnt = fOpt[i] ? (size_t)E : (size_t)gOpt[i];
      size_t hNeed = (size_t)gOpt[i] * szH1e + h2cnt * szH2e;
      if (hNeed < tNeed) hNeed = tNeed;
      if (fixed + hNeed <= ws_size) { G = gOpt[i]; fullh2 = fOpt[i]; break; }
    }
  }

  char* w = (char*)d_ws;
  auto alloc = [&](size_t n) { char* p = w; w += rnd(n); return p; };
  unsigned short* xb   = (unsigned short*)alloc((size_t)B * D * 2);
  unsigned short* W1t  = (unsigned short*)alloc((size_t)E * H1 * D * 2);
  unsigned short* W2t  = (unsigned short*)alloc((size_t)E * H2 * H1 * 2);
  unsigned short* W3t  = (unsigned short*)alloc((size_t)E * H3 * H2 * 2);
  unsigned short* Wt1t = (unsigned short*)alloc((size_t)2 * TU1 * TIN * 2);
  unsigned short* Wt2t = (unsigned short*)alloc((size_t)2 * TU2 * TU1 * 2);
  float*          lgts = (float*)alloc((size_t)B * 64 * 4);
  unsigned short* eo   = (unsigned short*)alloc((size_t)E * B * H3 * 2);
  char* hreg = w;
  unsigned short* h1  = (unsigned short*)hreg;
  unsigned short* h2  = (unsigned short*)(hreg + (size_t)G * szH1e);
  unsigned short* tin = (unsigned short*)hreg;
  unsigned short* t1  = (unsigned short*)(hreg + szTin);
  unsigned short* t2  = (unsigned short*)(hreg + szTin + szT1);
  (void)in_sizes; (void)n_in; (void)out_size;

  auto launch256 = [&](const unsigned short* Ap, int lda, long sA,
                       const unsigned short* Btp, long sB,
                       const float* biasp, long sBias,
                       unsigned short* Outp, int ldo, long sOut,
                       int N, int K, int nz) {
    const int nbx = N / 256, nby = B / 256;
    gemm256<<<dim3(nbx * nby * nz), 512, 0, stream>>>(
        Ap, Btp, biasp, Outp, K, lda, ldo, nbx, nby, sA, sB, sBias, sOut);
  };

  // ONE prep launch: gate logits + all conversions/transposes
  prep_all<<<dim3(26496), 256, 0, stream>>>(
      W1, W2, W3, Wt1, Wt2, x,
      Wg_sh, bg_sh, Wg_sa, bg_sa, Wg_ra, bg_ra, Wg_ea, bg_ea,
      W1t, W2t, W3t, Wt1t, Wt2t, xb, lgts);

  // experts
  for (int e0 = 0; e0 < E; e0 += G) {
    launch256(xb, D, 0,
              W1t + (size_t)e0 * H1 * D, (long)H1 * D,
              b1 + (size_t)e0 * H1, H1,
              h1, H1, (long)B * H1, H1, D, G);
    unsigned short* h2dst = fullh2 ? (h2 + (size_t)e0 * B * H2) : h2;
    launch256(h1, H1, (long)B * H1,
              W2t + (size_t)e0 * H2 * H1, (long)H2 * H1,
              b2 + (size_t)e0 * H2, H2,
              h2dst, H2, (long)B * H2, H2, H1, G);
    if (!fullh2) {
      launch256(h2, H2, (long)B * H2,
                W3t + (size_t)e0 * H3 * H2, (long)H3 * H2,
                b3 + (size_t)e0 * H3, H3,
                eo + (size_t)e0 * H3, E * H3, H3, H3, H2, G);
    }
  }
  if (fullh2) {
    launch256(h2, H2, (long)B * H2,
              W3t, (long)H3 * H2,
              b3, H3,
              eo, E * H3, H3, H3, H2, E);
  }

  combine_k<<<dim3(B), 256, 0, stream>>>(eo, lgts, tin);

  // towers (z = task)
  launch256(tin, TIN, 0, Wt1t, (long)TU1 * TIN, bt1, TU1,
            t1, TU1, (long)B * TU1, TU1, TIN, 2);
  launch256(t1, TU1, (long)B * TU1, Wt2t, (long)TU2 * TU1, bt2, TU2,
            t2, TU2, (long)B * TU2, TU2, TU1, 2);

  outd_k<<<dim3(B * 2 / 4), 256, 0, stream>>>(t2, Wd0, bd0, Wd1, bd1, out);
}

// Round 9
// 2111.488 us; speedup vs baseline: 1.7374x; 1.0248x over previous
//
#include <hip/hip_runtime.h>

#define DEV __device__ __forceinline__

typedef __bf16 bf16x8 __attribute__((ext_vector_type(8)));
typedef float f32x4 __attribute__((ext_vector_type(4)));

DEV unsigned short f2bf(float f) {
  union { float f; unsigned u; } v; v.f = f;
  unsigned r = v.u + 0x7FFFu + ((v.u >> 16) & 1u);
  return (unsigned short)(r >> 16);
}
DEV float bf2f(unsigned short h) {
  union { float f; unsigned u; } v; v.u = ((unsigned)h) << 16;
  return v.f;
}

// async global->LDS, 16B per lane.
DEV void gload16(const void* g, void* l) {
  __builtin_amdgcn_global_load_lds(
      (__attribute__((address_space(1))) void*)(g),
      (__attribute__((address_space(3))) void*)(l), 16, 0, 0);
}

#define MFMA16(a, b, c) __builtin_amdgcn_mfma_f32_16x16x32_bf16((a), (b), (c), 0, 0, 0)

// ---------------------------------------------------------------------------
// gemm256: Out[r*ldo+c] = lrelu(A[r*lda+k] @ Bt[N][K]^T + bias), bf16 in/out.
// 256x256 tile, BK=64, 512 thr (8 waves 2Mx4N, 128x64 out each).
// 4-phase/K-tile interleave (T3) + counted vmcnt (T4) + setprio (T5) +
// XOR-swizzled LDS via pre-swizzled global source (T2, rule #21) +
// bijective XCD swizzle (T1). PROVEN — do not touch.
// ---------------------------------------------------------------------------
__global__ __launch_bounds__(512) void gemm256(
    const unsigned short* __restrict__ A,
    const unsigned short* __restrict__ Bt,
    const float* __restrict__ bias,
    unsigned short* __restrict__ Out,
    int K, int lda, int ldo, int nbx, int nby,
    long sA, long sB, long sBias, long sOut)
{
  int wg = blockIdx.x;
  {
    const int nwg = gridDim.x;
    const int q = nwg >> 3, r = nwg & 7;
    const int xcd = wg & 7, pos = wg >> 3;
    wg = (xcd < r ? xcd * (q + 1) : r * (q + 1) + (xcd - r) * q) + pos;
  }
  const int per_z = nbx * nby;
  const int z  = wg / per_z;
  const int rz = wg - z * per_z;
  const int by = rz / nbx;
  const int bx = rz - by * nbx;

  A    += (size_t)z * sA;
  Bt   += (size_t)z * sB;
  bias += (size_t)z * sBias;
  Out  += (size_t)z * sOut;

  const int tid  = threadIdx.x;
  const int lane = tid & 63;
  const int wid  = tid >> 6;
  const int wm   = wid >> 2, wn = wid & 3;   // 2 x 4 wave grid
  const int m0   = by * 256, n0 = bx * 256;

  __shared__ alignas(16) char sm[2][65536];  // per buf: A[256][128B] | B[256][128B]

  f32x4 acc[8][4];
  const f32x4 fz = {0.f, 0.f, 0.f, 0.f};
#pragma unroll
  for (int i = 0; i < 8; ++i)
#pragma unroll
    for (int j = 0; j < 4; ++j) acc[i][j] = fz;

  const int rr = tid >> 3;                   // 0..63
  const int ch = (tid & 7) ^ (rr & 7);       // pre-swizzled 16B chunk in 128B row
  const char* gA = (const char*)A  + ((size_t)(m0 + rr) * lda) * 2 + ch * 16;
  const char* gB = (const char*)Bt + ((size_t)(n0 + rr) * K)   * 2 + ch * 16;
  const size_t stepA = (size_t)64 * lda * 2;
  const size_t stepB = (size_t)64 * K * 2;

  // fragment read offsets (swizzle bits 4..6 of the 128B row)
  const int koff0 = (((lane >> 4) << 4) ^ ((lane & 7) << 4)); // ks=0; ks=1 -> ^64
  const int aRow  = wm * 128 + (lane & 15);
  const int bRow  = wn * 64  + (lane & 15);

  const int nkt = K >> 6;

  auto SA = [&](int buf, int kt, int jh) {   // A rows [128*jh, 128*jh+128)
    const char* s = gA + (size_t)kt * 128 + (2 * jh) * stepA;
    char* l = sm[buf] + tid * 16 + (2 * jh) * 8192;
    gload16(s, l);
    gload16(s + stepA, l + 8192);
  };
  auto SB = [&](int buf, int kt, int jh) {   // B rows [128*jh, 128*jh+128)
    const char* s = gB + (size_t)kt * 128 + (2 * jh) * stepB;
    char* l = sm[buf] + 32768 + tid * 16 + (2 * jh) * 8192;
    gload16(s, l);
    gload16(s + stepB, l + 8192);
  };

  // prologue: stage tile 0 fully (8 loads, FIFO)
  SA(0, 0, 0); SA(0, 0, 1); SB(0, 0, 0); SB(0, 0, 1);

  for (int kt = 0; kt < nkt; ++kt) {
    const int cur = kt & 1, nb = cur ^ 1;
    const bool pre = (kt + 1 < nkt);
    if (pre) {
      SA(nb, kt + 1, 0);                                  // 2 newer in flight
      asm volatile("s_waitcnt vmcnt(2)" ::: "memory");    // tile kt landed
    } else {
      asm volatile("s_waitcnt vmcnt(0)" ::: "memory");
    }
    __builtin_amdgcn_s_barrier();                         // tile kt visible to all
    __builtin_amdgcn_sched_barrier(0);

    const char* pA = sm[cur] + aRow * 128;
    const char* pB = sm[cur] + 32768 + bRow * 128;
    bf16x8 a0[4], a1[4], b0[4], b1[4];

    // ---- phase 0: mi 0-3, ks0 (loads b0)
    {
#pragma unroll
      for (int i = 0; i < 4; ++i) a0[i] = *(const bf16x8*)(pA + i * 2048 + koff0);
#pragma unroll
      for (int n = 0; n < 4; ++n) b0[n] = *(const bf16x8*)(pB + n * 2048 + koff0);
      if (pre) SA(nb, kt + 1, 1);
      asm volatile("s_waitcnt lgkmcnt(0)" ::: "memory");
      __builtin_amdgcn_sched_barrier(0);
      __builtin_amdgcn_s_setprio(1);
#pragma unroll
      for (int i = 0; i < 4; ++i)
#pragma unroll
        for (int n = 0; n < 4; ++n) acc[i][n] = MFMA16(a0[i], b0[n], acc[i][n]);
      __builtin_amdgcn_s_setprio(0);
      __builtin_amdgcn_sched_barrier(0);
      __builtin_amdgcn_s_barrier();
      __builtin_amdgcn_sched_barrier(0);
    }
    // ---- phase 1: mi 4-7, ks0 (reuses b0); stage BOTH B-halves for kt+1
    {
#pragma unroll
      for (int i = 0; i < 4; ++i) a1[i] = *(const bf16x8*)(pA + (i + 4) * 2048 + koff0);
      if (pre) { SB(nb, kt + 1, 0); SB(nb, kt + 1, 1); }
      asm volatile("s_waitcnt lgkmcnt(0)" ::: "memory");
      __builtin_amdgcn_sched_barrier(0);
      __builtin_amdgcn_s_setprio(1);
#pragma unroll
      for (int i = 0; i < 4; ++i)
#pragma unroll
        for (int n = 0; n < 4; ++n) acc[i + 4][n] = MFMA16(a1[i], b0[n], acc[i + 4][n]);
      __builtin_amdgcn_s_setprio(0);
      __builtin_amdgcn_sched_barrier(0);
      __builtin_amdgcn_s_barrier();
      __builtin_amdgcn_sched_barrier(0);
    }
    // ---- phase 2: mi 0-3, ks1 (loads b1)
    {
      const int ko = koff0 ^ 64;
#pragma unroll
      for (int i = 0; i < 4; ++i) a0[i] = *(const bf16x8*)(pA + i * 2048 + ko);
#pragma unroll
      for (int n = 0; n < 4; ++n) b1[n] = *(const bf16x8*)(pB + n * 2048 + ko);
      asm volatile("s_waitcnt lgkmcnt(0)" ::: "memory");
      __builtin_amdgcn_sched_barrier(0);
      __builtin_amdgcn_s_setprio(1);
#pragma unroll
      for (int i = 0; i < 4; ++i)
#pragma unroll
        for (int n = 0; n < 4; ++n) acc[i][n] = MFMA16(a0[i], b1[n], acc[i][n]);
      __builtin_amdgcn_s_setprio(0);
      __builtin_amdgcn_sched_barrier(0);
      __builtin_amdgcn_s_barrier();
      __builtin_amdgcn_sched_barrier(0);
    }
    // ---- phase 3: mi 4-7, ks1
    {
      const int ko = koff0 ^ 64;
#pragma unroll
      for (int i = 0; i < 4; ++i) a1[i] = *(const bf16x8*)(pA + (i + 4) * 2048 + ko);
      asm volatile("s_waitcnt lgkmcnt(0)" ::: "memory");
      __builtin_amdgcn_sched_barrier(0);
      __builtin_amdgcn_s_setprio(1);
#pragma unroll
      for (int i = 0; i < 4; ++i)
#pragma unroll
        for (int n = 0; n < 4; ++n) acc[i + 4][n] = MFMA16(a1[i], b1[n], acc[i + 4][n]);
      __builtin_amdgcn_s_setprio(0);
      __builtin_amdgcn_sched_barrier(0);
      __builtin_amdgcn_s_barrier();   // all reads of buf[cur] done before next SA
      __builtin_amdgcn_sched_barrier(0);
    }
  }

  // epilogue: bias + lrelu + bf16 store (C/D: col=lane&15, row=(lane>>4)*4+j)
#pragma unroll
  for (int ni = 0; ni < 4; ++ni) {
    const int c = n0 + wn * 64 + ni * 16 + (lane & 15);
    const float bv = bias[c];
#pragma unroll
    for (int mi = 0; mi < 8; ++mi) {
      const int r0 = m0 + wm * 128 + mi * 16 + ((lane >> 4) << 2);
#pragma unroll
      for (int j = 0; j < 4; ++j) {
        float v = acc[mi][ni][j] + bv;
        v = v >= 0.f ? v : 0.1f * v;
        Out[(size_t)(r0 + j) * ldo + c] = f2bf(v);
      }
    }
  }
}

// ---------------------------------------------------------------------------
// gate weight/bias gather (concatenated column space: sh20|sa12|ra12|ea12, pad 0)
// ---------------------------------------------------------------------------
DEV float gateW(const float* Wsh, const float* Wsa, const float* Wra,
                const float* Wea, int k, int c) {
  if (c < 20) return Wsh[(size_t)k * 20 + c];
  if (c < 32) return Wsa[(size_t)k * 12 + (c - 20)];
  if (c < 44) return Wra[(size_t)k * 12 + (c - 32)];
  if (c < 56) return Wea[(size_t)k * 12 + (c - 44)];
  return 0.f;
}
DEV float gateB(const float* bsh, const float* bsa, const float* bra,
                const float* bea, int c) {
  if (c < 20) return bsh[c];
  if (c < 32) return bsa[c - 20];
  if (c < 44) return bra[c - 32];
  if (c < 56) return bea[c - 44];
  return 0.f;
}

// ---------------------------------------------------------------------------
// prep_all: ONE launch for gate logits + all fp32->bf16 conversions.
// Segments by blockIdx.x:
//   [0,128):        gate logits, 64 rows/block (fp32 micro-GEMM, reads raw W/b)
//   [128,24448):    weight transposes (W1,W2,W3,Wt1,Wt2), 64x64 tiles
//   [24448,26496):  x straight convert
// Transpose LDS pad = 66 shorts (132B): column-gather stride -> 2-way (free).
// ---------------------------------------------------------------------------
__global__ __launch_bounds__(256) void prep_all(
    const float* __restrict__ W1,  const float* __restrict__ W2,
    const float* __restrict__ W3,  const float* __restrict__ Wt1,
    const float* __restrict__ Wt2, const float* __restrict__ x,
    const float* __restrict__ Wsh, const float* __restrict__ bsh,
    const float* __restrict__ Wsa, const float* __restrict__ bsa,
    const float* __restrict__ Wra, const float* __restrict__ bra,
    const float* __restrict__ Wea, const float* __restrict__ bea,
    unsigned short* __restrict__ W1t,  unsigned short* __restrict__ W2t,
    unsigned short* __restrict__ W3t,  unsigned short* __restrict__ Wt1t,
    unsigned short* __restrict__ Wt2t, unsigned short* __restrict__ xb,
    float* __restrict__ logits)
{
  __shared__ alignas(16) char smem[16384];
  const int id = blockIdx.x;
  const int t  = threadIdx.x;

  if (id < 128) {
    // ---- gates segment: logits[b0+0..63][0..63]
    float (*sx)[64] = (float (*)[64])smem;            // [32][64] k-major x
    float (*sw)[64] = (float (*)[64])(smem + 8192);   // [32][64] k-major W
    const int b0 = id * 64;
    const int tr = t >> 4, tc = t & 15;
    float acc[4][4] = {};

    for (int kt = 0; kt < 32; ++kt) {
      const int k0 = kt * 32;
      __syncthreads();
#pragma unroll
      for (int it = 0; it < 2; ++it) {
        const int idx = t + it * 256;
        const int r = idx >> 3, c4 = (idx & 7) * 4;
        const float4 v = *(const float4*)(x + (size_t)(b0 + r) * 1024 + k0 + c4);
        sx[c4 + 0][r] = v.x; sx[c4 + 1][r] = v.y;
        sx[c4 + 2][r] = v.z; sx[c4 + 3][r] = v.w;
      }
#pragma unroll
      for (int it = 0; it < 2; ++it) {
        const int idx = t + it * 256;     // 0..511
        const int row = idx >> 4;         // 0..31
        const int c4  = (idx & 15) * 4;   // 0..60
#pragma unroll
        for (int j = 0; j < 4; ++j)
          sw[row][c4 + j] = gateW(Wsh, Wsa, Wra, Wea, k0 + row, c4 + j);
      }
      __syncthreads();
#pragma unroll
      for (int kk = 0; kk < 32; ++kk) {
        const float4 rx = *(const float4*)&sx[kk][tr * 4];
        const float4 wv = *(const float4*)&sw[kk][tc * 4];
#pragma unroll
        for (int i = 0; i < 4; ++i) {
          const float xv = (i == 0) ? rx.x : (i == 1) ? rx.y : (i == 2) ? rx.z : rx.w;
          acc[i][0] += xv * wv.x; acc[i][1] += xv * wv.y;
          acc[i][2] += xv * wv.z; acc[i][3] += xv * wv.w;
        }
      }
    }
    float bv[4];
#pragma unroll
    for (int j = 0; j < 4; ++j) bv[j] = gateB(bsh, bsa, bra, bea, tc * 4 + j);
#pragma unroll
    for (int i = 0; i < 4; ++i) {
      float4 o;
      o.x = acc[i][0] + bv[0]; o.y = acc[i][1] + bv[1];
      o.z = acc[i][2] + bv[2]; o.w = acc[i][3] + bv[3];
      *(float4*)&logits[(size_t)(b0 + tr * 4 + i) * 64 + tc * 4] = o;
    }
    return;
  }

  if (id >= 24448) {                 // x straight convert
    const int local = id - 24448;    // 0..2047; x is [8192][1024]
    const int r0 = (local >> 4) * 64, c0 = (local & 15) * 64;
#pragma unroll
    for (int i = 0; i < 4; ++i) {
      const int row = r0 + i * 16 + (t >> 4);
      const int col = c0 + (t & 15) * 4;
      const float4 v = *(const float4*)(x + (size_t)row * 1024 + col);
      ushort4 u = make_ushort4(f2bf(v.x), f2bf(v.y), f2bf(v.z), f2bf(v.w));
      *(ushort4*)(xb + (size_t)row * 1024 + col) = u;
    }
    return;
  }

  // ---- weight transposes
  const int wid2 = id - 128;
  const float* src; unsigned short* dst; int K, N, local;
  if (wid2 < 10240)      { src = W1;  dst = W1t;  K = 1024; N = 2048; local = wid2; }
  else if (wid2 < 20480) { src = W2;  dst = W2t;  K = 2048; N = 1024; local = wid2 - 10240; }
  else if (wid2 < 23040) { src = W3;  dst = W3t;  K = 1024; N = 512;  local = wid2 - 20480; }
  else if (wid2 < 24064) { src = Wt1; dst = Wt1t; K = 2048; N = 1024; local = wid2 - 23040; }
  else                   { src = Wt2; dst = Wt2t; K = 1024; N = 512;  local = wid2 - 24064; }

  const int nkt = K >> 6, nnt = N >> 6;
  const int per_z = nkt * nnt;
  const int z   = local / per_z;
  const int rem = local - z * per_z;
  const int k0  = (rem % nkt) * 64;
  const int n0  = (rem / nkt) * 64;
  src += (size_t)z * K * N;
  dst += (size_t)z * K * N;

  unsigned short (*lds)[66] = (unsigned short (*)[66])smem;  // [64][66], 132B rows
  const int cr = t >> 4;
  const int cc = (t & 15) * 4;
#pragma unroll
  for (int i = 0; i < 4; ++i) {
    const int row = i * 16 + cr;
    const float4 v = *(const float4*)(src + (size_t)(k0 + row) * N + n0 + cc);
    ushort2 u0; u0.x = f2bf(v.x); u0.y = f2bf(v.y);
    ushort2 u1; u1.x = f2bf(v.z); u1.y = f2bf(v.w);
    *(ushort2*)&lds[row][cc]     = u0;
    *(ushort2*)&lds[row][cc + 2] = u1;
  }
  __syncthreads();
#pragma unroll
  for (int i = 0; i < 4; ++i) {
    const int nrow = i * 16 + cr;
    ushort4 u = make_ushort4(lds[cc + 0][nrow], lds[cc + 1][nrow],
                             lds[cc + 2][nrow], lds[cc + 3][nrow]);
    *(ushort4*)(dst + (size_t)(n0 + nrow) * K + k0 + cc) = u;
  }
}

// ---------------------------------------------------------------------------
// combine: async eo-row staging (global_load_lds) overlapped with softmax,
// then gate-weighted expert sums.
// eo layout: [B][20*512] (expert e at columns e*512..) -> row-contiguous.
// ---------------------------------------------------------------------------
__global__ __launch_bounds__(256) void combine_k(
    const unsigned short* __restrict__ eo,   // [8192][10240]
    const float* __restrict__ logits,        // [8192][64]
    unsigned short* __restrict__ tin)        // [8192][2048]
{
  const int b = blockIdx.x;
  const int t = threadIdx.x;
  __shared__ alignas(16) unsigned short lds[20][512];
  __shared__ float gsm[56];
  const unsigned short* er = eo + (size_t)b * 10240;
  unsigned short* ldsf = &lds[0][0];
#pragma unroll
  for (int i = 0; i < 5; ++i)
    gload16(er + (i * 256 + t) * 8, ldsf + (i * 256 + t) * 8);

  if (t < 64) {
    const float v0 = (t < 56) ? logits[(size_t)b * 64 + t] : 0.f;
    const int off[4] = {0, 20, 32, 44};
    const int wd[4]  = {20, 12, 12, 12};
    for (int g = 0; g < 4; ++g) {
      const bool in = (t >= off[g]) && (t < off[g] + wd[g]);
      float vv = in ? v0 : -1e30f;
      float m = vv;
#pragma unroll
      for (int o = 32; o; o >>= 1) m = fmaxf(m, __shfl_xor(m, o));
      float e = in ? __expf(vv - m) : 0.f;
      float s = e;
#pragma unroll
      for (int o = 32; o; o >>= 1) s += __shfl_xor(s, o);
      if (in) gsm[t] = e / s;
    }
  }
  __syncthreads();   // drains vmcnt (gload_lds) + lgkm and barriers

  const int sec = t >> 6;
  const int h0 = (t & 63) * 8;
  float acc[8] = {0.f, 0.f, 0.f, 0.f, 0.f, 0.f, 0.f, 0.f};
  if (sec == 0) {
    for (int e = 0; e < 20; ++e) {
      const float w = gsm[e];
#pragma unroll
      for (int j = 0; j < 8; ++j) acc[j] += w * bf2f(lds[e][h0 + j]);
    }
  } else {
    const int goff = 20 + (sec - 1) * 12;
    const int ebase = 8 + (sec - 1) * 4;
    for (int tt = 0; tt < 4; ++tt) {
      const float w = gsm[goff + tt];
#pragma unroll
      for (int j = 0; j < 8; ++j) acc[j] += w * bf2f(lds[ebase + tt][h0 + j]);
    }
    for (int ss = 0; ss < 8; ++ss) {
      const float w = gsm[goff + 4 + ss];
#pragma unroll
      for (int j = 0; j < 8; ++j) acc[j] += w * bf2f(lds[ss][h0 + j]);
    }
  }
  unsigned short* ob = tin + (size_t)b * 2048 + sec * 512 + h0;
  ushort4 u0 = make_ushort4(f2bf(acc[0]), f2bf(acc[1]), f2bf(acc[2]), f2bf(acc[3]));
  ushort4 u1 = make_ushort4(f2bf(acc[4]), f2bf(acc[5]), f2bf(acc[6]), f2bf(acc[7]));
  *(ushort4*)ob = u0;
  *(ushort4*)(ob + 4) = u1;
}

// ---------------------------------------------------------------------------
// final dense: wave per (b, task)
// ---------------------------------------------------------------------------
__global__ __launch_bounds__(256) void outd_k(
    const unsigned short* __restrict__ t2,   // [2][8192][512]
    const float* __restrict__ Wd0, const float* __restrict__ bd0,
    const float* __restrict__ Wd1, const float* __restrict__ bd1,
    float* __restrict__ out)
{
  const int gid = blockIdx.x * 4 + (threadIdx.x >> 6);
  const int lane = threadIdx.x & 63;
  const int b = gid >> 1, task = gid & 1;
  const uint4 raw = *(const uint4*)(t2 + ((size_t)task * 8192 + b) * 512 + lane * 8);
  const unsigned short* rs = (const unsigned short*)&raw;
  float v[8];
#pragma unroll
  for (int j = 0; j < 8; ++j) v[j] = bf2f(rs[j]);
  const float* Wd = task ? Wd1 : Wd0;
  const float* bd = task ? bd1 : bd0;
  const int ncol = task ? 4 : 6;
  float* ob = task ? (out + (size_t)8192 * 6 + (size_t)b * 4) : (out + (size_t)b * 6);
  for (int c = 0; c < ncol; ++c) {
    float p = 0.f;
#pragma unroll
    for (int j = 0; j < 8; ++j) p += v[j] * Wd[(size_t)(lane * 8 + j) * ncol + c];
#pragma unroll
    for (int o = 32; o; o >>= 1) p += __shfl_xor(p, o);
    if (lane == 0) ob[c] = p + bd[c];
  }
}

// ---------------------------------------------------------------------------
extern "C" void kernel_launch(void* const* d_in, const int* in_sizes, int n_in,
                              void* d_out, int out_size, void* d_ws, size_t ws_size,
                              hipStream_t stream) {
  const float* x     = (const float*)d_in[0];
  const float* W1    = (const float*)d_in[1];
  const float* b1    = (const float*)d_in[2];
  const float* W2    = (const float*)d_in[3];
  const float* b2    = (const float*)d_in[4];
  const float* W3    = (const float*)d_in[5];
  const float* b3    = (const float*)d_in[6];
  const float* Wg_sh = (const float*)d_in[7];
  const float* bg_sh = (const float*)d_in[8];
  const float* Wg_sa = (const float*)d_in[9];
  const float* bg_sa = (const float*)d_in[10];
  const float* Wg_ra = (const float*)d_in[11];
  const float* bg_ra = (const float*)d_in[12];
  const float* Wg_ea = (const float*)d_in[13];
  const float* bg_ea = (const float*)d_in[14];
  const float* Wt1   = (const float*)d_in[15];
  const float* bt1   = (const float*)d_in[16];
  const float* Wt2   = (const float*)d_in[17];
  const float* bt2   = (const float*)d_in[18];
  const float* Wd0   = (const float*)d_in[19];
  const float* bd0   = (const float*)d_in[20];
  const float* Wd1   = (const float*)d_in[21];
  const float* bd1   = (const float*)d_in[22];
  float* out = (float*)d_out;

  const int B = 8192, D = 1024, H1 = 2048, H2 = 1024, H3 = 512;
  const int E = 20, TU1 = 1024, TU2 = 512, TIN = 2048;

  auto rnd = [](size_t n) { return (n + 255) & ~(size_t)255; };
  const size_t szXb   = rnd((size_t)B * D * 2);
  const size_t szW1t  = rnd((size_t)E * H1 * D * 2);
  const size_t szW2t  = rnd((size_t)E * H2 * H1 * 2);
  const size_t szW3t  = rnd((size_t)E * H3 * H2 * 2);
  const size_t szWt1t = rnd((size_t)2 * TU1 * TIN * 2);
  const size_t szWt2t = rnd((size_t)2 * TU2 * TU1 * 2);
  const size_t szLog  = rnd((size_t)B * 64 * 4);
  const size_t szEo   = rnd((size_t)E * B * H3 * 2);
  const size_t szTin  = rnd((size_t)B * TIN * 2);
  const size_t szT1   = rnd((size_t)2 * B * TU1 * 2);
  const size_t szT2   = rnd((size_t)2 * B * TU2 * 2);
  const size_t szH1e  = rnd((size_t)B * H1 * 2);      // 33.6 MB per expert
  const size_t szH2e  = rnd((size_t)B * H2 * 2);      // 16.8 MB per expert
  const size_t fixed = szXb + szW1t + szW2t + szW3t + szWt1t + szWt2t +
                       szLog + szEo;
  const size_t tNeed = szTin + szT1 + szT2;

  // G=2 rotating h1 keeps L1->L2 L3-resident; hg = h2 accumulation depth
  // (L3-gemm batches over hg experts). Pick largest hg that fits ws.
  const int G = 2;
  int hg = 2;
  {
    const int opts[3] = {10, 5, 2};
    for (int i = 0; i < 3; ++i) {
      size_t hNeed = (size_t)G * szH1e + (size_t)opts[i] * szH2e;
      if (hNeed < tNeed) hNeed = tNeed;
      if (fixed + hNeed <= ws_size) { hg = opts[i]; break; }
    }
  }

  char* w = (char*)d_ws;
  auto alloc = [&](size_t n) { char* p = w; w += rnd(n); return p; };
  unsigned short* xb   = (unsigned short*)alloc((size_t)B * D * 2);
  unsigned short* W1t  = (unsigned short*)alloc((size_t)E * H1 * D * 2);
  unsigned short* W2t  = (unsigned short*)alloc((size_t)E * H2 * H1 * 2);
  unsigned short* W3t  = (unsigned short*)alloc((size_t)E * H3 * H2 * 2);
  unsigned short* Wt1t = (unsigned short*)alloc((size_t)2 * TU1 * TIN * 2);
  unsigned short* Wt2t = (unsigned short*)alloc((size_t)2 * TU2 * TU1 * 2);
  float*          lgts = (float*)alloc((size_t)B * 64 * 4);
  unsigned short* eo   = (unsigned short*)alloc((size_t)E * B * H3 * 2);
  char* hreg = w;
  unsigned short* h1  = (unsigned short*)hreg;                       // [2][B][H1] rot
  unsigned short* h2  = (unsigned short*)(hreg + (size_t)G * szH1e); // [hg][B][H2]
  unsigned short* tin = (unsigned short*)hreg;
  unsigned short* t1  = (unsigned short*)(hreg + szTin);
  unsigned short* t2  = (unsigned short*)(hreg + szTin + szT1);
  (void)in_sizes; (void)n_in; (void)out_size;

  auto launch256 = [&](const unsigned short* Ap, int lda, long sA,
                       const unsigned short* Btp, long sB,
                       const float* biasp, long sBias,
                       unsigned short* Outp, int ldo, long sOut,
                       int N, int K, int nz) {
    const int nbx = N / 256, nby = B / 256;
    gemm256<<<dim3(nbx * nby * nz), 512, 0, stream>>>(
        Ap, Btp, biasp, Outp, K, lda, ldo, nbx, nby, sA, sB, sBias, sOut);
  };

  // ONE prep launch: gate logits + all conversions/transposes
  prep_all<<<dim3(26496), 256, 0, stream>>>(
      W1, W2, W3, Wt1, Wt2, x,
      Wg_sh, bg_sh, Wg_sa, bg_sa, Wg_ra, bg_ra, Wg_ea, bg_ea,
      W1t, W2t, W3t, Wt1t, Wt2t, xb, lgts);

  // experts: L1/L2 at G=2 (L3-cache-resident h1), L3-gemm batched per hg
  for (int e0 = 0; e0 < E; e0 += G) {
    launch256(xb, D, 0,
              W1t + (size_t)e0 * H1 * D, (long)H1 * D,
              b1 + (size_t)e0 * H1, H1,
              h1, H1, (long)B * H1, H1, D, G);
    launch256(h1, H1, (long)B * H1,
              W2t + (size_t)e0 * H2 * H1, (long)H2 * H1,
              b2 + (size_t)e0 * H2, H2,
              h2 + (size_t)(e0 % hg) * B * H2, H2, (long)B * H2, H2, H1, G);
    if ((e0 + G) % hg == 0) {
      const int eb = e0 + G - hg;        // first expert of the filled h2 window
      launch256(h2, H2, (long)B * H2,
                W3t + (size_t)eb * H3 * H2, (long)H3 * H2,
                b3 + (size_t)eb * H3, H3,
                eo + (size_t)eb * H3, E * H3, H3, H3, H2, hg);
    }
  }

  combine_k<<<dim3(B), 256, 0, stream>>>(eo, lgts, tin);

  // towers (z = task)
  launch256(tin, TIN, 0, Wt1t, (long)TU1 * TIN, bt1, TU1,
            t1, TU1, (long)B * TU1, TU1, TIN, 2);
  launch256(t1, TU1, (long)B * TU1, Wt2t, (long)TU2 * TU1, bt2, TU2,
            t2, TU2, (long)B * TU2, TU2, TU1, 2);

  outd_k<<<dim3(B * 2 / 4), 256, 0, stream>>>(t2, Wd0, bd0, Wd1, bd1, out);
}